// Round 1
// 638.931 us; speedup vs baseline: 1.0772x; 1.0772x over previous
//
#include <hip/hip_runtime.h>

// CompressiveMemory — round 6.
//  * gemm_qkv rewritten as 256x256/BK=64 8-wave 8-phase pipeline (T3+T4+T5):
//    128KB double-buffered LDS, one half-tile global_load_lds prefetch per
//    phase, counted vmcnt(6) at phases 4/8 only (never 0 in the loop),
//    setprio(1) around each 16-MFMA cluster, raw s_barriers. Stage schedule
//    verified: every half lands >=3 phases before first read, issued after
//    its previous content's last read (>=1 barrier pair).
//  * Swizzle folded into per-lane GLOBAL source column ((lane&7)^(lane>>3));
//    LDS stays linear for global_load_lds; frag reads apply same involution.
//  * XCD-bijective block swizzle (768 blocks % 8 == 0).
//  * Epilogue reuses the 128KB LDS (exactly one 256x256 bf16 tile).
//  * Everything else (seg_stats / prefix / attn / out-GEMM) unchanged.

#define H_ 16
#define SEG_ 512
#define NSEG_ 16
#define B_ 2
#define T_ 8192
#define D_ 1024
#define BT_ 16384

#define NPROJ ((size_t)BT_ * D_)   // 16,777,216
#define NW ((size_t)D_ * D_)       // 1,048,576

__device__ unsigned short g_qb[NPROJ], g_kb[NPROJ], g_vb[NPROJ];   // bf16 projections
__device__ unsigned short g_xh[NPROJ];
__device__ unsigned short g_wqkv[3 * NW];                          // [Wq;Wk;Wv] bf16
__device__ unsigned short g_ath[NPROJ], g_atl[NPROJ];
__device__ unsigned short g_woh[NW], g_wol[NW];
__device__ unsigned short g_vt[(size_t)512 * 64 * 512];            // per-tile V^T bf16
__device__ float g_M[(size_t)512 * 4096];
__device__ float g_z[(size_t)512 * 64];

typedef __attribute__((ext_vector_type(8))) short short8;
typedef __attribute__((ext_vector_type(8))) unsigned short ushort8;
typedef __attribute__((ext_vector_type(4))) float f32x4;

__device__ __forceinline__ float elu1(float x) {
    return x > 0.f ? x + 1.f : __expf(x);
}
__device__ __forceinline__ unsigned short f2bf(float x) {
    unsigned u = __float_as_uint(x);
    u += 0x7fffu + ((u >> 16) & 1u);           // RNE
    return (unsigned short)(u >> 16);
}
__device__ __forceinline__ float bf2f(unsigned short h) {
    return __uint_as_float((unsigned)h << 16);
}
__device__ __forceinline__ void load_lds16(const unsigned short* g, unsigned short* l) {
    __builtin_amdgcn_global_load_lds(
        (const __attribute__((address_space(1))) unsigned int*)g,
        (__attribute__((address_space(3))) unsigned int*)l, 16, 0, 0);
}
// ushort offset of (row, 8-elem block) in a [128][32]-bf16 LDS tile, XOR-swizzled.
// (still used by gemm_bt_split)
__device__ __forceinline__ int swz(int row, int blk) {
    return row * 32 + ((blk ^ ((row >> 1) & 3)) << 3);
}

__global__ __launch_bounds__(256) void cast_bf16(
    const float* __restrict__ in, unsigned short* __restrict__ out, int n)
{
    int i = (blockIdx.x * 256 + threadIdx.x) * 4;
    if (i >= n) return;
    float4 x = *(const float4*)(in + i);
    ushort4 h;
    h.x = f2bf(x.x); h.y = f2bf(x.y); h.z = f2bf(x.z); h.w = f2bf(x.w);
    *(ushort4*)(out + i) = h;
}

__global__ __launch_bounds__(256) void split_bf16(
    const float* __restrict__ in, unsigned short* __restrict__ hi,
    unsigned short* __restrict__ lo, int n)
{
    int i = (blockIdx.x * 256 + threadIdx.x) * 4;
    if (i >= n) return;
    float4 x = *(const float4*)(in + i);
    ushort4 h, l;
    h.x = f2bf(x.x); l.x = f2bf(x.x - bf2f(h.x));
    h.y = f2bf(x.y); l.y = f2bf(x.y - bf2f(h.y));
    h.z = f2bf(x.z); l.z = f2bf(x.z - bf2f(h.z));
    h.w = f2bf(x.w); l.w = f2bf(x.w - bf2f(h.w));
    *(ushort4*)(hi + i) = h;
    *(ushort4*)(lo + i) = l;
}

// ---------------------------------------------------------------------------
// Fused QKV GEMM, 8-phase 256x256 pipeline.
// C[m,n] = sum_k x[m,k] * Wqkv[n,k]; M=16384, N=3072, K=1024; bf16 out.
// 8 waves: wave_m = w>>2 (2), wave_n = w&3 (4); per-wave output 128x64.
// LDS per buffer: A 256x64 bf16 (32KB) + B 256x64 (32KB); 2 buffers = 128KB.
// Half-tile = 128 rows (16KB) = 2 global_load_lds per wave.
// ---------------------------------------------------------------------------

#define VMC(N) asm volatile("s_waitcnt vmcnt(" #N ")" ::: "memory")

#define STAGE_A(p, h, tt, u) \
    load_lds16(Aw + ((h) * 128 + (u) * 8) * 1024 + (tt) * 64, \
               &lds[(p) * 32768 + ((h) * 128 + w * 16 + (u) * 8) * 64])
#define STAGE_B(p, h, tt, u) \
    load_lds16(Bww + ((h) * 128 + (u) * 8) * 1024 + (tt) * 64, \
               &lds[(p) * 32768 + 16384 + ((h) * 128 + w * 16 + (u) * 8) * 64])
#define STAGE_AH(p, h, tt) do { STAGE_A(p, h, tt, 0); STAGE_A(p, h, tt, 1); } while (0)
#define STAGE_BH(p, h, tt) do { STAGE_B(p, h, tt, 0); STAGE_B(p, h, tt, 1); } while (0)

#define LDA(PBUF, MLO) do { \
    _Pragma("unroll") for (int m2 = 0; m2 < 4; ++m2) \
    _Pragma("unroll") for (int ks2 = 0; ks2 < 2; ++ks2) \
        a[m2][ks2] = *(const short8*)&lds[(PBUF) * 32768 + aoff[ks2] + ((MLO) + m2) * 1024]; \
} while (0)

#define LDB(PBUF) do { \
    _Pragma("unroll") for (int n2 = 0; n2 < 4; ++n2) \
    _Pragma("unroll") for (int ks2 = 0; ks2 < 2; ++ks2) \
        b[n2][ks2] = *(const short8*)&lds[(PBUF) * 32768 + boff[ks2] + n2 * 1024]; \
} while (0)

#define MFMA_QUAD(MLO, NLO) do { \
    _Pragma("unroll") for (int m2 = 0; m2 < 4; ++m2) \
    _Pragma("unroll") for (int n2 = 0; n2 < 2; ++n2) \
    _Pragma("unroll") for (int ks2 = 0; ks2 < 2; ++ks2) \
        acc[(MLO) + m2][(NLO) + n2] = __builtin_amdgcn_mfma_f32_16x16x32_bf16( \
            a[m2][ks2], b[(NLO) + n2][ks2], acc[(MLO) + m2][(NLO) + n2], 0, 0, 0); \
} while (0)

#define PH(MLO, NLO) do { \
    __builtin_amdgcn_s_barrier(); \
    asm volatile("s_waitcnt lgkmcnt(0)" ::: "memory"); \
    __builtin_amdgcn_sched_barrier(0); \
    __builtin_amdgcn_s_setprio(1); \
    MFMA_QUAD(MLO, NLO); \
    __builtin_amdgcn_s_setprio(0); \
    __builtin_amdgcn_sched_barrier(0); \
    __builtin_amdgcn_s_barrier(); \
} while (0)

__global__ __launch_bounds__(512, 2) void gemm_qkv8(
    const unsigned short* __restrict__ A, const unsigned short* __restrict__ Bw,
    unsigned short* __restrict__ Q, unsigned short* __restrict__ Kp,
    unsigned short* __restrict__ V)
{
    __shared__ unsigned short lds[65536];   // 128KB: [buf0 A|B][buf1 A|B]
    const int t = threadIdx.x, lane = t & 63, w = t >> 6;
    const int wave_m = w >> 2, wave_n = w & 3;

    // XCD-bijective swizzle: 768 blocks = 96 * 8.
    const int bid = blockIdx.x;
    const int sb = (bid & 7) * 96 + (bid >> 3);
    const int mb = sb / 12, nb = sb % 12;
    const int m0 = mb * 256, n0 = nb * 256;

    // staging per-lane constants (LDS linear; swizzle folded into global col)
    const int lrow = lane >> 3;                       // 0..7
    const int lcol = ((lane & 7) ^ lrow) * 8;         // swizzled ushort col
    const unsigned short* Aw  = A  + (size_t)(m0 + w * 16 + lrow) * 1024 + lcol;
    const unsigned short* Bww = Bw + (size_t)(n0 + w * 16 + lrow) * 1024 + lcol;

    // frag-read per-lane ushort offsets (same involution as the stage side)
    const int fr = lane & 15, g4 = lane >> 4;
    int aoff[2], boff[2];
#pragma unroll
    for (int ks2 = 0; ks2 < 2; ++ks2) {
        aoff[ks2] = (wave_m * 128 + fr) * 64 + (((ks2 * 4 + g4) ^ (fr & 7)) * 8);
        boff[ks2] = 16384 + (wave_n * 64 + fr) * 64 + (((ks2 * 4 + g4) ^ (fr & 7)) * 8);
    }

    f32x4 acc[8][4];
#pragma unroll
    for (int i = 0; i < 8; ++i)
#pragma unroll
        for (int j = 0; j < 4; ++j) acc[i][j] = (f32x4)0.f;
    short8 a[4][2], b[4][2];

    // Prologue: tile0 (buf0) fully + tile1 (buf1) B0,B1,A0. vmcnt(6) -> tile0 landed.
    STAGE_BH(0, 0, 0); STAGE_BH(0, 1, 0); STAGE_AH(0, 0, 0); STAGE_AH(0, 1, 0);
    STAGE_BH(1, 0, 1); STAGE_BH(1, 1, 1); STAGE_AH(1, 0, 1);
    VMC(6);
    __builtin_amdgcn_s_barrier();

    // Main loop: 7 full iterations (tiles 0..13 computed, 2..15 prefetched).
#pragma unroll 1
    for (int it = 0; it < 7; ++it) {
        const int t1 = 2 * it + 1, t2 = 2 * it + 2, t3 = 2 * it + 3;
        // p1: compute buf0 quad(0,0); stage buf1.A1 (tile t1, needed p5/p7)
        LDB(0); LDA(0, 0);
        STAGE_AH(1, 1, t1);
        PH(0, 0);
        // p2: quad(0,2); stage buf0.B0 (tile t2)
        STAGE_BH(0, 0, t2);
        PH(0, 2);
        // p3: quad(4,0); stage buf0.B1
        LDA(0, 4);
        STAGE_BH(0, 1, t2);
        PH(4, 0);
        // p4: quad(4,2); stage buf0.A0; counted vmcnt
        STAGE_AH(0, 0, t2);
        VMC(6);
        PH(4, 2);
        // p5: compute buf1 quad(0,0); stage buf0.A1 (tile t2)
        LDB(1); LDA(1, 0);
        STAGE_AH(0, 1, t2);
        PH(0, 0);
        // p6: quad(0,2); stage buf1.B0 (tile t3)
        STAGE_BH(1, 0, t3);
        PH(0, 2);
        // p7: quad(4,0); stage buf1.B1
        LDA(1, 4);
        STAGE_BH(1, 1, t3);
        PH(4, 0);
        // p8: quad(4,2); stage buf1.A0; counted vmcnt
        STAGE_AH(1, 0, t3);
        VMC(6);
        PH(4, 2);
    }
    // Final iteration: tiles 14 (buf0) and 15 (buf1); only p1's stage remains.
    LDB(0); LDA(0, 0);
    STAGE_AH(1, 1, 15);
    PH(0, 0);
    PH(0, 2);
    LDA(0, 4);
    PH(4, 0);
    VMC(0);           // drain: tile 15 fully landed before p5 reads
    PH(4, 2);
    LDB(1); LDA(1, 0);
    PH(0, 0);
    PH(0, 2);
    LDA(1, 4);
    PH(4, 0);
    PH(4, 2);

    // Epilogue: acc -> bf16 -> LDS (exactly 256x256 ushorts) -> coalesced store.
    const int ccol = lane & 15, crow = (lane >> 4) * 4;
#pragma unroll
    for (int m = 0; m < 8; ++m)
#pragma unroll
        for (int n = 0; n < 4; ++n) {
            const int row = wave_m * 128 + m * 16 + crow;
            const int col = wave_n * 64 + n * 16 + ccol;
#pragma unroll
            for (int r = 0; r < 4; ++r)
                lds[(row + r) * 256 + col] = f2bf(acc[m][n][r]);
        }
    __syncthreads();
    const int which = n0 >> 10, col0 = n0 & 1023;
    unsigned short* outp = which == 0 ? Q : (which == 1 ? Kp : V);
    const int orow = t >> 1, och = (t & 1) * 128;
    unsigned short* gp = outp + (size_t)(m0 + orow) * 1024 + col0 + och;
    const unsigned short* lp = &lds[orow * 256 + och];
#pragma unroll
    for (int u = 0; u < 128; u += 8)
        *(ushort8*)(gp + u) = *(const ushort8*)(lp + u);
}

// Out-GEMM: C[m,n] = sum_k A[m,k]*B[n,k], split-bf16 (3 MFMA), fp32 C. Swizzled.
#define BK 32
__global__ __launch_bounds__(256) void gemm_bt_split(
    const unsigned short* __restrict__ Ah, const unsigned short* __restrict__ Al,
    const unsigned short* __restrict__ Bh, const unsigned short* __restrict__ Bl,
    float* __restrict__ C, int M, int N, int K)
{
    __shared__ unsigned short sAh[128 * BK], sAl[128 * BK];
    __shared__ unsigned short sBh[128 * BK], sBl[128 * BK];
    const int t = threadIdx.x, lane = t & 63, wave = t >> 6;
    const int m0 = blockIdx.y * 128, n0 = blockIdx.x * 128;
    const int wm = (wave & 1) * 64, wn = (wave >> 1) * 64;
    const int srow = wave * 32 + (lane >> 2);
    const int scol = ((lane & 3) ^ ((lane >> 3) & 3)) * 8;
    const int fr = lane & 15, g4 = lane >> 4;

    f32x4 acc[4][4];
#pragma unroll
    for (int i = 0; i < 4; ++i)
#pragma unroll
        for (int j = 0; j < 4; ++j) acc[i][j] = (f32x4)0.f;

    for (int k0 = 0; k0 < K; k0 += BK) {
        __syncthreads();
#pragma unroll
        for (int i = 0; i < 2; ++i) {
            const size_t ga = (size_t)(m0 + srow + i * 16) * K + k0 + scol;
            const size_t gb = (size_t)(n0 + srow + i * 16) * K + k0 + scol;
            const int lb = (wave * 32 + i * 16) * BK;
            load_lds16(Ah + ga, &sAh[lb]);
            load_lds16(Al + ga, &sAl[lb]);
            load_lds16(Bh + gb, &sBh[lb]);
            load_lds16(Bl + gb, &sBl[lb]);
        }
        __syncthreads();
        short8 ah[4], al[4], bh[4], bl[4];
#pragma unroll
        for (int i = 0; i < 4; ++i) {
            ah[i] = *(const short8*)&sAh[swz(wm + i * 16 + fr, g4)];
            al[i] = *(const short8*)&sAl[swz(wm + i * 16 + fr, g4)];
            bh[i] = *(const short8*)&sBh[swz(wn + i * 16 + fr, g4)];
            bl[i] = *(const short8*)&sBl[swz(wn + i * 16 + fr, g4)];
        }
#pragma unroll
        for (int i = 0; i < 4; ++i)
#pragma unroll
            for (int j = 0; j < 4; ++j) {
                acc[i][j] = __builtin_amdgcn_mfma_f32_16x16x32_bf16(ah[i], bh[j], acc[i][j], 0, 0, 0);
                acc[i][j] = __builtin_amdgcn_mfma_f32_16x16x32_bf16(al[i], bh[j], acc[i][j], 0, 0, 0);
                acc[i][j] = __builtin_amdgcn_mfma_f32_16x16x32_bf16(ah[i], bl[j], acc[i][j], 0, 0, 0);
            }
    }
    const int ccol = lane & 15, crow = (lane >> 4) * 4;
#pragma unroll
    for (int i = 0; i < 4; ++i)
#pragma unroll
        for (int j = 0; j < 4; ++j) {
            float* cp = C + (size_t)(m0 + wm + i * 16 + crow) * N + (n0 + wn + j * 16 + ccol);
#pragma unroll
            for (int r = 0; r < 4; ++r) cp[(size_t)r * N] = acc[i][j][r];
        }
}

// Per (b,h,seg): M_seg[d][v], zsum[d], and V^T bf16 tile. Inputs bf16.
__global__ __launch_bounds__(256) void seg_stats(
    const unsigned short* __restrict__ kproj, const unsigned short* __restrict__ vproj,
    float* __restrict__ Mseg, float* __restrict__ zsum,
    unsigned short* __restrict__ vtg)
{
    __shared__ float ks[64][68];
    __shared__ float vs[64][68];
    const int idx = blockIdx.x;
    const int seg = idx & 15;
    const int bh  = idx >> 4;
    const int h   = bh & 15;
    const int b   = bh >> 4;
    const size_t base = ((size_t)b * T_ + (size_t)seg * SEG_ + (size_t)h * 32) * D_;
    const unsigned short* kt = kproj + base;
    const unsigned short* vt = vproj + base;
    const int t  = threadIdx.x;
    const int d0 = (t >> 4) * 4;
    const int v0 = (t & 15) * 4;
    const int lr = t >> 2;
    const int lc = (t & 3) * 16;
    float acc[4][4];
#pragma unroll
    for (int i = 0; i < 4; ++i)
#pragma unroll
        for (int j = 0; j < 4; ++j) acc[i][j] = 0.f;
    float zacc = 0.f;

    for (int c0 = 0; c0 < SEG_; c0 += 64) {
        __syncthreads();
        {
            const unsigned short* kp = kt + (size_t)(c0 + lr) * 64 + lc;
            const unsigned short* vp = vt + (size_t)(c0 + lr) * 64 + lc;
            ushort8 k0 = *(const ushort8*)kp,       k1 = *(const ushort8*)(kp + 8);
            ushort8 v0v = *(const ushort8*)vp,      v1 = *(const ushort8*)(vp + 8);
#pragma unroll
            for (int e = 0; e < 8; ++e) {
                ks[lr][lc + e]     = elu1(bf2f(k0[e]));
                ks[lr][lc + 8 + e] = elu1(bf2f(k1[e]));
                vs[lr][lc + e]     = bf2f(v0v[e]);
                vs[lr][lc + 8 + e] = bf2f(v1[e]);
            }
        }
        __syncthreads();
#pragma unroll 8
        for (int i = 0; i < 64; ++i) {
            float a0 = ks[i][d0 + 0], a1 = ks[i][d0 + 1];
            float a2 = ks[i][d0 + 2], a3 = ks[i][d0 + 3];
            float b0 = vs[i][v0 + 0], b1 = vs[i][v0 + 1];
            float b2 = vs[i][v0 + 2], b3 = vs[i][v0 + 3];
            acc[0][0] += a0 * b0; acc[0][1] += a0 * b1; acc[0][2] += a0 * b2; acc[0][3] += a0 * b3;
            acc[1][0] += a1 * b0; acc[1][1] += a1 * b1; acc[1][2] += a1 * b2; acc[1][3] += a1 * b3;
            acc[2][0] += a2 * b0; acc[2][1] += a2 * b1; acc[2][2] += a2 * b2; acc[2][3] += a2 * b3;
            acc[3][0] += a3 * b0; acc[3][1] += a3 * b1; acc[3][2] += a3 * b2; acc[3][3] += a3 * b3;
        }
        if (t < 64) {
#pragma unroll 8
            for (int i = 0; i < 64; ++i) zacc += ks[i][t];
        }
        {   // V^T bf16: row = v-dim (lr), cols = time
            ushort8 w0, w1;
#pragma unroll
            for (int i = 0; i < 8; ++i) w0[i] = f2bf(vs[lc + i][lr]);
#pragma unroll
            for (int i = 0; i < 8; ++i) w1[i] = f2bf(vs[lc + 8 + i][lr]);
            unsigned short* vo = vtg + ((size_t)idx * 64 + lr) * 512 + c0 + lc;
            *(ushort8*)vo       = w0;
            *(ushort8*)(vo + 8) = w1;
        }
    }
    float* Mout = Mseg + (size_t)idx * 4096;
#pragma unroll
    for (int i = 0; i < 4; ++i)
        *(float4*)(Mout + (size_t)(d0 + i) * 64 + v0) =
            make_float4(acc[i][0], acc[i][1], acc[i][2], acc[i][3]);
    if (t < 64) zsum[(size_t)idx * 64 + t] = zacc;
}

// Per (b,h): in-place exclusive prefix of M, inclusive prefix of z.
__global__ __launch_bounds__(256) void prefix_scan(
    float* __restrict__ M, float* __restrict__ z)
{
    const int bh = blockIdx.x;
    const int t  = threadIdx.x;
    float run[16];
#pragma unroll
    for (int u = 0; u < 16; ++u) run[u] = 0.f;
    float runz = 0.f;
    for (int seg = 0; seg < NSEG_; ++seg) {
        const size_t o = ((size_t)bh * NSEG_ + seg) * 4096 + (size_t)t * 16;
#pragma unroll
        for (int u = 0; u < 16; u += 4) {
            float4 m = *(const float4*)(M + o + u);
            *(float4*)(M + o + u) = make_float4(run[u], run[u+1], run[u+2], run[u+3]);
            run[u] += m.x; run[u+1] += m.y; run[u+2] += m.z; run[u+3] += m.w;
        }
        if (t < 64) {
            const size_t oz = ((size_t)bh * NSEG_ + seg) * 64 + t;
            runz += z[oz];
            z[oz] = runz;
        }
    }
}

// MFMA flash attention per (b,h,seg,64-row q-chunk). bf16 q/k/v inputs.
__global__ __launch_bounds__(256) void attn_mfma(
    const unsigned short* __restrict__ qproj, const unsigned short* __restrict__ kproj,
    const unsigned short* __restrict__ vtg, const float* __restrict__ memb,
    const float* __restrict__ Zaf, const float* __restrict__ betas,
    unsigned short* __restrict__ ath, unsigned short* __restrict__ atl)
{
    __shared__ unsigned short sm_k[64 * 72];   // k bf16 ; epilogue att_hi
    __shared__ unsigned short sm_v[64 * 72];   // V^T bf16 ; epilogue att_lo
    __shared__ unsigned short sm_p[64 * 72];   // mem^T bf16, then P bf16
    __shared__ float Zsh[64], gsh[64];

    const int idx  = blockIdx.x;
    const int qc   = idx & 7;
    const int rest = idx >> 3;
    const int seg  = rest & 15;
    const int bh   = rest >> 4;
    const int h    = bh & 15;
    const int b    = bh >> 4;
    const size_t base = ((size_t)b * T_ + (size_t)seg * SEG_ + (size_t)h * 32) * D_;

    const int t    = threadIdx.x;
    const int lane = t & 63;
    const int w    = t >> 6;
    const int c16  = lane & 15;
    const int g4   = lane >> 4;
    const int lr   = t >> 2;
    const int lc   = (t & 3) * 16;

    const unsigned short* qt = qproj + base + (size_t)qc * 4096;
    const unsigned short* kt = kproj + base;
    const unsigned short* vt = vtg + (size_t)rest * (64 * 512);
    const float* mb = memb + (size_t)rest * 4096;

    if (t < 64) {
        Zsh[t] = Zaf[(size_t)rest * 64 + t];
        gsh[t] = 1.f / (1.f + __expf(-betas[h * 64 + t]));
    }

    // q fragments (A-layout: m = w*16+c16, k = g4*8 + ks*32 + j), sq, rowsum
    short8 qh[2], sqh[2];
    float rowsum = 0.f;
#pragma unroll
    for (int ks = 0; ks < 2; ++ks) {
        const unsigned short* qp = qt + (size_t)(w * 16 + c16) * 64 + g4 * 8 + ks * 32;
        ushort8 qv = *(const ushort8*)qp;
        short8 qf, sf;
#pragma unroll
        for (int j = 0; j < 8; ++j) {
            float e = elu1(bf2f(qv[j]));
            rowsum += e;
            qf[j] = (short)qv[j];
            sf[j] = (short)f2bf(e);
        }
        qh[ks] = qf; sqh[ks] = sf;
    }
    rowsum += __shfl_xor(rowsum, 16);
    rowsum += __shfl_xor(rowsum, 32);

    // stage mem^T (bf16) into sm_p
    {
        const float* mp = mb + (size_t)lr * 64 + lc;
#pragma unroll
        for (int u = 0; u < 4; ++u) {
            float4 m4 = *(const float4*)(mp + u * 4);
            sm_p[(lc + u * 4 + 0) * 72 + lr] = f2bf(m4.x);
            sm_p[(lc + u * 4 + 1) * 72 + lr] = f2bf(m4.y);
            sm_p[(lc + u * 4 + 2) * 72 + lr] = f2bf(m4.z);
            sm_p[(lc + u * 4 + 3) * 72 + lr] = f2bf(m4.w);
        }
    }
    __syncthreads();

    // num = sq @ mem  (B-operand = mem^T[v][d])
    f32x4 numf[4];
#pragma unroll
    for (int nf = 0; nf < 4; ++nf) numf[nf] = (f32x4)0.f;
#pragma unroll
    for (int ks = 0; ks < 2; ++ks)
#pragma unroll
        for (int nf = 0; nf < 4; ++nf) {
            short8 bm = *(const short8*)&sm_p[(nf * 16 + c16) * 72 + g4 * 8 + ks * 32];
            numf[nf] = __builtin_amdgcn_mfma_f32_16x16x32_bf16(sqh[ks], bm, numf[nf], 0, 0, 0);
        }

    f32x4 o[4];
#pragma unroll
    for (int nf = 0; nf < 4; ++nf) o[nf] = (f32x4)0.f;
    float mrow[4] = {-1e30f, -1e30f, -1e30f, -1e30f};
    float lrow[4] = {0.f, 0.f, 0.f, 0.f};

    for (int kb = 0; kb < 8; ++kb) {
        __syncthreads();
        {   // stage k and V^T (both already bf16 — raw 16B copies)
            const unsigned short* kp = kt + (size_t)(kb * 64 + lr) * 64 + lc;
            *(ushort8*)&sm_k[lr * 72 + lc]     = *(const ushort8*)kp;
            *(ushort8*)&sm_k[lr * 72 + lc + 8] = *(const ushort8*)(kp + 8);
            const unsigned short* vp = vt + (size_t)lr * 512 + kb * 64 + lc;
            *(ushort8*)&sm_v[lr * 72 + lc]     = *(const ushort8*)vp;
            *(ushort8*)&sm_v[lr * 72 + lc + 8] = *(const ushort8*)(vp + 8);
        }
        __syncthreads();

        // scores S = Q @ K^T
        f32x4 s[4];
#pragma unroll
        for (int nf = 0; nf < 4; ++nf) s[nf] = (f32x4)0.f;
#pragma unroll
        for (int ks = 0; ks < 2; ++ks)
#pragma unroll
            for (int nf = 0; nf < 4; ++nf) {
                short8 bk = *(const short8*)&sm_k[(nf * 16 + c16) * 72 + g4 * 8 + ks * 32];
                s[nf] = __builtin_amdgcn_mfma_f32_16x16x32_bf16(qh[ks], bk, s[nf], 0, 0, 0);
            }
#pragma unroll
        for (int nf = 0; nf < 4; ++nf) s[nf] *= 0.125f;

        float corr[4];
#pragma unroll
        for (int r = 0; r < 4; ++r) {
            float mx = fmaxf(fmaxf(s[0][r], s[1][r]), fmaxf(s[2][r], s[3][r]));
            mx = fmaxf(mx, __shfl_xor(mx, 1));
            mx = fmaxf(mx, __shfl_xor(mx, 2));
            mx = fmaxf(mx, __shfl_xor(mx, 4));
            mx = fmaxf(mx, __shfl_xor(mx, 8));
            float mnew = fmaxf(mrow[r], mx);
            corr[r] = __expf(mrow[r] - mnew);
            mrow[r] = mnew;
        }
#pragma unroll
        for (int nf = 0; nf < 4; ++nf)
#pragma unroll
            for (int r = 0; r < 4; ++r)
                s[nf][r] = __expf(s[nf][r] - mrow[r]);
#pragma unroll
        for (int r = 0; r < 4; ++r) {
            float ps = s[0][r] + s[1][r] + s[2][r] + s[3][r];
            ps += __shfl_xor(ps, 1);
            ps += __shfl_xor(ps, 2);
            ps += __shfl_xor(ps, 4);
            ps += __shfl_xor(ps, 8);
            lrow[r] = lrow[r] * corr[r] + ps;
        }
#pragma unroll
        for (int nf = 0; nf < 4; ++nf)
#pragma unroll
            for (int r = 0; r < 4; ++r) o[nf][r] *= corr[r];

        // publish P (C-layout -> A-layout), same-wave rows only: no barrier
#pragma unroll
        for (int nf = 0; nf < 4; ++nf)
#pragma unroll
            for (int r = 0; r < 4; ++r)
                sm_p[(w * 16 + g4 * 4 + r) * 72 + nf * 16 + c16] = f2bf(s[nf][r]);

        // O += P @ V  (B-operand = V^T[v][t])
#pragma unroll
        for (int ks = 0; ks < 2; ++ks) {
            short8 pa = *(const short8*)&sm_p[(w * 16 + c16) * 72 + g4 * 8 + ks * 32];
#pragma unroll
            for (int nf = 0; nf < 4; ++nf) {
                short8 bv = *(const short8*)&sm_v[(nf * 16 + c16) * 72 + g4 * 8 + ks * 32];
                o[nf] = __builtin_amdgcn_mfma_f32_16x16x32_bf16(pa, bv, o[nf], 0, 0, 0);
            }
        }
    }

    __syncthreads();   // staging done — reuse sm_k/sm_v for att hi/lo

    float rs[4], invl[4];
#pragma unroll
    for (int r = 0; r < 4; ++r) {
        rs[r]   = __shfl(rowsum, (g4 << 2) + r);
        invl[r] = 1.f / lrow[r];
    }
#pragma unroll
    for (int nf = 0; nf < 4; ++nf) {
        const int col = nf * 16 + c16;
        const float Zc = Zsh[col], gc = gsh[col];
        const float izc = 1.f / Zc;
#pragma unroll
        for (int r = 0; r < 4; ++r) {
            const float adot = o[nf][r] * invl[r];
            const float amem = numf[nf][r] * izc / rs[r];
            const float res  = gc * amem + (1.f - gc) * adot;
            const unsigned short hv = f2bf(res);
            const unsigned short lv = f2bf(res - bf2f(hv));
            const int row = w * 16 + g4 * 4 + r;
            sm_k[row * 72 + col] = hv;
            sm_v[row * 72 + col] = lv;
        }
    }
    __syncthreads();
    {
        const size_t ob = base + (size_t)(qc * 64 + lr) * 64 + lc;
        *(ushort8*)(ath + ob)     = *(const ushort8*)&sm_k[lr * 72 + lc];
        *(ushort8*)(ath + ob + 8) = *(const ushort8*)&sm_k[lr * 72 + lc + 8];
        *(ushort8*)(atl + ob)     = *(const ushort8*)&sm_v[lr * 72 + lc];
        *(ushort8*)(atl + ob + 8) = *(const ushort8*)&sm_v[lr * 72 + lc + 8];
    }
}

extern "C" void kernel_launch(void* const* d_in, const int* in_sizes, int n_in,
                              void* d_out, int out_size, void* d_ws, size_t ws_size,
                              hipStream_t stream) {
    const float* x     = (const float*)d_in[0];
    const float* Wq    = (const float*)d_in[1];
    const float* Wk    = (const float*)d_in[2];
    const float* Wv    = (const float*)d_in[3];
    const float* Wout  = (const float*)d_in[4];
    const float* betas = (const float*)d_in[5];
    float* out = (float*)d_out;
    (void)d_ws; (void)ws_size;

    float *M, *z;
    unsigned short *qb, *kb, *vb, *xh, *wqkv, *vt, *ath, *atl, *woh, *wol;
    hipGetSymbolAddress((void**)&qb,   HIP_SYMBOL(g_qb));
    hipGetSymbolAddress((void**)&kb,   HIP_SYMBOL(g_kb));
    hipGetSymbolAddress((void**)&vb,   HIP_SYMBOL(g_vb));
    hipGetSymbolAddress((void**)&xh,   HIP_SYMBOL(g_xh));
    hipGetSymbolAddress((void**)&wqkv, HIP_SYMBOL(g_wqkv));
    hipGetSymbolAddress((void**)&vt,   HIP_SYMBOL(g_vt));
    hipGetSymbolAddress((void**)&ath,  HIP_SYMBOL(g_ath));
    hipGetSymbolAddress((void**)&atl,  HIP_SYMBOL(g_atl));
    hipGetSymbolAddress((void**)&woh,  HIP_SYMBOL(g_woh));
    hipGetSymbolAddress((void**)&wol,  HIP_SYMBOL(g_wol));
    hipGetSymbolAddress((void**)&M,    HIP_SYMBOL(g_M));
    hipGetSymbolAddress((void**)&z,    HIP_SYMBOL(g_z));

    const int nX = (int)NPROJ, nW = (int)NW;
    cast_bf16<<<nX / 1024, 256, 0, stream>>>(x, xh, nX);
    cast_bf16<<<nW / 1024, 256, 0, stream>>>(Wq, wqkv, nW);
    cast_bf16<<<nW / 1024, 256, 0, stream>>>(Wk, wqkv + NW, nW);
    cast_bf16<<<nW / 1024, 256, 0, stream>>>(Wv, wqkv + 2 * NW, nW);
    split_bf16<<<nW / 1024, 256, 0, stream>>>(Wout, woh, wol, nW);

    gemm_qkv8<<<dim3(768), 512, 0, stream>>>(xh, wqkv, qb, kb, vb);
    seg_stats<<<B_ * H_ * NSEG_, 256, 0, stream>>>(kb, vb, M, z, vt);
    prefix_scan<<<B_ * H_, 256, 0, stream>>>(M, z);
    attn_mfma<<<B_ * H_ * NSEG_ * 8, 256, 0, stream>>>(qb, kb, vt, M, z, betas, ath, atl);
    gemm_bt_split<<<dim3(D_ / 128, BT_ / 128), 256, 0, stream>>>(ath, atl, woh, wol, out, BT_, D_, D_);
}

// Round 2
// 559.647 us; speedup vs baseline: 1.2298x; 1.1417x over previous
//
#include <hip/hip_runtime.h>

// CompressiveMemory — round 7.
//  * Out-GEMM rebuilt as 8-phase 256x256/BK=32 split-bf16 pipeline (gemm_bt8):
//    - 4 LDS arrays (Ah/Al/Bh/Bl), 32KB each... per buffer 64KB, dbuf = 128KB.
//    - Stage units {Bh,Bl,Ah,Al} map 1:1 onto qkv8's {B0,B1,A0,A1}; identical
//      phase schedule, counted vmcnt(6) at phases 4/8, setprio around MFMA.
//    - Grid 256 blocks (= 1/CU); XCD chunk-swizzle puts the 4 column tiles of
//      each row panel on ONE XCD -> A panel fetched once, shared via L2
//      (was 8x re-fetch = 442MB; ideal 68MB).
//    - Swizzle blk ^ ((row>>1)&3) folded into global source col; LDS linear.
//    - Same BK=32 K-order and hh/lh/hl MFMA order as before: numerics
//      bit-identical to round 6.
//  * qkv8 / seg_stats / prefix / attn unchanged.

#define H_ 16
#define SEG_ 512
#define NSEG_ 16
#define B_ 2
#define T_ 8192
#define D_ 1024
#define BT_ 16384

#define NPROJ ((size_t)BT_ * D_)   // 16,777,216
#define NW ((size_t)D_ * D_)       // 1,048,576

__device__ unsigned short g_qb[NPROJ], g_kb[NPROJ], g_vb[NPROJ];   // bf16 projections
__device__ unsigned short g_xh[NPROJ];
__device__ unsigned short g_wqkv[3 * NW];                          // [Wq;Wk;Wv] bf16
__device__ unsigned short g_ath[NPROJ], g_atl[NPROJ];
__device__ unsigned short g_woh[NW], g_wol[NW];
__device__ unsigned short g_vt[(size_t)512 * 64 * 512];            // per-tile V^T bf16
__device__ float g_M[(size_t)512 * 4096];
__device__ float g_z[(size_t)512 * 64];

typedef __attribute__((ext_vector_type(8))) short short8;
typedef __attribute__((ext_vector_type(8))) unsigned short ushort8;
typedef __attribute__((ext_vector_type(4))) float f32x4;

__device__ __forceinline__ float elu1(float x) {
    return x > 0.f ? x + 1.f : __expf(x);
}
__device__ __forceinline__ unsigned short f2bf(float x) {
    unsigned u = __float_as_uint(x);
    u += 0x7fffu + ((u >> 16) & 1u);           // RNE
    return (unsigned short)(u >> 16);
}
__device__ __forceinline__ float bf2f(unsigned short h) {
    return __uint_as_float((unsigned)h << 16);
}
__device__ __forceinline__ void load_lds16(const unsigned short* g, unsigned short* l) {
    __builtin_amdgcn_global_load_lds(
        (const __attribute__((address_space(1))) unsigned int*)g,
        (__attribute__((address_space(3))) unsigned int*)l, 16, 0, 0);
}

__global__ __launch_bounds__(256) void cast_bf16(
    const float* __restrict__ in, unsigned short* __restrict__ out, int n)
{
    int i = (blockIdx.x * 256 + threadIdx.x) * 4;
    if (i >= n) return;
    float4 x = *(const float4*)(in + i);
    ushort4 h;
    h.x = f2bf(x.x); h.y = f2bf(x.y); h.z = f2bf(x.z); h.w = f2bf(x.w);
    *(ushort4*)(out + i) = h;
}

__global__ __launch_bounds__(256) void split_bf16(
    const float* __restrict__ in, unsigned short* __restrict__ hi,
    unsigned short* __restrict__ lo, int n)
{
    int i = (blockIdx.x * 256 + threadIdx.x) * 4;
    if (i >= n) return;
    float4 x = *(const float4*)(in + i);
    ushort4 h, l;
    h.x = f2bf(x.x); l.x = f2bf(x.x - bf2f(h.x));
    h.y = f2bf(x.y); l.y = f2bf(x.y - bf2f(h.y));
    h.z = f2bf(x.z); l.z = f2bf(x.z - bf2f(h.z));
    h.w = f2bf(x.w); l.w = f2bf(x.w - bf2f(h.w));
    *(ushort4*)(hi + i) = h;
    *(ushort4*)(lo + i) = l;
}

// ---------------------------------------------------------------------------
// Fused QKV GEMM, 8-phase 256x256 pipeline (unchanged from round 6).
// ---------------------------------------------------------------------------

#define VMC(N) asm volatile("s_waitcnt vmcnt(" #N ")" ::: "memory")

#define STAGE_A(p, h, tt, u) \
    load_lds16(Aw + ((h) * 128 + (u) * 8) * 1024 + (tt) * 64, \
               &lds[(p) * 32768 + ((h) * 128 + w * 16 + (u) * 8) * 64])
#define STAGE_B(p, h, tt, u) \
    load_lds16(Bww + ((h) * 128 + (u) * 8) * 1024 + (tt) * 64, \
               &lds[(p) * 32768 + 16384 + ((h) * 128 + w * 16 + (u) * 8) * 64])
#define STAGE_AH(p, h, tt) do { STAGE_A(p, h, tt, 0); STAGE_A(p, h, tt, 1); } while (0)
#define STAGE_BH(p, h, tt) do { STAGE_B(p, h, tt, 0); STAGE_B(p, h, tt, 1); } while (0)

#define LDA(PBUF, MLO) do { \
    _Pragma("unroll") for (int m2 = 0; m2 < 4; ++m2) \
    _Pragma("unroll") for (int ks2 = 0; ks2 < 2; ++ks2) \
        a[m2][ks2] = *(const short8*)&lds[(PBUF) * 32768 + aoff[ks2] + ((MLO) + m2) * 1024]; \
} while (0)

#define LDB(PBUF) do { \
    _Pragma("unroll") for (int n2 = 0; n2 < 4; ++n2) \
    _Pragma("unroll") for (int ks2 = 0; ks2 < 2; ++ks2) \
        b[n2][ks2] = *(const short8*)&lds[(PBUF) * 32768 + boff[ks2] + n2 * 1024]; \
} while (0)

#define MFMA_QUAD(MLO, NLO) do { \
    _Pragma("unroll") for (int m2 = 0; m2 < 4; ++m2) \
    _Pragma("unroll") for (int n2 = 0; n2 < 2; ++n2) \
    _Pragma("unroll") for (int ks2 = 0; ks2 < 2; ++ks2) \
        acc[(MLO) + m2][(NLO) + n2] = __builtin_amdgcn_mfma_f32_16x16x32_bf16( \
            a[m2][ks2], b[(NLO) + n2][ks2], acc[(MLO) + m2][(NLO) + n2], 0, 0, 0); \
} while (0)

#define PH(MLO, NLO) do { \
    __builtin_amdgcn_s_barrier(); \
    asm volatile("s_waitcnt lgkmcnt(0)" ::: "memory"); \
    __builtin_amdgcn_sched_barrier(0); \
    __builtin_amdgcn_s_setprio(1); \
    MFMA_QUAD(MLO, NLO); \
    __builtin_amdgcn_s_setprio(0); \
    __builtin_amdgcn_sched_barrier(0); \
    __builtin_amdgcn_s_barrier(); \
} while (0)

__global__ __launch_bounds__(512, 2) void gemm_qkv8(
    const unsigned short* __restrict__ A, const unsigned short* __restrict__ Bw,
    unsigned short* __restrict__ Q, unsigned short* __restrict__ Kp,
    unsigned short* __restrict__ V)
{
    __shared__ unsigned short lds[65536];   // 128KB: [buf0 A|B][buf1 A|B]
    const int t = threadIdx.x, lane = t & 63, w = t >> 6;
    const int wave_m = w >> 2, wave_n = w & 3;

    // XCD-bijective swizzle: 768 blocks = 96 * 8.
    const int bid = blockIdx.x;
    const int sb = (bid & 7) * 96 + (bid >> 3);
    const int mb = sb / 12, nb = sb % 12;
    const int m0 = mb * 256, n0 = nb * 256;

    // staging per-lane constants (LDS linear; swizzle folded into global col)
    const int lrow = lane >> 3;                       // 0..7
    const int lcol = ((lane & 7) ^ lrow) * 8;         // swizzled ushort col
    const unsigned short* Aw  = A  + (size_t)(m0 + w * 16 + lrow) * 1024 + lcol;
    const unsigned short* Bww = Bw + (size_t)(n0 + w * 16 + lrow) * 1024 + lcol;

    // frag-read per-lane ushort offsets (same involution as the stage side)
    const int fr = lane & 15, g4 = lane >> 4;
    int aoff[2], boff[2];
#pragma unroll
    for (int ks2 = 0; ks2 < 2; ++ks2) {
        aoff[ks2] = (wave_m * 128 + fr) * 64 + (((ks2 * 4 + g4) ^ (fr & 7)) * 8);
        boff[ks2] = 16384 + (wave_n * 64 + fr) * 64 + (((ks2 * 4 + g4) ^ (fr & 7)) * 8);
    }

    f32x4 acc[8][4];
#pragma unroll
    for (int i = 0; i < 8; ++i)
#pragma unroll
        for (int j = 0; j < 4; ++j) acc[i][j] = (f32x4)0.f;
    short8 a[4][2], b[4][2];

    // Prologue: tile0 (buf0) fully + tile1 (buf1) B0,B1,A0. vmcnt(6) -> tile0 landed.
    STAGE_BH(0, 0, 0); STAGE_BH(0, 1, 0); STAGE_AH(0, 0, 0); STAGE_AH(0, 1, 0);
    STAGE_BH(1, 0, 1); STAGE_BH(1, 1, 1); STAGE_AH(1, 0, 1);
    VMC(6);
    __builtin_amdgcn_s_barrier();

    // Main loop: 7 full iterations (tiles 0..13 computed, 2..15 prefetched).
#pragma unroll 1
    for (int it = 0; it < 7; ++it) {
        const int t1 = 2 * it + 1, t2 = 2 * it + 2, t3 = 2 * it + 3;
        LDB(0); LDA(0, 0);
        STAGE_AH(1, 1, t1);
        PH(0, 0);
        STAGE_BH(0, 0, t2);
        PH(0, 2);
        LDA(0, 4);
        STAGE_BH(0, 1, t2);
        PH(4, 0);
        STAGE_AH(0, 0, t2);
        VMC(6);
        PH(4, 2);
        LDB(1); LDA(1, 0);
        STAGE_AH(0, 1, t2);
        PH(0, 0);
        STAGE_BH(1, 0, t3);
        PH(0, 2);
        LDA(1, 4);
        STAGE_BH(1, 1, t3);
        PH(4, 0);
        STAGE_AH(1, 0, t3);
        VMC(6);
        PH(4, 2);
    }
    // Final iteration: tiles 14 (buf0) and 15 (buf1).
    LDB(0); LDA(0, 0);
    STAGE_AH(1, 1, 15);
    PH(0, 0);
    PH(0, 2);
    LDA(0, 4);
    PH(4, 0);
    VMC(0);
    PH(4, 2);
    LDB(1); LDA(1, 0);
    PH(0, 0);
    PH(0, 2);
    LDA(1, 4);
    PH(4, 0);
    PH(4, 2);

    // Epilogue: acc -> bf16 -> LDS (exactly 256x256 ushorts) -> coalesced store.
    const int ccol = lane & 15, crow = (lane >> 4) * 4;
#pragma unroll
    for (int m = 0; m < 8; ++m)
#pragma unroll
        for (int n = 0; n < 4; ++n) {
            const int row = wave_m * 128 + m * 16 + crow;
            const int col = wave_n * 64 + n * 16 + ccol;
#pragma unroll
            for (int r = 0; r < 4; ++r)
                lds[(row + r) * 256 + col] = f2bf(acc[m][n][r]);
        }
    __syncthreads();
    const int which = n0 >> 10, col0 = n0 & 1023;
    unsigned short* outp = which == 0 ? Q : (which == 1 ? Kp : V);
    const int orow = t >> 1, och = (t & 1) * 128;
    unsigned short* gp = outp + (size_t)(m0 + orow) * 1024 + col0 + och;
    const unsigned short* lp = &lds[orow * 256 + och];
#pragma unroll
    for (int u = 0; u < 128; u += 8)
        *(ushort8*)(gp + u) = *(const ushort8*)(lp + u);
}

// ---------------------------------------------------------------------------
// Out-GEMM, 8-phase 256x256/BK=32 split-bf16 pipeline.
// C[m,n] = sum_k A[m,k]*B[n,k]; M=16384, N=1024, K=1024; fp32 out.
// LDS per buffer: Ah/Al/Bh/Bl each 256x32 bf16 (16KB) = 64KB; dbuf = 128KB.
// Stage unit = one array's full 256 rows = 2 global_load_lds per wave.
// ---------------------------------------------------------------------------

#define OSTG(p, arrp, aroff, tt, u) \
    load_lds16(arrp + (size_t)(u) * 16 * 1024 + (tt) * 32, \
               &lds[(p) * 32768 + (aroff) + (w * 32 + (u) * 16) * 32])
#define OUNIT(p, arrp, aroff, tt) do { OSTG(p, arrp, aroff, tt, 0); OSTG(p, arrp, aroff, tt, 1); } while (0)

#define OLDA(PBUF, MLO) do { \
    _Pragma("unroll") for (int m2 = 0; m2 < 4; ++m2) { \
        ah[m2] = *(const short8*)&lds[(PBUF) * 32768 +         ao + ((MLO) + m2) * 512]; \
        al[m2] = *(const short8*)&lds[(PBUF) * 32768 +  8192 + ao + ((MLO) + m2) * 512]; \
    } \
} while (0)

#define OLDB(PBUF) do { \
    _Pragma("unroll") for (int n2 = 0; n2 < 4; ++n2) { \
        bh[n2] = *(const short8*)&lds[(PBUF) * 32768 + 16384 + bo + n2 * 512]; \
        bl[n2] = *(const short8*)&lds[(PBUF) * 32768 + 24576 + bo + n2 * 512]; \
    } \
} while (0)

#define OQUAD(MLO, NLO) do { \
    _Pragma("unroll") for (int m2 = 0; m2 < 4; ++m2) \
    _Pragma("unroll") for (int n2 = 0; n2 < 2; ++n2) { \
        acc[(MLO) + m2][(NLO) + n2] = __builtin_amdgcn_mfma_f32_16x16x32_bf16( \
            ah[m2], bh[(NLO) + n2], acc[(MLO) + m2][(NLO) + n2], 0, 0, 0); \
        acc[(MLO) + m2][(NLO) + n2] = __builtin_amdgcn_mfma_f32_16x16x32_bf16( \
            al[m2], bh[(NLO) + n2], acc[(MLO) + m2][(NLO) + n2], 0, 0, 0); \
        acc[(MLO) + m2][(NLO) + n2] = __builtin_amdgcn_mfma_f32_16x16x32_bf16( \
            ah[m2], bl[(NLO) + n2], acc[(MLO) + m2][(NLO) + n2], 0, 0, 0); \
    } \
} while (0)

#define OPH(MLO, NLO) do { \
    __builtin_amdgcn_s_barrier(); \
    asm volatile("s_waitcnt lgkmcnt(0)" ::: "memory"); \
    __builtin_amdgcn_sched_barrier(0); \
    __builtin_amdgcn_s_setprio(1); \
    OQUAD(MLO, NLO); \
    __builtin_amdgcn_s_setprio(0); \
    __builtin_amdgcn_sched_barrier(0); \
    __builtin_amdgcn_s_barrier(); \
} while (0)

__global__ __launch_bounds__(512, 2) void gemm_bt8(
    const unsigned short* __restrict__ Ah, const unsigned short* __restrict__ Al,
    const unsigned short* __restrict__ Bh, const unsigned short* __restrict__ Bl,
    float* __restrict__ C)
{
    __shared__ unsigned short lds[65536];   // 128KB: [buf0 Ah|Al|Bh|Bl][buf1 ...]
    const int t = threadIdx.x, lane = t & 63, w = t >> 6;
    const int wave_m = w >> 2, wave_n = w & 3;

    // XCD chunk-swizzle: 256 blocks, 32/XCD; the 4 col tiles of each row panel
    // land on the same XCD -> A panel fetched once, shared via that XCD's L2.
    const int bid = blockIdx.x;
    const int sb = (bid & 7) * 32 + (bid >> 3);
    const int m0 = (sb >> 2) * 256, n0 = (sb & 3) * 256;

    // staging per-lane constants (LDS linear; swizzle folded into global col)
    const int lrow = lane >> 2;                               // 0..15
    const int lcol = ((lane & 3) ^ ((lane >> 3) & 3)) * 8;    // blk ^ ((row>>1)&3)
    const unsigned short* Ahp = Ah + (size_t)(m0 + w * 32 + lrow) * 1024 + lcol;
    const unsigned short* Alp = Al + (size_t)(m0 + w * 32 + lrow) * 1024 + lcol;
    const unsigned short* Bhp = Bh + (size_t)(n0 + w * 32 + lrow) * 1024 + lcol;
    const unsigned short* Blp = Bl + (size_t)(n0 + w * 32 + lrow) * 1024 + lcol;

    // frag-read per-lane ushort offsets (same involution)
    const int fr = lane & 15, g4 = lane >> 4;
    const int xo = (g4 ^ ((fr >> 1) & 3)) * 8;
    const int ao = (wave_m * 128 + fr) * 32 + xo;
    const int bo = (wave_n * 64 + fr) * 32 + xo;

    f32x4 acc[8][4];
#pragma unroll
    for (int i = 0; i < 8; ++i)
#pragma unroll
        for (int j = 0; j < 4; ++j) acc[i][j] = (f32x4)0.f;
    short8 ah[4], al[4], bh[4], bl[4];

    // Prologue: tile0 (buf0) all 4 units + tile1 (buf1) Bh,Bl,Ah.
    OUNIT(0, Bhp, 16384, 0); OUNIT(0, Blp, 24576, 0); OUNIT(0, Ahp, 0, 0); OUNIT(0, Alp, 8192, 0);
    OUNIT(1, Bhp, 16384, 1); OUNIT(1, Blp, 24576, 1); OUNIT(1, Ahp, 0, 1);
    VMC(6);
    __builtin_amdgcn_s_barrier();

    // Main loop: 15 full iterations (tiles 0..29 computed, 2..31 prefetched).
#pragma unroll 1
    for (int it = 0; it < 15; ++it) {
        const int t1 = 2 * it + 1, t2 = 2 * it + 2, t3 = 2 * it + 3;
        OLDB(0); OLDA(0, 0);
        OUNIT(1, Alp, 8192, t1);
        OPH(0, 0);
        OUNIT(0, Bhp, 16384, t2);
        OPH(0, 2);
        OLDA(0, 4);
        OUNIT(0, Blp, 24576, t2);
        OPH(4, 0);
        OUNIT(0, Ahp, 0, t2);
        VMC(6);
        OPH(4, 2);
        OLDB(1); OLDA(1, 0);
        OUNIT(0, Alp, 8192, t2);
        OPH(0, 0);
        OUNIT(1, Bhp, 16384, t3);
        OPH(0, 2);
        OLDA(1, 4);
        OUNIT(1, Blp, 24576, t3);
        OPH(4, 0);
        OUNIT(1, Ahp, 0, t3);
        VMC(6);
        OPH(4, 2);
    }
    // Final iteration: tiles 30 (buf0) and 31 (buf1).
    OLDB(0); OLDA(0, 0);
    OUNIT(1, Alp, 8192, 31);
    OPH(0, 0);
    OPH(0, 2);
    OLDA(0, 4);
    OPH(4, 0);
    VMC(0);
    OPH(4, 2);
    OLDB(1); OLDA(1, 0);
    OPH(0, 0);
    OPH(0, 2);
    OLDA(1, 4);
    OPH(4, 0);
    OPH(4, 2);

    // Epilogue: fp32 C direct store (same pattern as before; write BW-bound).
    const int ccol = lane & 15, crow = (lane >> 4) * 4;
#pragma unroll
    for (int m = 0; m < 8; ++m)
#pragma unroll
        for (int n = 0; n < 4; ++n) {
            float* cp = C + (size_t)(m0 + wave_m * 128 + m * 16 + crow) * 1024
                          + (n0 + wave_n * 64 + n * 16 + ccol);
#pragma unroll
            for (int r = 0; r < 4; ++r) cp[(size_t)r * 1024] = acc[m][n][r];
        }
}

// Per (b,h,seg): M_seg[d][v], zsum[d], and V^T bf16 tile. Inputs bf16.
__global__ __launch_bounds__(256) void seg_stats(
    const unsigned short* __restrict__ kproj, const unsigned short* __restrict__ vproj,
    float* __restrict__ Mseg, float* __restrict__ zsum,
    unsigned short* __restrict__ vtg)
{
    __shared__ float ks[64][68];
    __shared__ float vs[64][68];
    const int idx = blockIdx.x;
    const int seg = idx & 15;
    const int bh  = idx >> 4;
    const int h   = bh & 15;
    const int b   = bh >> 4;
    const size_t base = ((size_t)b * T_ + (size_t)seg * SEG_ + (size_t)h * 32) * D_;
    const unsigned short* kt = kproj + base;
    const unsigned short* vt = vproj + base;
    const int t  = threadIdx.x;
    const int d0 = (t >> 4) * 4;
    const int v0 = (t & 15) * 4;
    const int lr = t >> 2;
    const int lc = (t & 3) * 16;
    float acc[4][4];
#pragma unroll
    for (int i = 0; i < 4; ++i)
#pragma unroll
        for (int j = 0; j < 4; ++j) acc[i][j] = 0.f;
    float zacc = 0.f;

    for (int c0 = 0; c0 < SEG_; c0 += 64) {
        __syncthreads();
        {
            const unsigned short* kp = kt + (size_t)(c0 + lr) * 64 + lc;
            const unsigned short* vp = vt + (size_t)(c0 + lr) * 64 + lc;
            ushort8 k0 = *(const ushort8*)kp,       k1 = *(const ushort8*)(kp + 8);
            ushort8 v0v = *(const ushort8*)vp,      v1 = *(const ushort8*)(vp + 8);
#pragma unroll
            for (int e = 0; e < 8; ++e) {
                ks[lr][lc + e]     = elu1(bf2f(k0[e]));
                ks[lr][lc + 8 + e] = elu1(bf2f(k1[e]));
                vs[lr][lc + e]     = bf2f(v0v[e]);
                vs[lr][lc + 8 + e] = bf2f(v1[e]);
            }
        }
        __syncthreads();
#pragma unroll 8
        for (int i = 0; i < 64; ++i) {
            float a0 = ks[i][d0 + 0], a1 = ks[i][d0 + 1];
            float a2 = ks[i][d0 + 2], a3 = ks[i][d0 + 3];
            float b0 = vs[i][v0 + 0], b1 = vs[i][v0 + 1];
            float b2 = vs[i][v0 + 2], b3 = vs[i][v0 + 3];
            acc[0][0] += a0 * b0; acc[0][1] += a0 * b1; acc[0][2] += a0 * b2; acc[0][3] += a0 * b3;
            acc[1][0] += a1 * b0; acc[1][1] += a1 * b1; acc[1][2] += a1 * b2; acc[1][3] += a1 * b3;
            acc[2][0] += a2 * b0; acc[2][1] += a2 * b1; acc[2][2] += a2 * b2; acc[2][3] += a2 * b3;
            acc[3][0] += a3 * b0; acc[3][1] += a3 * b1; acc[3][2] += a3 * b2; acc[3][3] += a3 * b3;
        }
        if (t < 64) {
#pragma unroll 8
            for (int i = 0; i < 64; ++i) zacc += ks[i][t];
        }
        {   // V^T bf16: row = v-dim (lr), cols = time
            ushort8 w0, w1;
#pragma unroll
            for (int i = 0; i < 8; ++i) w0[i] = f2bf(vs[lc + i][lr]);
#pragma unroll
            for (int i = 0; i < 8; ++i) w1[i] = f2bf(vs[lc + 8 + i][lr]);
            unsigned short* vo = vtg + ((size_t)idx * 64 + lr) * 512 + c0 + lc;
            *(ushort8*)vo       = w0;
            *(ushort8*)(vo + 8) = w1;
        }
    }
    float* Mout = Mseg + (size_t)idx * 4096;
#pragma unroll
    for (int i = 0; i < 4; ++i)
        *(float4*)(Mout + (size_t)(d0 + i) * 64 + v0) =
            make_float4(acc[i][0], acc[i][1], acc[i][2], acc[i][3]);
    if (t < 64) zsum[(size_t)idx * 64 + t] = zacc;
}

// Per (b,h): in-place exclusive prefix of M, inclusive prefix of z.
__global__ __launch_bounds__(256) void prefix_scan(
    float* __restrict__ M, float* __restrict__ z)
{
    const int bh = blockIdx.x;
    const int t  = threadIdx.x;
    float run[16];
#pragma unroll
    for (int u = 0; u < 16; ++u) run[u] = 0.f;
    float runz = 0.f;
    for (int seg = 0; seg < NSEG_; ++seg) {
        const size_t o = ((size_t)bh * NSEG_ + seg) * 4096 + (size_t)t * 16;
#pragma unroll
        for (int u = 0; u < 16; u += 4) {
            float4 m = *(const float4*)(M + o + u);
            *(float4*)(M + o + u) = make_float4(run[u], run[u+1], run[u+2], run[u+3]);
            run[u] += m.x; run[u+1] += m.y; run[u+2] += m.z; run[u+3] += m.w;
        }
        if (t < 64) {
            const size_t oz = ((size_t)bh * NSEG_ + seg) * 64 + t;
            runz += z[oz];
            z[oz] = runz;
        }
    }
}

// MFMA flash attention per (b,h,seg,64-row q-chunk). bf16 q/k/v inputs.
__global__ __launch_bounds__(256) void attn_mfma(
    const unsigned short* __restrict__ qproj, const unsigned short* __restrict__ kproj,
    const unsigned short* __restrict__ vtg, const float* __restrict__ memb,
    const float* __restrict__ Zaf, const float* __restrict__ betas,
    unsigned short* __restrict__ ath, unsigned short* __restrict__ atl)
{
    __shared__ unsigned short sm_k[64 * 72];   // k bf16 ; epilogue att_hi
    __shared__ unsigned short sm_v[64 * 72];   // V^T bf16 ; epilogue att_lo
    __shared__ unsigned short sm_p[64 * 72];   // mem^T bf16, then P bf16
    __shared__ float Zsh[64], gsh[64];

    const int idx  = blockIdx.x;
    const int qc   = idx & 7;
    const int rest = idx >> 3;
    const int seg  = rest & 15;
    const int bh   = rest >> 4;
    const int h    = bh & 15;
    const int b    = bh >> 4;
    const size_t base = ((size_t)b * T_ + (size_t)seg * SEG_ + (size_t)h * 32) * D_;

    const int t    = threadIdx.x;
    const int lane = t & 63;
    const int w    = t >> 6;
    const int c16  = lane & 15;
    const int g4   = lane >> 4;
    const int lr   = t >> 2;
    const int lc   = (t & 3) * 16;

    const unsigned short* qt = qproj + base + (size_t)qc * 4096;
    const unsigned short* kt = kproj + base;
    const unsigned short* vt = vtg + (size_t)rest * (64 * 512);
    const float* mb = memb + (size_t)rest * 4096;

    if (t < 64) {
        Zsh[t] = Zaf[(size_t)rest * 64 + t];
        gsh[t] = 1.f / (1.f + __expf(-betas[h * 64 + t]));
    }

    // q fragments (A-layout: m = w*16+c16, k = g4*8 + ks*32 + j), sq, rowsum
    short8 qh[2], sqh[2];
    float rowsum = 0.f;
#pragma unroll
    for (int ks = 0; ks < 2; ++ks) {
        const unsigned short* qp = qt + (size_t)(w * 16 + c16) * 64 + g4 * 8 + ks * 32;
        ushort8 qv = *(const ushort8*)qp;
        short8 qf, sf;
#pragma unroll
        for (int j = 0; j < 8; ++j) {
            float e = elu1(bf2f(qv[j]));
            rowsum += e;
            qf[j] = (short)qv[j];
            sf[j] = (short)f2bf(e);
        }
        qh[ks] = qf; sqh[ks] = sf;
    }
    rowsum += __shfl_xor(rowsum, 16);
    rowsum += __shfl_xor(rowsum, 32);

    // stage mem^T (bf16) into sm_p
    {
        const float* mp = mb + (size_t)lr * 64 + lc;
#pragma unroll
        for (int u = 0; u < 4; ++u) {
            float4 m4 = *(const float4*)(mp + u * 4);
            sm_p[(lc + u * 4 + 0) * 72 + lr] = f2bf(m4.x);
            sm_p[(lc + u * 4 + 1) * 72 + lr] = f2bf(m4.y);
            sm_p[(lc + u * 4 + 2) * 72 + lr] = f2bf(m4.z);
            sm_p[(lc + u * 4 + 3) * 72 + lr] = f2bf(m4.w);
        }
    }
    __syncthreads();

    // num = sq @ mem  (B-operand = mem^T[v][d])
    f32x4 numf[4];
#pragma unroll
    for (int nf = 0; nf < 4; ++nf) numf[nf] = (f32x4)0.f;
#pragma unroll
    for (int ks = 0; ks < 2; ++ks)
#pragma unroll
        for (int nf = 0; nf < 4; ++nf) {
            short8 bm = *(const short8*)&sm_p[(nf * 16 + c16) * 72 + g4 * 8 + ks * 32];
            numf[nf] = __builtin_amdgcn_mfma_f32_16x16x32_bf16(sqh[ks], bm, numf[nf], 0, 0, 0);
        }

    f32x4 o[4];
#pragma unroll
    for (int nf = 0; nf < 4; ++nf) o[nf] = (f32x4)0.f;
    float mrow[4] = {-1e30f, -1e30f, -1e30f, -1e30f};
    float lrow[4] = {0.f, 0.f, 0.f, 0.f};

    for (int kb = 0; kb < 8; ++kb) {
        __syncthreads();
        {   // stage k and V^T (both already bf16 — raw 16B copies)
            const unsigned short* kp = kt + (size_t)(kb * 64 + lr) * 64 + lc;
            *(ushort8*)&sm_k[lr * 72 + lc]     = *(const ushort8*)kp;
            *(ushort8*)&sm_k[lr * 72 + lc + 8] = *(const ushort8*)(kp + 8);
            const unsigned short* vp = vt + (size_t)lr * 512 + kb * 64 + lc;
            *(ushort8*)&sm_v[lr * 72 + lc]     = *(const ushort8*)vp;
            *(ushort8*)&sm_v[lr * 72 + lc + 8] = *(const ushort8*)(vp + 8);
        }
        __syncthreads();

        // scores S = Q @ K^T
        f32x4 s[4];
#pragma unroll
        for (int nf = 0; nf < 4; ++nf) s[nf] = (f32x4)0.f;
#pragma unroll
        for (int ks = 0; ks < 2; ++ks)
#pragma unroll
            for (int nf = 0; nf < 4; ++nf) {
                short8 bk = *(const short8*)&sm_k[(nf * 16 + c16) * 72 + g4 * 8 + ks * 32];
                s[nf] = __builtin_amdgcn_mfma_f32_16x16x32_bf16(qh[ks], bk, s[nf], 0, 0, 0);
            }
#pragma unroll
        for (int nf = 0; nf < 4; ++nf) s[nf] *= 0.125f;

        float corr[4];
#pragma unroll
        for (int r = 0; r < 4; ++r) {
            float mx = fmaxf(fmaxf(s[0][r], s[1][r]), fmaxf(s[2][r], s[3][r]));
            mx = fmaxf(mx, __shfl_xor(mx, 1));
            mx = fmaxf(mx, __shfl_xor(mx, 2));
            mx = fmaxf(mx, __shfl_xor(mx, 4));
            mx = fmaxf(mx, __shfl_xor(mx, 8));
            float mnew = fmaxf(mrow[r], mx);
            corr[r] = __expf(mrow[r] - mnew);
            mrow[r] = mnew;
        }
#pragma unroll
        for (int nf = 0; nf < 4; ++nf)
#pragma unroll
            for (int r = 0; r < 4; ++r)
                s[nf][r] = __expf(s[nf][r] - mrow[r]);
#pragma unroll
        for (int r = 0; r < 4; ++r) {
            float ps = s[0][r] + s[1][r] + s[2][r] + s[3][r];
            ps += __shfl_xor(ps, 1);
            ps += __shfl_xor(ps, 2);
            ps += __shfl_xor(ps, 4);
            ps += __shfl_xor(ps, 8);
            lrow[r] = lrow[r] * corr[r] + ps;
        }
#pragma unroll
        for (int nf = 0; nf < 4; ++nf)
#pragma unroll
            for (int r = 0; r < 4; ++r) o[nf][r] *= corr[r];

        // publish P (C-layout -> A-layout), same-wave rows only: no barrier
#pragma unroll
        for (int nf = 0; nf < 4; ++nf)
#pragma unroll
            for (int r = 0; r < 4; ++r)
                sm_p[(w * 16 + g4 * 4 + r) * 72 + nf * 16 + c16] = f2bf(s[nf][r]);

        // O += P @ V  (B-operand = V^T[v][t])
#pragma unroll
        for (int ks = 0; ks < 2; ++ks) {
            short8 pa = *(const short8*)&sm_p[(w * 16 + c16) * 72 + g4 * 8 + ks * 32];
#pragma unroll
            for (int nf = 0; nf < 4; ++nf) {
                short8 bv = *(const short8*)&sm_v[(nf * 16 + c16) * 72 + g4 * 8 + ks * 32];
                o[nf] = __builtin_amdgcn_mfma_f32_16x16x32_bf16(pa, bv, o[nf], 0, 0, 0);
            }
        }
    }

    __syncthreads();   // staging done — reuse sm_k/sm_v for att hi/lo

    float rs[4], invl[4];
#pragma unroll
    for (int r = 0; r < 4; ++r) {
        rs[r]   = __shfl(rowsum, (g4 << 2) + r);
        invl[r] = 1.f / lrow[r];
    }
#pragma unroll
    for (int nf = 0; nf < 4; ++nf) {
        const int col = nf * 16 + c16;
        const float Zc = Zsh[col], gc = gsh[col];
        const float izc = 1.f / Zc;
#pragma unroll
        for (int r = 0; r < 4; ++r) {
            const float adot = o[nf][r] * invl[r];
            const float amem = numf[nf][r] * izc / rs[r];
            const float res  = gc * amem + (1.f - gc) * adot;
            const unsigned short hv = f2bf(res);
            const unsigned short lv = f2bf(res - bf2f(hv));
            const int row = w * 16 + g4 * 4 + r;
            sm_k[row * 72 + col] = hv;
            sm_v[row * 72 + col] = lv;
        }
    }
    __syncthreads();
    {
        const size_t ob = base + (size_t)(qc * 64 + lr) * 64 + lc;
        *(ushort8*)(ath + ob)     = *(const ushort8*)&sm_k[lr * 72 + lc];
        *(ushort8*)(ath + ob + 8) = *(const ushort8*)&sm_k[lr * 72 + lc + 8];
        *(ushort8*)(atl + ob)     = *(const ushort8*)&sm_v[lr * 72 + lc];
        *(ushort8*)(atl + ob + 8) = *(const ushort8*)&sm_v[lr * 72 + lc + 8];
    }
}

extern "C" void kernel_launch(void* const* d_in, const int* in_sizes, int n_in,
                              void* d_out, int out_size, void* d_ws, size_t ws_size,
                              hipStream_t stream) {
    const float* x     = (const float*)d_in[0];
    const float* Wq    = (const float*)d_in[1];
    const float* Wk    = (const float*)d_in[2];
    const float* Wv    = (const float*)d_in[3];
    const float* Wout  = (const float*)d_in[4];
    const float* betas = (const float*)d_in[5];
    float* out = (float*)d_out;
    (void)d_ws; (void)ws_size;

    float *M, *z;
    unsigned short *qb, *kb, *vb, *xh, *wqkv, *vt, *ath, *atl, *woh, *wol;
    hipGetSymbolAddress((void**)&qb,   HIP_SYMBOL(g_qb));
    hipGetSymbolAddress((void**)&kb,   HIP_SYMBOL(g_kb));
    hipGetSymbolAddress((void**)&vb,   HIP_SYMBOL(g_vb));
    hipGetSymbolAddress((void**)&xh,   HIP_SYMBOL(g_xh));
    hipGetSymbolAddress((void**)&wqkv, HIP_SYMBOL(g_wqkv));
    hipGetSymbolAddress((void**)&vt,   HIP_SYMBOL(g_vt));
    hipGetSymbolAddress((void**)&ath,  HIP_SYMBOL(g_ath));
    hipGetSymbolAddress((void**)&atl,  HIP_SYMBOL(g_atl));
    hipGetSymbolAddress((void**)&woh,  HIP_SYMBOL(g_woh));
    hipGetSymbolAddress((void**)&wol,  HIP_SYMBOL(g_wol));
    hipGetSymbolAddress((void**)&M,    HIP_SYMBOL(g_M));
    hipGetSymbolAddress((void**)&z,    HIP_SYMBOL(g_z));

    const int nX = (int)NPROJ, nW = (int)NW;
    cast_bf16<<<nX / 1024, 256, 0, stream>>>(x, xh, nX);
    cast_bf16<<<nW / 1024, 256, 0, stream>>>(Wq, wqkv, nW);
    cast_bf16<<<nW / 1024, 256, 0, stream>>>(Wk, wqkv + NW, nW);
    cast_bf16<<<nW / 1024, 256, 0, stream>>>(Wv, wqkv + 2 * NW, nW);
    split_bf16<<<nW / 1024, 256, 0, stream>>>(Wout, woh, wol, nW);

    gemm_qkv8<<<dim3(768), 512, 0, stream>>>(xh, wqkv, qb, kb, vb);
    seg_stats<<<B_ * H_ * NSEG_, 256, 0, stream>>>(kb, vb, M, z, vt);
    prefix_scan<<<B_ * H_, 256, 0, stream>>>(M, z);
    attn_mfma<<<B_ * H_ * NSEG_ * 8, 256, 0, stream>>>(qb, kb, vt, M, z, betas, ath, atl);
    gemm_bt8<<<dim3(256), 512, 0, stream>>>(ath, atl, woh, wol, out);
}

// Round 3
// 512.221 us; speedup vs baseline: 1.3436x; 1.0926x over previous
//
#include <hip/hip_runtime.h>

// CompressiveMemory — round 8.
//  * attn_mfma overhaul (was 164us, MfmaUtil 9%, VALUBusy 48%, 1.2e7 bank
//    conflicts, 341MB fetch):
//    - XCD-aware bid remap: the 8 qc-blocks of one (b,h,seg) land on ONE XCD
//      within a 64-bid dispatch window (bids = g*64 + qc*8 + rest%8) ->
//      k/V^T tile fetched once per XCD and stays L2-resident (~1.5MB live).
//    - LDS stride 72 -> 64 with XOR-8-block swizzle (blk ^ (row&7)) on both
//      write and read sides: every ds_read_b128 / stage / publish hits the
//      uniform 8-access/bank floor (was 8-way conflicted).
//    - T13 ballot-deferred max: __all(partial-max <= mrow+8) over the wave
//      covers the c16 reduction lanes for free -> common path has ZERO
//      shuffles and skips corr/rescale (exp args bounded by 8).
//    - Row-sum via ones-MFMA (psum = mfma(P, 1)): kills the 16 sum-shuffles
//      per kb; denominator now consistent with the bf16 P of the numerator.
//  * qkv8 / bt8 / seg_stats / prefix unchanged (proven round 6/7).

#define H_ 16
#define SEG_ 512
#define NSEG_ 16
#define B_ 2
#define T_ 8192
#define D_ 1024
#define BT_ 16384

#define NPROJ ((size_t)BT_ * D_)   // 16,777,216
#define NW ((size_t)D_ * D_)       // 1,048,576

__device__ unsigned short g_qb[NPROJ], g_kb[NPROJ], g_vb[NPROJ];   // bf16 projections
__device__ unsigned short g_xh[NPROJ];
__device__ unsigned short g_wqkv[3 * NW];                          // [Wq;Wk;Wv] bf16
__device__ unsigned short g_ath[NPROJ], g_atl[NPROJ];
__device__ unsigned short g_woh[NW], g_wol[NW];
__device__ unsigned short g_vt[(size_t)512 * 64 * 512];            // per-tile V^T bf16
__device__ float g_M[(size_t)512 * 4096];
__device__ float g_z[(size_t)512 * 64];

typedef __attribute__((ext_vector_type(8))) short short8;
typedef __attribute__((ext_vector_type(8))) unsigned short ushort8;
typedef __attribute__((ext_vector_type(4))) float f32x4;

__device__ __forceinline__ float elu1(float x) {
    return x > 0.f ? x + 1.f : __expf(x);
}
__device__ __forceinline__ unsigned short f2bf(float x) {
    unsigned u = __float_as_uint(x);
    u += 0x7fffu + ((u >> 16) & 1u);           // RNE
    return (unsigned short)(u >> 16);
}
__device__ __forceinline__ float bf2f(unsigned short h) {
    return __uint_as_float((unsigned)h << 16);
}
__device__ __forceinline__ void load_lds16(const unsigned short* g, unsigned short* l) {
    __builtin_amdgcn_global_load_lds(
        (const __attribute__((address_space(1))) unsigned int*)g,
        (__attribute__((address_space(3))) unsigned int*)l, 16, 0, 0);
}
// ushort offset of (row, 8-ushort block blk) in a [64][64]-bf16 LDS tile,
// XOR-swizzled so column-slice b128 reads hit the uniform bank floor.
__device__ __forceinline__ int sz8(int row, int blk) {
    return row * 64 + ((blk ^ (row & 7)) << 3);
}

__global__ __launch_bounds__(256) void cast_bf16(
    const float* __restrict__ in, unsigned short* __restrict__ out, int n)
{
    int i = (blockIdx.x * 256 + threadIdx.x) * 4;
    if (i >= n) return;
    float4 x = *(const float4*)(in + i);
    ushort4 h;
    h.x = f2bf(x.x); h.y = f2bf(x.y); h.z = f2bf(x.z); h.w = f2bf(x.w);
    *(ushort4*)(out + i) = h;
}

__global__ __launch_bounds__(256) void split_bf16(
    const float* __restrict__ in, unsigned short* __restrict__ hi,
    unsigned short* __restrict__ lo, int n)
{
    int i = (blockIdx.x * 256 + threadIdx.x) * 4;
    if (i >= n) return;
    float4 x = *(const float4*)(in + i);
    ushort4 h, l;
    h.x = f2bf(x.x); l.x = f2bf(x.x - bf2f(h.x));
    h.y = f2bf(x.y); l.y = f2bf(x.y - bf2f(h.y));
    h.z = f2bf(x.z); l.z = f2bf(x.z - bf2f(h.z));
    h.w = f2bf(x.w); l.w = f2bf(x.w - bf2f(h.w));
    *(ushort4*)(hi + i) = h;
    *(ushort4*)(lo + i) = l;
}

// ---------------------------------------------------------------------------
// Fused QKV GEMM, 8-phase 256x256 pipeline (unchanged from round 6).
// ---------------------------------------------------------------------------

#define VMC(N) asm volatile("s_waitcnt vmcnt(" #N ")" ::: "memory")

#define STAGE_A(p, h, tt, u) \
    load_lds16(Aw + ((h) * 128 + (u) * 8) * 1024 + (tt) * 64, \
               &lds[(p) * 32768 + ((h) * 128 + w * 16 + (u) * 8) * 64])
#define STAGE_B(p, h, tt, u) \
    load_lds16(Bww + ((h) * 128 + (u) * 8) * 1024 + (tt) * 64, \
               &lds[(p) * 32768 + 16384 + ((h) * 128 + w * 16 + (u) * 8) * 64])
#define STAGE_AH(p, h, tt) do { STAGE_A(p, h, tt, 0); STAGE_A(p, h, tt, 1); } while (0)
#define STAGE_BH(p, h, tt) do { STAGE_B(p, h, tt, 0); STAGE_B(p, h, tt, 1); } while (0)

#define LDA(PBUF, MLO) do { \
    _Pragma("unroll") for (int m2 = 0; m2 < 4; ++m2) \
    _Pragma("unroll") for (int ks2 = 0; ks2 < 2; ++ks2) \
        a[m2][ks2] = *(const short8*)&lds[(PBUF) * 32768 + aoff[ks2] + ((MLO) + m2) * 1024]; \
} while (0)

#define LDB(PBUF) do { \
    _Pragma("unroll") for (int n2 = 0; n2 < 4; ++n2) \
    _Pragma("unroll") for (int ks2 = 0; ks2 < 2; ++ks2) \
        b[n2][ks2] = *(const short8*)&lds[(PBUF) * 32768 + boff[ks2] + n2 * 1024]; \
} while (0)

#define MFMA_QUAD(MLO, NLO) do { \
    _Pragma("unroll") for (int m2 = 0; m2 < 4; ++m2) \
    _Pragma("unroll") for (int n2 = 0; n2 < 2; ++n2) \
    _Pragma("unroll") for (int ks2 = 0; ks2 < 2; ++ks2) \
        acc[(MLO) + m2][(NLO) + n2] = __builtin_amdgcn_mfma_f32_16x16x32_bf16( \
            a[m2][ks2], b[(NLO) + n2][ks2], acc[(MLO) + m2][(NLO) + n2], 0, 0, 0); \
} while (0)

#define PH(MLO, NLO) do { \
    __builtin_amdgcn_s_barrier(); \
    asm volatile("s_waitcnt lgkmcnt(0)" ::: "memory"); \
    __builtin_amdgcn_sched_barrier(0); \
    __builtin_amdgcn_s_setprio(1); \
    MFMA_QUAD(MLO, NLO); \
    __builtin_amdgcn_s_setprio(0); \
    __builtin_amdgcn_sched_barrier(0); \
    __builtin_amdgcn_s_barrier(); \
} while (0)

__global__ __launch_bounds__(512, 2) void gemm_qkv8(
    const unsigned short* __restrict__ A, const unsigned short* __restrict__ Bw,
    unsigned short* __restrict__ Q, unsigned short* __restrict__ Kp,
    unsigned short* __restrict__ V)
{
    __shared__ unsigned short lds[65536];   // 128KB: [buf0 A|B][buf1 A|B]
    const int t = threadIdx.x, lane = t & 63, w = t >> 6;
    const int wave_m = w >> 2, wave_n = w & 3;

    // XCD-bijective swizzle: 768 blocks = 96 * 8.
    const int bid = blockIdx.x;
    const int sb = (bid & 7) * 96 + (bid >> 3);
    const int mb = sb / 12, nb = sb % 12;
    const int m0 = mb * 256, n0 = nb * 256;

    // staging per-lane constants (LDS linear; swizzle folded into global col)
    const int lrow = lane >> 3;                       // 0..7
    const int lcol = ((lane & 7) ^ lrow) * 8;         // swizzled ushort col
    const unsigned short* Aw  = A  + (size_t)(m0 + w * 16 + lrow) * 1024 + lcol;
    const unsigned short* Bww = Bw + (size_t)(n0 + w * 16 + lrow) * 1024 + lcol;

    // frag-read per-lane ushort offsets (same involution as the stage side)
    const int fr = lane & 15, g4 = lane >> 4;
    int aoff[2], boff[2];
#pragma unroll
    for (int ks2 = 0; ks2 < 2; ++ks2) {
        aoff[ks2] = (wave_m * 128 + fr) * 64 + (((ks2 * 4 + g4) ^ (fr & 7)) * 8);
        boff[ks2] = 16384 + (wave_n * 64 + fr) * 64 + (((ks2 * 4 + g4) ^ (fr & 7)) * 8);
    }

    f32x4 acc[8][4];
#pragma unroll
    for (int i = 0; i < 8; ++i)
#pragma unroll
        for (int j = 0; j < 4; ++j) acc[i][j] = (f32x4)0.f;
    short8 a[4][2], b[4][2];

    // Prologue: tile0 (buf0) fully + tile1 (buf1) B0,B1,A0. vmcnt(6) -> tile0 landed.
    STAGE_BH(0, 0, 0); STAGE_BH(0, 1, 0); STAGE_AH(0, 0, 0); STAGE_AH(0, 1, 0);
    STAGE_BH(1, 0, 1); STAGE_BH(1, 1, 1); STAGE_AH(1, 0, 1);
    VMC(6);
    __builtin_amdgcn_s_barrier();

#pragma unroll 1
    for (int it = 0; it < 7; ++it) {
        const int t1 = 2 * it + 1, t2 = 2 * it + 2, t3 = 2 * it + 3;
        LDB(0); LDA(0, 0);
        STAGE_AH(1, 1, t1);
        PH(0, 0);
        STAGE_BH(0, 0, t2);
        PH(0, 2);
        LDA(0, 4);
        STAGE_BH(0, 1, t2);
        PH(4, 0);
        STAGE_AH(0, 0, t2);
        VMC(6);
        PH(4, 2);
        LDB(1); LDA(1, 0);
        STAGE_AH(0, 1, t2);
        PH(0, 0);
        STAGE_BH(1, 0, t3);
        PH(0, 2);
        LDA(1, 4);
        STAGE_BH(1, 1, t3);
        PH(4, 0);
        STAGE_AH(1, 0, t3);
        VMC(6);
        PH(4, 2);
    }
    LDB(0); LDA(0, 0);
    STAGE_AH(1, 1, 15);
    PH(0, 0);
    PH(0, 2);
    LDA(0, 4);
    PH(4, 0);
    VMC(0);
    PH(4, 2);
    LDB(1); LDA(1, 0);
    PH(0, 0);
    PH(0, 2);
    LDA(1, 4);
    PH(4, 0);
    PH(4, 2);

    // Epilogue: acc -> bf16 -> LDS (exactly 256x256 ushorts) -> coalesced store.
    const int ccol = lane & 15, crow = (lane >> 4) * 4;
#pragma unroll
    for (int m = 0; m < 8; ++m)
#pragma unroll
        for (int n = 0; n < 4; ++n) {
            const int row = wave_m * 128 + m * 16 + crow;
            const int col = wave_n * 64 + n * 16 + ccol;
#pragma unroll
            for (int r = 0; r < 4; ++r)
                lds[(row + r) * 256 + col] = f2bf(acc[m][n][r]);
        }
    __syncthreads();
    const int which = n0 >> 10, col0 = n0 & 1023;
    unsigned short* outp = which == 0 ? Q : (which == 1 ? Kp : V);
    const int orow = t >> 1, och = (t & 1) * 128;
    unsigned short* gp = outp + (size_t)(m0 + orow) * 1024 + col0 + och;
    const unsigned short* lp = &lds[orow * 256 + och];
#pragma unroll
    for (int u = 0; u < 128; u += 8)
        *(ushort8*)(gp + u) = *(const ushort8*)(lp + u);
}

// ---------------------------------------------------------------------------
// Out-GEMM, 8-phase 256x256/BK=32 split-bf16 pipeline (unchanged, round 7).
// ---------------------------------------------------------------------------

#define OSTG(p, arrp, aroff, tt, u) \
    load_lds16(arrp + (size_t)(u) * 16 * 1024 + (tt) * 32, \
               &lds[(p) * 32768 + (aroff) + (w * 32 + (u) * 16) * 32])
#define OUNIT(p, arrp, aroff, tt) do { OSTG(p, arrp, aroff, tt, 0); OSTG(p, arrp, aroff, tt, 1); } while (0)

#define OLDA(PBUF, MLO) do { \
    _Pragma("unroll") for (int m2 = 0; m2 < 4; ++m2) { \
        ah[m2] = *(const short8*)&lds[(PBUF) * 32768 +         ao + ((MLO) + m2) * 512]; \
        al[m2] = *(const short8*)&lds[(PBUF) * 32768 +  8192 + ao + ((MLO) + m2) * 512]; \
    } \
} while (0)

#define OLDB(PBUF) do { \
    _Pragma("unroll") for (int n2 = 0; n2 < 4; ++n2) { \
        bh[n2] = *(const short8*)&lds[(PBUF) * 32768 + 16384 + bo + n2 * 512]; \
        bl[n2] = *(const short8*)&lds[(PBUF) * 32768 + 24576 + bo + n2 * 512]; \
    } \
} while (0)

#define OQUAD(MLO, NLO) do { \
    _Pragma("unroll") for (int m2 = 0; m2 < 4; ++m2) \
    _Pragma("unroll") for (int n2 = 0; n2 < 2; ++n2) { \
        acc[(MLO) + m2][(NLO) + n2] = __builtin_amdgcn_mfma_f32_16x16x32_bf16( \
            ah[m2], bh[(NLO) + n2], acc[(MLO) + m2][(NLO) + n2], 0, 0, 0); \
        acc[(MLO) + m2][(NLO) + n2] = __builtin_amdgcn_mfma_f32_16x16x32_bf16( \
            al[m2], bh[(NLO) + n2], acc[(MLO) + m2][(NLO) + n2], 0, 0, 0); \
        acc[(MLO) + m2][(NLO) + n2] = __builtin_amdgcn_mfma_f32_16x16x32_bf16( \
            ah[m2], bl[(NLO) + n2], acc[(MLO) + m2][(NLO) + n2], 0, 0, 0); \
    } \
} while (0)

#define OPH(MLO, NLO) do { \
    __builtin_amdgcn_s_barrier(); \
    asm volatile("s_waitcnt lgkmcnt(0)" ::: "memory"); \
    __builtin_amdgcn_sched_barrier(0); \
    __builtin_amdgcn_s_setprio(1); \
    OQUAD(MLO, NLO); \
    __builtin_amdgcn_s_setprio(0); \
    __builtin_amdgcn_sched_barrier(0); \
    __builtin_amdgcn_s_barrier(); \
} while (0)

__global__ __launch_bounds__(512, 2) void gemm_bt8(
    const unsigned short* __restrict__ Ah, const unsigned short* __restrict__ Al,
    const unsigned short* __restrict__ Bh, const unsigned short* __restrict__ Bl,
    float* __restrict__ C)
{
    __shared__ unsigned short lds[65536];   // 128KB: [buf0 Ah|Al|Bh|Bl][buf1 ...]
    const int t = threadIdx.x, lane = t & 63, w = t >> 6;
    const int wave_m = w >> 2, wave_n = w & 3;

    const int bid = blockIdx.x;
    const int sb = (bid & 7) * 32 + (bid >> 3);
    const int m0 = (sb >> 2) * 256, n0 = (sb & 3) * 256;

    const int lrow = lane >> 2;                               // 0..15
    const int lcol = ((lane & 3) ^ ((lane >> 3) & 3)) * 8;    // blk ^ ((row>>1)&3)
    const unsigned short* Ahp = Ah + (size_t)(m0 + w * 32 + lrow) * 1024 + lcol;
    const unsigned short* Alp = Al + (size_t)(m0 + w * 32 + lrow) * 1024 + lcol;
    const unsigned short* Bhp = Bh + (size_t)(n0 + w * 32 + lrow) * 1024 + lcol;
    const unsigned short* Blp = Bl + (size_t)(n0 + w * 32 + lrow) * 1024 + lcol;

    const int fr = lane & 15, g4 = lane >> 4;
    const int xo = (g4 ^ ((fr >> 1) & 3)) * 8;
    const int ao = (wave_m * 128 + fr) * 32 + xo;
    const int bo = (wave_n * 64 + fr) * 32 + xo;

    f32x4 acc[8][4];
#pragma unroll
    for (int i = 0; i < 8; ++i)
#pragma unroll
        for (int j = 0; j < 4; ++j) acc[i][j] = (f32x4)0.f;
    short8 ah[4], al[4], bh[4], bl[4];

    OUNIT(0, Bhp, 16384, 0); OUNIT(0, Blp, 24576, 0); OUNIT(0, Ahp, 0, 0); OUNIT(0, Alp, 8192, 0);
    OUNIT(1, Bhp, 16384, 1); OUNIT(1, Blp, 24576, 1); OUNIT(1, Ahp, 0, 1);
    VMC(6);
    __builtin_amdgcn_s_barrier();

#pragma unroll 1
    for (int it = 0; it < 15; ++it) {
        const int t1 = 2 * it + 1, t2 = 2 * it + 2, t3 = 2 * it + 3;
        OLDB(0); OLDA(0, 0);
        OUNIT(1, Alp, 8192, t1);
        OPH(0, 0);
        OUNIT(0, Bhp, 16384, t2);
        OPH(0, 2);
        OLDA(0, 4);
        OUNIT(0, Blp, 24576, t2);
        OPH(4, 0);
        OUNIT(0, Ahp, 0, t2);
        VMC(6);
        OPH(4, 2);
        OLDB(1); OLDA(1, 0);
        OUNIT(0, Alp, 8192, t2);
        OPH(0, 0);
        OUNIT(1, Bhp, 16384, t3);
        OPH(0, 2);
        OLDA(1, 4);
        OUNIT(1, Blp, 24576, t3);
        OPH(4, 0);
        OUNIT(1, Ahp, 0, t3);
        VMC(6);
        OPH(4, 2);
    }
    OLDB(0); OLDA(0, 0);
    OUNIT(1, Alp, 8192, 31);
    OPH(0, 0);
    OPH(0, 2);
    OLDA(0, 4);
    OPH(4, 0);
    VMC(0);
    OPH(4, 2);
    OLDB(1); OLDA(1, 0);
    OPH(0, 0);
    OPH(0, 2);
    OLDA(1, 4);
    OPH(4, 0);
    OPH(4, 2);

    const int ccol = lane & 15, crow = (lane >> 4) * 4;
#pragma unroll
    for (int m = 0; m < 8; ++m)
#pragma unroll
        for (int n = 0; n < 4; ++n) {
            float* cp = C + (size_t)(m0 + wave_m * 128 + m * 16 + crow) * 1024
                          + (n0 + wave_n * 64 + n * 16 + ccol);
#pragma unroll
            for (int r = 0; r < 4; ++r) cp[(size_t)r * 1024] = acc[m][n][r];
        }
}

// Per (b,h,seg): M_seg[d][v], zsum[d], and V^T bf16 tile. Inputs bf16.
__global__ __launch_bounds__(256) void seg_stats(
    const unsigned short* __restrict__ kproj, const unsigned short* __restrict__ vproj,
    float* __restrict__ Mseg, float* __restrict__ zsum,
    unsigned short* __restrict__ vtg)
{
    __shared__ float ks[64][68];
    __shared__ float vs[64][68];
    const int idx = blockIdx.x;
    const int seg = idx & 15;
    const int bh  = idx >> 4;
    const int h   = bh & 15;
    const int b   = bh >> 4;
    const size_t base = ((size_t)b * T_ + (size_t)seg * SEG_ + (size_t)h * 32) * D_;
    const unsigned short* kt = kproj + base;
    const unsigned short* vt = vproj + base;
    const int t  = threadIdx.x;
    const int d0 = (t >> 4) * 4;
    const int v0 = (t & 15) * 4;
    const int lr = t >> 2;
    const int lc = (t & 3) * 16;
    float acc[4][4];
#pragma unroll
    for (int i = 0; i < 4; ++i)
#pragma unroll
        for (int j = 0; j < 4; ++j) acc[i][j] = 0.f;
    float zacc = 0.f;

    for (int c0 = 0; c0 < SEG_; c0 += 64) {
        __syncthreads();
        {
            const unsigned short* kp = kt + (size_t)(c0 + lr) * 64 + lc;
            const unsigned short* vp = vt + (size_t)(c0 + lr) * 64 + lc;
            ushort8 k0 = *(const ushort8*)kp,       k1 = *(const ushort8*)(kp + 8);
            ushort8 v0v = *(const ushort8*)vp,      v1 = *(const ushort8*)(vp + 8);
#pragma unroll
            for (int e = 0; e < 8; ++e) {
                ks[lr][lc + e]     = elu1(bf2f(k0[e]));
                ks[lr][lc + 8 + e] = elu1(bf2f(k1[e]));
                vs[lr][lc + e]     = bf2f(v0v[e]);
                vs[lr][lc + 8 + e] = bf2f(v1[e]);
            }
        }
        __syncthreads();
#pragma unroll 8
        for (int i = 0; i < 64; ++i) {
            float a0 = ks[i][d0 + 0], a1 = ks[i][d0 + 1];
            float a2 = ks[i][d0 + 2], a3 = ks[i][d0 + 3];
            float b0 = vs[i][v0 + 0], b1 = vs[i][v0 + 1];
            float b2 = vs[i][v0 + 2], b3 = vs[i][v0 + 3];
            acc[0][0] += a0 * b0; acc[0][1] += a0 * b1; acc[0][2] += a0 * b2; acc[0][3] += a0 * b3;
            acc[1][0] += a1 * b0; acc[1][1] += a1 * b1; acc[1][2] += a1 * b2; acc[1][3] += a1 * b3;
            acc[2][0] += a2 * b0; acc[2][1] += a2 * b1; acc[2][2] += a2 * b2; acc[2][3] += a2 * b3;
            acc[3][0] += a3 * b0; acc[3][1] += a3 * b1; acc[3][2] += a3 * b2; acc[3][3] += a3 * b3;
        }
        if (t < 64) {
#pragma unroll 8
            for (int i = 0; i < 64; ++i) zacc += ks[i][t];
        }
        {   // V^T bf16: row = v-dim (lr), cols = time
            ushort8 w0, w1;
#pragma unroll
            for (int i = 0; i < 8; ++i) w0[i] = f2bf(vs[lc + i][lr]);
#pragma unroll
            for (int i = 0; i < 8; ++i) w1[i] = f2bf(vs[lc + 8 + i][lr]);
            unsigned short* vo = vtg + ((size_t)idx * 64 + lr) * 512 + c0 + lc;
            *(ushort8*)vo       = w0;
            *(ushort8*)(vo + 8) = w1;
        }
    }
    float* Mout = Mseg + (size_t)idx * 4096;
#pragma unroll
    for (int i = 0; i < 4; ++i)
        *(float4*)(Mout + (size_t)(d0 + i) * 64 + v0) =
            make_float4(acc[i][0], acc[i][1], acc[i][2], acc[i][3]);
    if (t < 64) zsum[(size_t)idx * 64 + t] = zacc;
}

// Per (b,h): in-place exclusive prefix of M, inclusive prefix of z.
__global__ __launch_bounds__(256) void prefix_scan(
    float* __restrict__ M, float* __restrict__ z)
{
    const int bh = blockIdx.x;
    const int t  = threadIdx.x;
    float run[16];
#pragma unroll
    for (int u = 0; u < 16; ++u) run[u] = 0.f;
    float runz = 0.f;
    for (int seg = 0; seg < NSEG_; ++seg) {
        const size_t o = ((size_t)bh * NSEG_ + seg) * 4096 + (size_t)t * 16;
#pragma unroll
        for (int u = 0; u < 16; u += 4) {
            float4 m = *(const float4*)(M + o + u);
            *(float4*)(M + o + u) = make_float4(run[u], run[u+1], run[u+2], run[u+3]);
            run[u] += m.x; run[u+1] += m.y; run[u+2] += m.z; run[u+3] += m.w;
        }
        if (t < 64) {
            const size_t oz = ((size_t)bh * NSEG_ + seg) * 64 + t;
            runz += z[oz];
            z[oz] = runz;
        }
    }
}

// MFMA flash attention per (b,h,seg,64-row q-chunk). bf16 q/k/v inputs.
__global__ __launch_bounds__(256) void attn_mfma(
    const unsigned short* __restrict__ qproj, const unsigned short* __restrict__ kproj,
    const unsigned short* __restrict__ vtg, const float* __restrict__ memb,
    const float* __restrict__ Zaf, const float* __restrict__ betas,
    unsigned short* __restrict__ ath, unsigned short* __restrict__ atl)
{
    __shared__ unsigned short sm_k[64 * 64];   // k bf16 ; epilogue att_hi (swizzled)
    __shared__ unsigned short sm_v[64 * 64];   // V^T bf16 ; epilogue att_lo (swizzled)
    __shared__ unsigned short sm_p[64 * 64];   // mem^T bf16, then P bf16 (swizzled)
    __shared__ float Zsh[64], gsh[64];

    const int idx  = blockIdx.x;
    // XCD-aware remap: bids g*64 + qc*8 + x -> rest = g*8 + x, so one rest's
    // 8 qc-blocks share bid%8 (same XCD) inside a 64-bid window (co-resident).
    const int qc   = (idx >> 3) & 7;
    const int rest = (idx >> 6) * 8 + (idx & 7);
    const int bh   = rest >> 4;
    const int seg  = rest & 15;
    const int h    = bh & 15;
    const int b    = bh >> 4;
    const size_t base = ((size_t)b * T_ + (size_t)seg * SEG_ + (size_t)h * 32) * D_;

    const int t    = threadIdx.x;
    const int lane = t & 63;
    const int w    = t >> 6;
    const int c16  = lane & 15;
    const int g4   = lane >> 4;
    const int lr   = t >> 2;
    const int lc   = (t & 3) * 16;

    const unsigned short* qt = qproj + base + (size_t)qc * 4096;
    const unsigned short* kt = kproj + base;
    const unsigned short* vt = vtg + (size_t)rest * (64 * 512);
    const float* mb = memb + (size_t)rest * 4096;

    if (t < 64) {
        Zsh[t] = Zaf[(size_t)rest * 64 + t];
        gsh[t] = 1.f / (1.f + __expf(-betas[h * 64 + t]));
    }

    // q fragments (A-layout: m = w*16+c16, k = g4*8 + ks*32 + j), sq, rowsum
    short8 qh[2], sqh[2];
    float rowsum = 0.f;
#pragma unroll
    for (int ks = 0; ks < 2; ++ks) {
        const unsigned short* qp = qt + (size_t)(w * 16 + c16) * 64 + g4 * 8 + ks * 32;
        ushort8 qv = *(const ushort8*)qp;
        short8 qf, sf;
#pragma unroll
        for (int j = 0; j < 8; ++j) {
            float e = elu1(bf2f(qv[j]));
            rowsum += e;
            qf[j] = (short)qv[j];
            sf[j] = (short)f2bf(e);
        }
        qh[ks] = qf; sqh[ks] = sf;
    }
    rowsum += __shfl_xor(rowsum, 16);
    rowsum += __shfl_xor(rowsum, 32);

    // stage mem^T (bf16) into sm_p (swizzled scalar writes)
    {
        const float* mp = mb + (size_t)lr * 64 + lc;
#pragma unroll
        for (int u = 0; u < 4; ++u) {
            float4 m4 = *(const float4*)(mp + u * 4);
            sm_p[sz8(lc + u * 4 + 0, lr >> 3) + (lr & 7)] = f2bf(m4.x);
            sm_p[sz8(lc + u * 4 + 1, lr >> 3) + (lr & 7)] = f2bf(m4.y);
            sm_p[sz8(lc + u * 4 + 2, lr >> 3) + (lr & 7)] = f2bf(m4.z);
            sm_p[sz8(lc + u * 4 + 3, lr >> 3) + (lr & 7)] = f2bf(m4.w);
        }
    }
    __syncthreads();

    // num = sq @ mem  (B-operand = mem^T[v][d])
    f32x4 numf[4];
#pragma unroll
    for (int nf = 0; nf < 4; ++nf) numf[nf] = (f32x4)0.f;
#pragma unroll
    for (int ks = 0; ks < 2; ++ks)
#pragma unroll
        for (int nf = 0; nf < 4; ++nf) {
            short8 bm = *(const short8*)&sm_p[sz8(nf * 16 + c16, g4 + ks * 4)];
            numf[nf] = __builtin_amdgcn_mfma_f32_16x16x32_bf16(sqh[ks], bm, numf[nf], 0, 0, 0);
        }

    // ones B-frag (bf16 1.0) for row-sum-via-MFMA
    short8 bones;
#pragma unroll
    for (int j = 0; j < 8; ++j) bones[j] = (short)0x3F80;

    f32x4 o[4];
#pragma unroll
    for (int nf = 0; nf < 4; ++nf) o[nf] = (f32x4)0.f;
    float mrow[4] = {-1e30f, -1e30f, -1e30f, -1e30f};
    float lrow[4] = {0.f, 0.f, 0.f, 0.f};

    for (int kb = 0; kb < 8; ++kb) {
        __syncthreads();
        {   // stage k and V^T (both already bf16 — swizzled 16B copies)
            const unsigned short* kp = kt + (size_t)(kb * 64 + lr) * 64 + lc;
            *(ushort8*)&sm_k[sz8(lr, lc >> 3)]       = *(const ushort8*)kp;
            *(ushort8*)&sm_k[sz8(lr, (lc >> 3) + 1)] = *(const ushort8*)(kp + 8);
            const unsigned short* vp = vt + (size_t)lr * 512 + kb * 64 + lc;
            *(ushort8*)&sm_v[sz8(lr, lc >> 3)]       = *(const ushort8*)vp;
            *(ushort8*)&sm_v[sz8(lr, (lc >> 3) + 1)] = *(const ushort8*)(vp + 8);
        }
        __syncthreads();

        // scores S = Q @ K^T
        f32x4 s[4];
#pragma unroll
        for (int nf = 0; nf < 4; ++nf) s[nf] = (f32x4)0.f;
#pragma unroll
        for (int ks = 0; ks < 2; ++ks)
#pragma unroll
            for (int nf = 0; nf < 4; ++nf) {
                short8 bk = *(const short8*)&sm_k[sz8(nf * 16 + c16, g4 + ks * 4)];
                s[nf] = __builtin_amdgcn_mfma_f32_16x16x32_bf16(qh[ks], bk, s[nf], 0, 0, 0);
            }
#pragma unroll
        for (int nf = 0; nf < 4; ++nf) s[nf] *= 0.125f;

        // T13 deferred max: wave-wide __all over per-lane partial maxima
        // covers the c16 reduction lanes for free. Common path: no shuffles,
        // no corr, no rescale (exp args bounded by THR=8).
        float pmax[4];
#pragma unroll
        for (int r = 0; r < 4; ++r)
            pmax[r] = fmaxf(fmaxf(s[0][r], s[1][r]), fmaxf(s[2][r], s[3][r]));
        const bool ok = pmax[0] <= mrow[0] + 8.f && pmax[1] <= mrow[1] + 8.f &&
                        pmax[2] <= mrow[2] + 8.f && pmax[3] <= mrow[3] + 8.f;
        if (!__all(ok)) {
#pragma unroll
            for (int r = 0; r < 4; ++r) {
                float mx = pmax[r];
                mx = fmaxf(mx, __shfl_xor(mx, 1));
                mx = fmaxf(mx, __shfl_xor(mx, 2));
                mx = fmaxf(mx, __shfl_xor(mx, 4));
                mx = fmaxf(mx, __shfl_xor(mx, 8));
                const float mnew = fmaxf(mrow[r], mx);
                const float corr = __expf(mrow[r] - mnew);
                mrow[r] = mnew;
                lrow[r] *= corr;
#pragma unroll
                for (int nf = 0; nf < 4; ++nf) o[nf][r] *= corr;
            }
        }
#pragma unroll
        for (int nf = 0; nf < 4; ++nf)
#pragma unroll
            for (int r = 0; r < 4; ++r) {
                s[nf][r] = __expf(s[nf][r] - mrow[r]);
                // publish P (C-layout -> A-layout), same-wave rows only
                sm_p[sz8(w * 16 + g4 * 4 + r, nf * 2 + (c16 >> 3)) + (c16 & 7)] =
                    f2bf(s[nf][r]);
            }

        // O += P @ V ; row-sum via ones-MFMA (denominator from the same bf16 P)
        f32x4 psum = (f32x4)0.f;
#pragma unroll
        for (int ks = 0; ks < 2; ++ks) {
            short8 pa = *(const short8*)&sm_p[sz8(w * 16 + c16, g4 + ks * 4)];
            psum = __builtin_amdgcn_mfma_f32_16x16x32_bf16(pa, bones, psum, 0, 0, 0);
#pragma unroll
            for (int nf = 0; nf < 4; ++nf) {
                short8 bv = *(const short8*)&sm_v[sz8(nf * 16 + c16, g4 + ks * 4)];
                o[nf] = __builtin_amdgcn_mfma_f32_16x16x32_bf16(pa, bv, o[nf], 0, 0, 0);
            }
        }
#pragma unroll
        for (int r = 0; r < 4; ++r) lrow[r] += psum[r];
    }

    __syncthreads();   // staging done — reuse sm_k/sm_v for att hi/lo

    float rs[4], invl[4];
#pragma unroll
    for (int r = 0; r < 4; ++r) {
        rs[r]   = __shfl(rowsum, (g4 << 2) + r);
        invl[r] = 1.f / lrow[r];
    }
#pragma unroll
    for (int nf = 0; nf < 4; ++nf) {
        const int col = nf * 16 + c16;
        const float Zc = Zsh[col], gc = gsh[col];
        const float izc = 1.f / Zc;
#pragma unroll
        for (int r = 0; r < 4; ++r) {
            const float adot = o[nf][r] * invl[r];
            const float amem = numf[nf][r] * izc / rs[r];
            const float res  = gc * amem + (1.f - gc) * adot;
            const unsigned short hv = f2bf(res);
            const unsigned short lv = f2bf(res - bf2f(hv));
            const int row = w * 16 + g4 * 4 + r;
            const int so  = sz8(row, nf * 2 + (c16 >> 3)) + (c16 & 7);
            sm_k[so] = hv;
            sm_v[so] = lv;
        }
    }
    __syncthreads();
    {
        const size_t ob = base + (size_t)(qc * 64 + lr) * 64 + lc;
        *(ushort8*)(ath + ob)     = *(const ushort8*)&sm_k[sz8(lr, lc >> 3)];
        *(ushort8*)(ath + ob + 8) = *(const ushort8*)&sm_k[sz8(lr, (lc >> 3) + 1)];
        *(ushort8*)(atl + ob)     = *(const ushort8*)&sm_v[sz8(lr, lc >> 3)];
        *(ushort8*)(atl + ob + 8) = *(const ushort8*)&sm_v[sz8(lr, (lc >> 3) + 1)];
    }
}

extern "C" void kernel_launch(void* const* d_in, const int* in_sizes, int n_in,
                              void* d_out, int out_size, void* d_ws, size_t ws_size,
                              hipStream_t stream) {
    const float* x     = (const float*)d_in[0];
    const float* Wq    = (const float*)d_in[1];
    const float* Wk    = (const float*)d_in[2];
    const float* Wv    = (const float*)d_in[3];
    const float* Wout  = (const float*)d_in[4];
    const float* betas = (const float*)d_in[5];
    float* out = (float*)d_out;
    (void)d_ws; (void)ws_size;

    float *M, *z;
    unsigned short *qb, *kb, *vb, *xh, *wqkv, *vt, *ath, *atl, *woh, *wol;
    hipGetSymbolAddress((void**)&qb,   HIP_SYMBOL(g_qb));
    hipGetSymbolAddress((void**)&kb,   HIP_SYMBOL(g_kb));
    hipGetSymbolAddress((void**)&vb,   HIP_SYMBOL(g_vb));
    hipGetSymbolAddress((void**)&xh,   HIP_SYMBOL(g_xh));
    hipGetSymbolAddress((void**)&wqkv, HIP_SYMBOL(g_wqkv));
    hipGetSymbolAddress((void**)&vt,   HIP_SYMBOL(g_vt));
    hipGetSymbolAddress((void**)&ath,  HIP_SYMBOL(g_ath));
    hipGetSymbolAddress((void**)&atl,  HIP_SYMBOL(g_atl));
    hipGetSymbolAddress((void**)&woh,  HIP_SYMBOL(g_woh));
    hipGetSymbolAddress((void**)&wol,  HIP_SYMBOL(g_wol));
    hipGetSymbolAddress((void**)&M,    HIP_SYMBOL(g_M));
    hipGetSymbolAddress((void**)&z,    HIP_SYMBOL(g_z));

    const int nX = (int)NPROJ, nW = (int)NW;
    cast_bf16<<<nX / 1024, 256, 0, stream>>>(x, xh, nX);
    cast_bf16<<<nW / 1024, 256, 0, stream>>>(Wq, wqkv, nW);
    cast_bf16<<<nW / 1024, 256, 0, stream>>>(Wk, wqkv + NW, nW);
    cast_bf16<<<nW / 1024, 256, 0, stream>>>(Wv, wqkv + 2 * NW, nW);
    split_bf16<<<nW / 1024, 256, 0, stream>>>(Wout, woh, wol, nW);

    gemm_qkv8<<<dim3(768), 512, 0, stream>>>(xh, wqkv, qb, kb, vb);
    seg_stats<<<B_ * H_ * NSEG_, 256, 0, stream>>>(kb, vb, M, z, vt);
    prefix_scan<<<B_ * H_, 256, 0, stream>>>(M, z);
    attn_mfma<<<B_ * H_ * NSEG_ * 8, 256, 0, stream>>>(qb, kb, vt, M, z, betas, ath, atl);
    gemm_bt8<<<dim3(256), 512, 0, stream>>>(ath, atl, woh, wol, out);
}

// Round 4
// 502.370 us; speedup vs baseline: 1.3700x; 1.0196x over previous
//
#include <hip/hip_runtime.h>

// CompressiveMemory — round 9.
//  * qkv8 epilogue LDS conflict fix: the 256x256 transpose buffer has 512B
//    row stride (== 0 mod 128B), so readback put all 64 lanes on ONE 4-bank
//    group (64-way) and the bf16 scatter writes were 8-way. XOR the 16B-block
//    index with row&31 on both sides (bijective per row) -> reads 8 distinct
//    groups/instr, writes ~4-way. Bit-exact data movement.
//  * prefix_scan widened 32 -> 128 blocks (4 independent 1024-float slices
//    per (b,h); z handled by slice 0). Bit-identical.
//  * 5 prologue cast/split launches fused into one prep kernel (fewer
//    dispatch gaps). Bit-identical.
//  * qkv8 main loop / bt8 / seg_stats / attn unchanged (proven rounds 6-8).

#define H_ 16
#define SEG_ 512
#define NSEG_ 16
#define B_ 2
#define T_ 8192
#define D_ 1024
#define BT_ 16384

#define NPROJ ((size_t)BT_ * D_)   // 16,777,216
#define NW ((size_t)D_ * D_)       // 1,048,576

__device__ unsigned short g_qb[NPROJ], g_kb[NPROJ], g_vb[NPROJ];   // bf16 projections
__device__ unsigned short g_xh[NPROJ];
__device__ unsigned short g_wqkv[3 * NW];                          // [Wq;Wk;Wv] bf16
__device__ unsigned short g_ath[NPROJ], g_atl[NPROJ];
__device__ unsigned short g_woh[NW], g_wol[NW];
__device__ unsigned short g_vt[(size_t)512 * 64 * 512];            // per-tile V^T bf16
__device__ float g_M[(size_t)512 * 4096];
__device__ float g_z[(size_t)512 * 64];

typedef __attribute__((ext_vector_type(8))) short short8;
typedef __attribute__((ext_vector_type(8))) unsigned short ushort8;
typedef __attribute__((ext_vector_type(4))) float f32x4;

__device__ __forceinline__ float elu1(float x) {
    return x > 0.f ? x + 1.f : __expf(x);
}
__device__ __forceinline__ unsigned short f2bf(float x) {
    unsigned u = __float_as_uint(x);
    u += 0x7fffu + ((u >> 16) & 1u);           // RNE
    return (unsigned short)(u >> 16);
}
__device__ __forceinline__ float bf2f(unsigned short h) {
    return __uint_as_float((unsigned)h << 16);
}
__device__ __forceinline__ void load_lds16(const unsigned short* g, unsigned short* l) {
    __builtin_amdgcn_global_load_lds(
        (const __attribute__((address_space(1))) unsigned int*)g,
        (__attribute__((address_space(3))) unsigned int*)l, 16, 0, 0);
}
// ushort offset of (row, 8-ushort block blk) in a [64][64]-bf16 LDS tile,
// XOR-swizzled so column-slice b128 reads hit the uniform bank floor.
__device__ __forceinline__ int sz8(int row, int blk) {
    return row * 64 + ((blk ^ (row & 7)) << 3);
}

// Fused prologue: cast x, Wq, Wk, Wv to bf16; split Wout into hi/lo.
__global__ __launch_bounds__(256) void prep_cast(
    const float* __restrict__ x, const float* __restrict__ Wq,
    const float* __restrict__ Wk, const float* __restrict__ Wv,
    const float* __restrict__ Wout,
    unsigned short* __restrict__ xh, unsigned short* __restrict__ wqkv,
    unsigned short* __restrict__ woh, unsigned short* __restrict__ wol)
{
    const int b = blockIdx.x;
    const int nXB = (int)(NPROJ / 1024);           // 16384
    const int nWB = (int)(NW / 1024);              // 1024
    if (b < nXB + 3 * nWB) {
        const float* in;
        unsigned short* out;
        int i;
        if (b < nXB) {
            in = x; out = xh; i = (b * 256 + threadIdx.x) * 4;
        } else {
            const int wsel = (b - nXB) / nWB;      // 0,1,2
            const int wb   = (b - nXB) % nWB;
            in  = wsel == 0 ? Wq : (wsel == 1 ? Wk : Wv);
            out = wqkv + (size_t)wsel * NW;
            i = (wb * 256 + threadIdx.x) * 4;
        }
        float4 v = *(const float4*)(in + i);
        ushort4 h;
        h.x = f2bf(v.x); h.y = f2bf(v.y); h.z = f2bf(v.z); h.w = f2bf(v.w);
        *(ushort4*)(out + i) = h;
    } else {
        const int wb = b - nXB - 3 * nWB;
        const int i = (wb * 256 + threadIdx.x) * 4;
        float4 v = *(const float4*)(Wout + i);
        ushort4 h, l;
        h.x = f2bf(v.x); l.x = f2bf(v.x - bf2f(h.x));
        h.y = f2bf(v.y); l.y = f2bf(v.y - bf2f(h.y));
        h.z = f2bf(v.z); l.z = f2bf(v.z - bf2f(h.z));
        h.w = f2bf(v.w); l.w = f2bf(v.w - bf2f(h.w));
        *(ushort4*)(woh + i) = h;
        *(ushort4*)(wol + i) = l;
    }
}

// ---------------------------------------------------------------------------
// Fused QKV GEMM, 8-phase 256x256 pipeline (main loop unchanged from round 6).
// ---------------------------------------------------------------------------

#define VMC(N) asm volatile("s_waitcnt vmcnt(" #N ")" ::: "memory")

#define STAGE_A(p, h, tt, u) \
    load_lds16(Aw + ((h) * 128 + (u) * 8) * 1024 + (tt) * 64, \
               &lds[(p) * 32768 + ((h) * 128 + w * 16 + (u) * 8) * 64])
#define STAGE_B(p, h, tt, u) \
    load_lds16(Bww + ((h) * 128 + (u) * 8) * 1024 + (tt) * 64, \
               &lds[(p) * 32768 + 16384 + ((h) * 128 + w * 16 + (u) * 8) * 64])
#define STAGE_AH(p, h, tt) do { STAGE_A(p, h, tt, 0); STAGE_A(p, h, tt, 1); } while (0)
#define STAGE_BH(p, h, tt) do { STAGE_B(p, h, tt, 0); STAGE_B(p, h, tt, 1); } while (0)

#define LDA(PBUF, MLO) do { \
    _Pragma("unroll") for (int m2 = 0; m2 < 4; ++m2) \
    _Pragma("unroll") for (int ks2 = 0; ks2 < 2; ++ks2) \
        a[m2][ks2] = *(const short8*)&lds[(PBUF) * 32768 + aoff[ks2] + ((MLO) + m2) * 1024]; \
} while (0)

#define LDB(PBUF) do { \
    _Pragma("unroll") for (int n2 = 0; n2 < 4; ++n2) \
    _Pragma("unroll") for (int ks2 = 0; ks2 < 2; ++ks2) \
        b[n2][ks2] = *(const short8*)&lds[(PBUF) * 32768 + boff[ks2] + n2 * 1024]; \
} while (0)

#define MFMA_QUAD(MLO, NLO) do { \
    _Pragma("unroll") for (int m2 = 0; m2 < 4; ++m2) \
    _Pragma("unroll") for (int n2 = 0; n2 < 2; ++n2) \
    _Pragma("unroll") for (int ks2 = 0; ks2 < 2; ++ks2) \
        acc[(MLO) + m2][(NLO) + n2] = __builtin_amdgcn_mfma_f32_16x16x32_bf16( \
            a[m2][ks2], b[(NLO) + n2][ks2], acc[(MLO) + m2][(NLO) + n2], 0, 0, 0); \
} while (0)

#define PH(MLO, NLO) do { \
    __builtin_amdgcn_s_barrier(); \
    asm volatile("s_waitcnt lgkmcnt(0)" ::: "memory"); \
    __builtin_amdgcn_sched_barrier(0); \
    __builtin_amdgcn_s_setprio(1); \
    MFMA_QUAD(MLO, NLO); \
    __builtin_amdgcn_s_setprio(0); \
    __builtin_amdgcn_sched_barrier(0); \
    __builtin_amdgcn_s_barrier(); \
} while (0)

__global__ __launch_bounds__(512, 2) void gemm_qkv8(
    const unsigned short* __restrict__ A, const unsigned short* __restrict__ Bw,
    unsigned short* __restrict__ Q, unsigned short* __restrict__ Kp,
    unsigned short* __restrict__ V)
{
    __shared__ unsigned short lds[65536];   // 128KB: [buf0 A|B][buf1 A|B]
    const int t = threadIdx.x, lane = t & 63, w = t >> 6;
    const int wave_m = w >> 2, wave_n = w & 3;

    // XCD-bijective swizzle: 768 blocks = 96 * 8.
    const int bid = blockIdx.x;
    const int sb = (bid & 7) * 96 + (bid >> 3);
    const int mb = sb / 12, nb = sb % 12;
    const int m0 = mb * 256, n0 = nb * 256;

    // staging per-lane constants (LDS linear; swizzle folded into global col)
    const int lrow = lane >> 3;                       // 0..7
    const int lcol = ((lane & 7) ^ lrow) * 8;         // swizzled ushort col
    const unsigned short* Aw  = A  + (size_t)(m0 + w * 16 + lrow) * 1024 + lcol;
    const unsigned short* Bww = Bw + (size_t)(n0 + w * 16 + lrow) * 1024 + lcol;

    // frag-read per-lane ushort offsets (same involution as the stage side)
    const int fr = lane & 15, g4 = lane >> 4;
    int aoff[2], boff[2];
#pragma unroll
    for (int ks2 = 0; ks2 < 2; ++ks2) {
        aoff[ks2] = (wave_m * 128 + fr) * 64 + (((ks2 * 4 + g4) ^ (fr & 7)) * 8);
        boff[ks2] = 16384 + (wave_n * 64 + fr) * 64 + (((ks2 * 4 + g4) ^ (fr & 7)) * 8);
    }

    f32x4 acc[8][4];
#pragma unroll
    for (int i = 0; i < 8; ++i)
#pragma unroll
        for (int j = 0; j < 4; ++j) acc[i][j] = (f32x4)0.f;
    short8 a[4][2], b[4][2];

    // Prologue: tile0 (buf0) fully + tile1 (buf1) B0,B1,A0. vmcnt(6) -> tile0 landed.
    STAGE_BH(0, 0, 0); STAGE_BH(0, 1, 0); STAGE_AH(0, 0, 0); STAGE_AH(0, 1, 0);
    STAGE_BH(1, 0, 1); STAGE_BH(1, 1, 1); STAGE_AH(1, 0, 1);
    VMC(6);
    __builtin_amdgcn_s_barrier();

#pragma unroll 1
    for (int it = 0; it < 7; ++it) {
        const int t1 = 2 * it + 1, t2 = 2 * it + 2, t3 = 2 * it + 3;
        LDB(0); LDA(0, 0);
        STAGE_AH(1, 1, t1);
        PH(0, 0);
        STAGE_BH(0, 0, t2);
        PH(0, 2);
        LDA(0, 4);
        STAGE_BH(0, 1, t2);
        PH(4, 0);
        STAGE_AH(0, 0, t2);
        VMC(6);
        PH(4, 2);
        LDB(1); LDA(1, 0);
        STAGE_AH(0, 1, t2);
        PH(0, 0);
        STAGE_BH(1, 0, t3);
        PH(0, 2);
        LDA(1, 4);
        STAGE_BH(1, 1, t3);
        PH(4, 0);
        STAGE_AH(1, 0, t3);
        VMC(6);
        PH(4, 2);
    }
    LDB(0); LDA(0, 0);
    STAGE_AH(1, 1, 15);
    PH(0, 0);
    PH(0, 2);
    LDA(0, 4);
    PH(4, 0);
    VMC(0);
    PH(4, 2);
    LDB(1); LDA(1, 0);
    PH(0, 0);
    PH(0, 2);
    LDA(1, 4);
    PH(4, 0);
    PH(4, 2);

    // Epilogue: acc -> bf16 -> LDS -> coalesced store. 16B-block index XORed
    // with row&31 on both sides: row stride 512B made readback 64-way
    // conflicted (all lanes on one 4-bank group) and writes 8-way.
    const int ccol = lane & 15, crow = (lane >> 4) * 4;
#pragma unroll
    for (int m = 0; m < 8; ++m)
#pragma unroll
        for (int n = 0; n < 4; ++n) {
            const int col = wave_n * 64 + n * 16 + ccol;
            const int cb = col >> 3, cl = col & 7;
#pragma unroll
            for (int r = 0; r < 4; ++r) {
                const int row = wave_m * 128 + m * 16 + crow + r;
                lds[row * 256 + ((cb ^ (row & 31)) << 3) + cl] = f2bf(acc[m][n][r]);
            }
        }
    __syncthreads();
    const int which = n0 >> 10, col0 = n0 & 1023;
    unsigned short* outp = which == 0 ? Q : (which == 1 ? Kp : V);
    const int orow = t >> 1, och = (t & 1) * 128;
    unsigned short* gp = outp + (size_t)(m0 + orow) * 1024 + col0 + och;
#pragma unroll
    for (int u = 0; u < 128; u += 8) {
        const int bo = (och + u) >> 3;
        *(ushort8*)(gp + u) = *(const ushort8*)&lds[orow * 256 + ((bo ^ (orow & 31)) << 3)];
    }
}

// ---------------------------------------------------------------------------
// Out-GEMM, 8-phase 256x256/BK=32 split-bf16 pipeline (unchanged, round 7).
// ---------------------------------------------------------------------------

#define OSTG(p, arrp, aroff, tt, u) \
    load_lds16(arrp + (size_t)(u) * 16 * 1024 + (tt) * 32, \
               &lds[(p) * 32768 + (aroff) + (w * 32 + (u) * 16) * 32])
#define OUNIT(p, arrp, aroff, tt) do { OSTG(p, arrp, aroff, tt, 0); OSTG(p, arrp, aroff, tt, 1); } while (0)

#define OLDA(PBUF, MLO) do { \
    _Pragma("unroll") for (int m2 = 0; m2 < 4; ++m2) { \
        ah[m2] = *(const short8*)&lds[(PBUF) * 32768 +         ao + ((MLO) + m2) * 512]; \
        al[m2] = *(const short8*)&lds[(PBUF) * 32768 +  8192 + ao + ((MLO) + m2) * 512]; \
    } \
} while (0)

#define OLDB(PBUF) do { \
    _Pragma("unroll") for (int n2 = 0; n2 < 4; ++n2) { \
        bh[n2] = *(const short8*)&lds[(PBUF) * 32768 + 16384 + bo + n2 * 512]; \
        bl[n2] = *(const short8*)&lds[(PBUF) * 32768 + 24576 + bo + n2 * 512]; \
    } \
} while (0)

#define OQUAD(MLO, NLO) do { \
    _Pragma("unroll") for (int m2 = 0; m2 < 4; ++m2) \
    _Pragma("unroll") for (int n2 = 0; n2 < 2; ++n2) { \
        acc[(MLO) + m2][(NLO) + n2] = __builtin_amdgcn_mfma_f32_16x16x32_bf16( \
            ah[m2], bh[(NLO) + n2], acc[(MLO) + m2][(NLO) + n2], 0, 0, 0); \
        acc[(MLO) + m2][(NLO) + n2] = __builtin_amdgcn_mfma_f32_16x16x32_bf16( \
            al[m2], bh[(NLO) + n2], acc[(MLO) + m2][(NLO) + n2], 0, 0, 0); \
        acc[(MLO) + m2][(NLO) + n2] = __builtin_amdgcn_mfma_f32_16x16x32_bf16( \
            ah[m2], bl[(NLO) + n2], acc[(MLO) + m2][(NLO) + n2], 0, 0, 0); \
    } \
} while (0)

#define OPH(MLO, NLO) do { \
    __builtin_amdgcn_s_barrier(); \
    asm volatile("s_waitcnt lgkmcnt(0)" ::: "memory"); \
    __builtin_amdgcn_sched_barrier(0); \
    __builtin_amdgcn_s_setprio(1); \
    OQUAD(MLO, NLO); \
    __builtin_amdgcn_s_setprio(0); \
    __builtin_amdgcn_sched_barrier(0); \
    __builtin_amdgcn_s_barrier(); \
} while (0)

__global__ __launch_bounds__(512, 2) void gemm_bt8(
    const unsigned short* __restrict__ Ah, const unsigned short* __restrict__ Al,
    const unsigned short* __restrict__ Bh, const unsigned short* __restrict__ Bl,
    float* __restrict__ C)
{
    __shared__ unsigned short lds[65536];   // 128KB: [buf0 Ah|Al|Bh|Bl][buf1 ...]
    const int t = threadIdx.x, lane = t & 63, w = t >> 6;
    const int wave_m = w >> 2, wave_n = w & 3;

    const int bid = blockIdx.x;
    const int sb = (bid & 7) * 32 + (bid >> 3);
    const int m0 = (sb >> 2) * 256, n0 = (sb & 3) * 256;

    const int lrow = lane >> 2;                               // 0..15
    const int lcol = ((lane & 3) ^ ((lane >> 3) & 3)) * 8;    // blk ^ ((row>>1)&3)
    const unsigned short* Ahp = Ah + (size_t)(m0 + w * 32 + lrow) * 1024 + lcol;
    const unsigned short* Alp = Al + (size_t)(m0 + w * 32 + lrow) * 1024 + lcol;
    const unsigned short* Bhp = Bh + (size_t)(n0 + w * 32 + lrow) * 1024 + lcol;
    const unsigned short* Blp = Bl + (size_t)(n0 + w * 32 + lrow) * 1024 + lcol;

    const int fr = lane & 15, g4 = lane >> 4;
    const int xo = (g4 ^ ((fr >> 1) & 3)) * 8;
    const int ao = (wave_m * 128 + fr) * 32 + xo;
    const int bo = (wave_n * 64 + fr) * 32 + xo;

    f32x4 acc[8][4];
#pragma unroll
    for (int i = 0; i < 8; ++i)
#pragma unroll
        for (int j = 0; j < 4; ++j) acc[i][j] = (f32x4)0.f;
    short8 ah[4], al[4], bh[4], bl[4];

    OUNIT(0, Bhp, 16384, 0); OUNIT(0, Blp, 24576, 0); OUNIT(0, Ahp, 0, 0); OUNIT(0, Alp, 8192, 0);
    OUNIT(1, Bhp, 16384, 1); OUNIT(1, Blp, 24576, 1); OUNIT(1, Ahp, 0, 1);
    VMC(6);
    __builtin_amdgcn_s_barrier();

#pragma unroll 1
    for (int it = 0; it < 15; ++it) {
        const int t1 = 2 * it + 1, t2 = 2 * it + 2, t3 = 2 * it + 3;
        OLDB(0); OLDA(0, 0);
        OUNIT(1, Alp, 8192, t1);
        OPH(0, 0);
        OUNIT(0, Bhp, 16384, t2);
        OPH(0, 2);
        OLDA(0, 4);
        OUNIT(0, Blp, 24576, t2);
        OPH(4, 0);
        OUNIT(0, Ahp, 0, t2);
        VMC(6);
        OPH(4, 2);
        OLDB(1); OLDA(1, 0);
        OUNIT(0, Alp, 8192, t2);
        OPH(0, 0);
        OUNIT(1, Bhp, 16384, t3);
        OPH(0, 2);
        OLDA(1, 4);
        OUNIT(1, Blp, 24576, t3);
        OPH(4, 0);
        OUNIT(1, Ahp, 0, t3);
        VMC(6);
        OPH(4, 2);
    }
    OLDB(0); OLDA(0, 0);
    OUNIT(1, Alp, 8192, 31);
    OPH(0, 0);
    OPH(0, 2);
    OLDA(0, 4);
    OPH(4, 0);
    VMC(0);
    OPH(4, 2);
    OLDB(1); OLDA(1, 0);
    OPH(0, 0);
    OPH(0, 2);
    OLDA(1, 4);
    OPH(4, 0);
    OPH(4, 2);

    const int ccol = lane & 15, crow = (lane >> 4) * 4;
#pragma unroll
    for (int m = 0; m < 8; ++m)
#pragma unroll
        for (int n = 0; n < 4; ++n) {
            float* cp = C + (size_t)(m0 + wave_m * 128 + m * 16 + crow) * 1024
                          + (n0 + wave_n * 64 + n * 16 + ccol);
#pragma unroll
            for (int r = 0; r < 4; ++r) cp[(size_t)r * 1024] = acc[m][n][r];
        }
}

// Per (b,h,seg): M_seg[d][v], zsum[d], and V^T bf16 tile. Inputs bf16.
__global__ __launch_bounds__(256) void seg_stats(
    const unsigned short* __restrict__ kproj, const unsigned short* __restrict__ vproj,
    float* __restrict__ Mseg, float* __restrict__ zsum,
    unsigned short* __restrict__ vtg)
{
    __shared__ float ks[64][68];
    __shared__ float vs[64][68];
    const int idx = blockIdx.x;
    const int seg = idx & 15;
    const int bh  = idx >> 4;
    const int h   = bh & 15;
    const int b   = bh >> 4;
    const size_t base = ((size_t)b * T_ + (size_t)seg * SEG_ + (size_t)h * 32) * D_;
    const unsigned short* kt = kproj + base;
    const unsigned short* vt = vproj + base;
    const int t  = threadIdx.x;
    const int d0 = (t >> 4) * 4;
    const int v0 = (t & 15) * 4;
    const int lr = t >> 2;
    const int lc = (t & 3) * 16;
    float acc[4][4];
#pragma unroll
    for (int i = 0; i < 4; ++i)
#pragma unroll
        for (int j = 0; j < 4; ++j) acc[i][j] = 0.f;
    float zacc = 0.f;

    for (int c0 = 0; c0 < SEG_; c0 += 64) {
        __syncthreads();
        {
            const unsigned short* kp = kt + (size_t)(c0 + lr) * 64 + lc;
            const unsigned short* vp = vt + (size_t)(c0 + lr) * 64 + lc;
            ushort8 k0 = *(const ushort8*)kp,       k1 = *(const ushort8*)(kp + 8);
            ushort8 v0v = *(const ushort8*)vp,      v1 = *(const ushort8*)(vp + 8);
#pragma unroll
            for (int e = 0; e < 8; ++e) {
                ks[lr][lc + e]     = elu1(bf2f(k0[e]));
                ks[lr][lc + 8 + e] = elu1(bf2f(k1[e]));
                vs[lr][lc + e]     = bf2f(v0v[e]);
                vs[lr][lc + 8 + e] = bf2f(v1[e]);
            }
        }
        __syncthreads();
#pragma unroll 8
        for (int i = 0; i < 64; ++i) {
            float a0 = ks[i][d0 + 0], a1 = ks[i][d0 + 1];
            float a2 = ks[i][d0 + 2], a3 = ks[i][d0 + 3];
            float b0 = vs[i][v0 + 0], b1 = vs[i][v0 + 1];
            float b2 = vs[i][v0 + 2], b3 = vs[i][v0 + 3];
            acc[0][0] += a0 * b0; acc[0][1] += a0 * b1; acc[0][2] += a0 * b2; acc[0][3] += a0 * b3;
            acc[1][0] += a1 * b0; acc[1][1] += a1 * b1; acc[1][2] += a1 * b2; acc[1][3] += a1 * b3;
            acc[2][0] += a2 * b0; acc[2][1] += a2 * b1; acc[2][2] += a2 * b2; acc[2][3] += a2 * b3;
            acc[3][0] += a3 * b0; acc[3][1] += a3 * b1; acc[3][2] += a3 * b2; acc[3][3] += a3 * b3;
        }
        if (t < 64) {
#pragma unroll 8
            for (int i = 0; i < 64; ++i) zacc += ks[i][t];
        }
        {   // V^T bf16: row = v-dim (lr), cols = time
            ushort8 w0, w1;
#pragma unroll
            for (int i = 0; i < 8; ++i) w0[i] = f2bf(vs[lc + i][lr]);
#pragma unroll
            for (int i = 0; i < 8; ++i) w1[i] = f2bf(vs[lc + 8 + i][lr]);
            unsigned short* vo = vtg + ((size_t)idx * 64 + lr) * 512 + c0 + lc;
            *(ushort8*)vo       = w0;
            *(ushort8*)(vo + 8) = w1;
        }
    }
    float* Mout = Mseg + (size_t)idx * 4096;
#pragma unroll
    for (int i = 0; i < 4; ++i)
        *(float4*)(Mout + (size_t)(d0 + i) * 64 + v0) =
            make_float4(acc[i][0], acc[i][1], acc[i][2], acc[i][3]);
    if (t < 64) zsum[(size_t)idx * 64 + t] = zacc;
}

// Per (b,h,slice): in-place exclusive prefix of M (1024-float slice),
// inclusive prefix of z (slice 0). 128 blocks = 4x parallelism vs before.
__global__ __launch_bounds__(256) void prefix_scan(
    float* __restrict__ M, float* __restrict__ z)
{
    const int blk = blockIdx.x;
    const int bh  = blk >> 2, sl = blk & 3;
    const int t   = threadIdx.x;
    const size_t off = (size_t)bh * NSEG_ * 4096 + (size_t)sl * 1024 + (size_t)t * 4;
    float4 run = make_float4(0.f, 0.f, 0.f, 0.f);
    float runz = 0.f;
    for (int seg = 0; seg < NSEG_; ++seg) {
        const size_t o = off + (size_t)seg * 4096;
        float4 m = *(const float4*)(M + o);
        *(float4*)(M + o) = run;
        run.x += m.x; run.y += m.y; run.z += m.z; run.w += m.w;
        if (sl == 0 && t < 64) {
            const size_t oz = ((size_t)bh * NSEG_ + seg) * 64 + t;
            runz += z[oz];
            z[oz] = runz;
        }
    }
}

// MFMA flash attention per (b,h,seg,64-row q-chunk). bf16 q/k/v inputs.
__global__ __launch_bounds__(256) void attn_mfma(
    const unsigned short* __restrict__ qproj, const unsigned short* __restrict__ kproj,
    const unsigned short* __restrict__ vtg, const float* __restrict__ memb,
    const float* __restrict__ Zaf, const float* __restrict__ betas,
    unsigned short* __restrict__ ath, unsigned short* __restrict__ atl)
{
    __shared__ unsigned short sm_k[64 * 64];   // k bf16 ; epilogue att_hi (swizzled)
    __shared__ unsigned short sm_v[64 * 64];   // V^T bf16 ; epilogue att_lo (swizzled)
    __shared__ unsigned short sm_p[64 * 64];   // mem^T bf16, then P bf16 (swizzled)
    __shared__ float Zsh[64], gsh[64];

    const int idx  = blockIdx.x;
    // XCD-aware remap: bids g*64 + qc*8 + x -> rest = g*8 + x, so one rest's
    // 8 qc-blocks share bid%8 (same XCD) inside a 64-bid window (co-resident).
    const int qc   = (idx >> 3) & 7;
    const int rest = (idx >> 6) * 8 + (idx & 7);
    const int bh   = rest >> 4;
    const int seg  = rest & 15;
    const int h    = bh & 15;
    const int b    = bh >> 4;
    const size_t base = ((size_t)b * T_ + (size_t)seg * SEG_ + (size_t)h * 32) * D_;

    const int t    = threadIdx.x;
    const int lane = t & 63;
    const int w    = t >> 6;
    const int c16  = lane & 15;
    const int g4   = lane >> 4;
    const int lr   = t >> 2;
    const int lc   = (t & 3) * 16;

    const unsigned short* qt = qproj + base + (size_t)qc * 4096;
    const unsigned short* kt = kproj + base;
    const unsigned short* vt = vtg + (size_t)rest * (64 * 512);
    const float* mb = memb + (size_t)rest * 4096;

    if (t < 64) {
        Zsh[t] = Zaf[(size_t)rest * 64 + t];
        gsh[t] = 1.f / (1.f + __expf(-betas[h * 64 + t]));
    }

    // q fragments (A-layout: m = w*16+c16, k = g4*8 + ks*32 + j), sq, rowsum
    short8 qh[2], sqh[2];
    float rowsum = 0.f;
#pragma unroll
    for (int ks = 0; ks < 2; ++ks) {
        const unsigned short* qp = qt + (size_t)(w * 16 + c16) * 64 + g4 * 8 + ks * 32;
        ushort8 qv = *(const ushort8*)qp;
        short8 qf, sf;
#pragma unroll
        for (int j = 0; j < 8; ++j) {
            float e = elu1(bf2f(qv[j]));
            rowsum += e;
            qf[j] = (short)qv[j];
            sf[j] = (short)f2bf(e);
        }
        qh[ks] = qf; sqh[ks] = sf;
    }
    rowsum += __shfl_xor(rowsum, 16);
    rowsum += __shfl_xor(rowsum, 32);

    // stage mem^T (bf16) into sm_p (swizzled scalar writes)
    {
        const float* mp = mb + (size_t)lr * 64 + lc;
#pragma unroll
        for (int u = 0; u < 4; ++u) {
            float4 m4 = *(const float4*)(mp + u * 4);
            sm_p[sz8(lc + u * 4 + 0, lr >> 3) + (lr & 7)] = f2bf(m4.x);
            sm_p[sz8(lc + u * 4 + 1, lr >> 3) + (lr & 7)] = f2bf(m4.y);
            sm_p[sz8(lc + u * 4 + 2, lr >> 3) + (lr & 7)] = f2bf(m4.z);
            sm_p[sz8(lc + u * 4 + 3, lr >> 3) + (lr & 7)] = f2bf(m4.w);
        }
    }
    __syncthreads();

    // num = sq @ mem  (B-operand = mem^T[v][d])
    f32x4 numf[4];
#pragma unroll
    for (int nf = 0; nf < 4; ++nf) numf[nf] = (f32x4)0.f;
#pragma unroll
    for (int ks = 0; ks < 2; ++ks)
#pragma unroll
        for (int nf = 0; nf < 4; ++nf) {
            short8 bm = *(const short8*)&sm_p[sz8(nf * 16 + c16, g4 + ks * 4)];
            numf[nf] = __builtin_amdgcn_mfma_f32_16x16x32_bf16(sqh[ks], bm, numf[nf], 0, 0, 0);
        }

    // ones B-frag (bf16 1.0) for row-sum-via-MFMA
    short8 bones;
#pragma unroll
    for (int j = 0; j < 8; ++j) bones[j] = (short)0x3F80;

    f32x4 o[4];
#pragma unroll
    for (int nf = 0; nf < 4; ++nf) o[nf] = (f32x4)0.f;
    float mrow[4] = {-1e30f, -1e30f, -1e30f, -1e30f};
    float lrow[4] = {0.f, 0.f, 0.f, 0.f};

    for (int kb = 0; kb < 8; ++kb) {
        __syncthreads();
        {   // stage k and V^T (both already bf16 — swizzled 16B copies)
            const unsigned short* kp = kt + (size_t)(kb * 64 + lr) * 64 + lc;
            *(ushort8*)&sm_k[sz8(lr, lc >> 3)]       = *(const ushort8*)kp;
            *(ushort8*)&sm_k[sz8(lr, (lc >> 3) + 1)] = *(const ushort8*)(kp + 8);
            const unsigned short* vp = vt + (size_t)lr * 512 + kb * 64 + lc;
            *(ushort8*)&sm_v[sz8(lr, lc >> 3)]       = *(const ushort8*)vp;
            *(ushort8*)&sm_v[sz8(lr, (lc >> 3) + 1)] = *(const ushort8*)(vp + 8);
        }
        __syncthreads();

        // scores S = Q @ K^T
        f32x4 s[4];
#pragma unroll
        for (int nf = 0; nf < 4; ++nf) s[nf] = (f32x4)0.f;
#pragma unroll
        for (int ks = 0; ks < 2; ++ks)
#pragma unroll
            for (int nf = 0; nf < 4; ++nf) {
                short8 bk = *(const short8*)&sm_k[sz8(nf * 16 + c16, g4 + ks * 4)];
                s[nf] = __builtin_amdgcn_mfma_f32_16x16x32_bf16(qh[ks], bk, s[nf], 0, 0, 0);
            }
#pragma unroll
        for (int nf = 0; nf < 4; ++nf) s[nf] *= 0.125f;

        // T13 deferred max: wave-wide __all over per-lane partial maxima
        // covers the c16 reduction lanes for free.
        float pmax[4];
#pragma unroll
        for (int r = 0; r < 4; ++r)
            pmax[r] = fmaxf(fmaxf(s[0][r], s[1][r]), fmaxf(s[2][r], s[3][r]));
        const bool ok = pmax[0] <= mrow[0] + 8.f && pmax[1] <= mrow[1] + 8.f &&
                        pmax[2] <= mrow[2] + 8.f && pmax[3] <= mrow[3] + 8.f;
        if (!__all(ok)) {
#pragma unroll
            for (int r = 0; r < 4; ++r) {
                float mx = pmax[r];
                mx = fmaxf(mx, __shfl_xor(mx, 1));
                mx = fmaxf(mx, __shfl_xor(mx, 2));
                mx = fmaxf(mx, __shfl_xor(mx, 4));
                mx = fmaxf(mx, __shfl_xor(mx, 8));
                const float mnew = fmaxf(mrow[r], mx);
                const float corr = __expf(mrow[r] - mnew);
                mrow[r] = mnew;
                lrow[r] *= corr;
#pragma unroll
                for (int nf = 0; nf < 4; ++nf) o[nf][r] *= corr;
            }
        }
#pragma unroll
        for (int nf = 0; nf < 4; ++nf)
#pragma unroll
            for (int r = 0; r < 4; ++r) {
                s[nf][r] = __expf(s[nf][r] - mrow[r]);
                // publish P (C-layout -> A-layout), same-wave rows only
                sm_p[sz8(w * 16 + g4 * 4 + r, nf * 2 + (c16 >> 3)) + (c16 & 7)] =
                    f2bf(s[nf][r]);
            }

        // O += P @ V ; row-sum via ones-MFMA (denominator from the same bf16 P)
        f32x4 psum = (f32x4)0.f;
#pragma unroll
        for (int ks = 0; ks < 2; ++ks) {
            short8 pa = *(const short8*)&sm_p[sz8(w * 16 + c16, g4 + ks * 4)];
            psum = __builtin_amdgcn_mfma_f32_16x16x32_bf16(pa, bones, psum, 0, 0, 0);
#pragma unroll
            for (int nf = 0; nf < 4; ++nf) {
                short8 bv = *(const short8*)&sm_v[sz8(nf * 16 + c16, g4 + ks * 4)];
                o[nf] = __builtin_amdgcn_mfma_f32_16x16x32_bf16(pa, bv, o[nf], 0, 0, 0);
            }
        }
#pragma unroll
        for (int r = 0; r < 4; ++r) lrow[r] += psum[r];
    }

    __syncthreads();   // staging done — reuse sm_k/sm_v for att hi/lo

    float rs[4], invl[4];
#pragma unroll
    for (int r = 0; r < 4; ++r) {
        rs[r]   = __shfl(rowsum, (g4 << 2) + r);
        invl[r] = 1.f / lrow[r];
    }
#pragma unroll
    for (int nf = 0; nf < 4; ++nf) {
        const int col = nf * 16 + c16;
        const float Zc = Zsh[col], gc = gsh[col];
        const float izc = 1.f / Zc;
#pragma unroll
        for (int r = 0; r < 4; ++r) {
            const float adot = o[nf][r] * invl[r];
            const float amem = numf[nf][r] * izc / rs[r];
            const float res  = gc * amem + (1.f - gc) * adot;
            const unsigned short hv = f2bf(res);
            const unsigned short lv = f2bf(res - bf2f(hv));
            const int row = w * 16 + g4 * 4 + r;
            const int so  = sz8(row, nf * 2 + (c16 >> 3)) + (c16 & 7);
            sm_k[so] = hv;
            sm_v[so] = lv;
        }
    }
    __syncthreads();
    {
        const size_t ob = base + (size_t)(qc * 64 + lr) * 64 + lc;
        *(ushort8*)(ath + ob)     = *(const ushort8*)&sm_k[sz8(lr, lc >> 3)];
        *(ushort8*)(ath + ob + 8) = *(const ushort8*)&sm_k[sz8(lr, (lc >> 3) + 1)];
        *(ushort8*)(atl + ob)     = *(const ushort8*)&sm_v[sz8(lr, lc >> 3)];
        *(ushort8*)(atl + ob + 8) = *(const ushort8*)&sm_v[sz8(lr, (lc >> 3) + 1)];
    }
}

extern "C" void kernel_launch(void* const* d_in, const int* in_sizes, int n_in,
                              void* d_out, int out_size, void* d_ws, size_t ws_size,
                              hipStream_t stream) {
    const float* x     = (const float*)d_in[0];
    const float* Wq    = (const float*)d_in[1];
    const float* Wk    = (const float*)d_in[2];
    const float* Wv    = (const float*)d_in[3];
    const float* Wout  = (const float*)d_in[4];
    const float* betas = (const float*)d_in[5];
    float* out = (float*)d_out;
    (void)d_ws; (void)ws_size;

    float *M, *z;
    unsigned short *qb, *kb, *vb, *xh, *wqkv, *vt, *ath, *atl, *woh, *wol;
    hipGetSymbolAddress((void**)&qb,   HIP_SYMBOL(g_qb));
    hipGetSymbolAddress((void**)&kb,   HIP_SYMBOL(g_kb));
    hipGetSymbolAddress((void**)&vb,   HIP_SYMBOL(g_vb));
    hipGetSymbolAddress((void**)&xh,   HIP_SYMBOL(g_xh));
    hipGetSymbolAddress((void**)&wqkv, HIP_SYMBOL(g_wqkv));
    hipGetSymbolAddress((void**)&vt,   HIP_SYMBOL(g_vt));
    hipGetSymbolAddress((void**)&ath,  HIP_SYMBOL(g_ath));
    hipGetSymbolAddress((void**)&atl,  HIP_SYMBOL(g_atl));
    hipGetSymbolAddress((void**)&woh,  HIP_SYMBOL(g_woh));
    hipGetSymbolAddress((void**)&wol,  HIP_SYMBOL(g_wol));
    hipGetSymbolAddress((void**)&M,    HIP_SYMBOL(g_M));
    hipGetSymbolAddress((void**)&z,    HIP_SYMBOL(g_z));

    // fused prologue: x + Wq/Wk/Wv casts + Wout split in one launch
    const int nXB = (int)(NPROJ / 1024), nWB = (int)(NW / 1024);
    prep_cast<<<nXB + 4 * nWB, 256, 0, stream>>>(x, Wq, Wk, Wv, Wout,
                                                 xh, wqkv, woh, wol);

    gemm_qkv8<<<dim3(768), 512, 0, stream>>>(xh, wqkv, qb, kb, vb);
    seg_stats<<<B_ * H_ * NSEG_, 256, 0, stream>>>(kb, vb, M, z, vt);
    prefix_scan<<<B_ * H_ * 4, 256, 0, stream>>>(M, z);
    attn_mfma<<<B_ * H_ * NSEG_ * 8, 256, 0, stream>>>(qb, kb, vt, M, z, betas, ath, atl);
    gemm_bt8<<<dim3(256), 512, 0, stream>>>(ath, atl, woh, wol, out);
}

// Round 5
// 485.773 us; speedup vs baseline: 1.4168x; 1.0342x over previous
//
#include <hip/hip_runtime.h>

// CompressiveMemory — round 10.
//  * seg_stats rewritten as MFMA (was scalar-FMA outer product: ~1k broadcast
//    ds_read_b128 + 8k VALU FMA per thread ~= 40us LDS-bound):
//    - stage ksT-hi/ksT-lo (split-bf16 elu(k)) and vsT (exact bf16) tiles,
//      transposed at write: lane-per-row partition -> per-instr lanes fill
//      consecutive ushorts of one 16B granule = conflict-free.
//    - sz8 XOR layout (proven in attn) for all frag reads.
//    - M_seg = sk^T v via 16x16x32 MFMA (hi+lo, f32 acc); z via ones-MFMA.
//    - vsT tile doubles as the vtg output staging (transpose already paid).
//  * qkv8 / bt8 / attn / prefix / prep unchanged (rounds 6-9).
//  * R9 post-mortem: qkv8 epilogue conflict fix matched counters (7.47M->393K)
//    but time neutral -> conflicts were off critical path. qkv8 limit is the
//    phase/barrier structure; left untouched this round.

#define H_ 16
#define SEG_ 512
#define NSEG_ 16
#define B_ 2
#define T_ 8192
#define D_ 1024
#define BT_ 16384

#define NPROJ ((size_t)BT_ * D_)   // 16,777,216
#define NW ((size_t)D_ * D_)       // 1,048,576

__device__ unsigned short g_qb[NPROJ], g_kb[NPROJ], g_vb[NPROJ];   // bf16 projections
__device__ unsigned short g_xh[NPROJ];
__device__ unsigned short g_wqkv[3 * NW];                          // [Wq;Wk;Wv] bf16
__device__ unsigned short g_ath[NPROJ], g_atl[NPROJ];
__device__ unsigned short g_woh[NW], g_wol[NW];
__device__ unsigned short g_vt[(size_t)512 * 64 * 512];            // per-tile V^T bf16
__device__ float g_M[(size_t)512 * 4096];
__device__ float g_z[(size_t)512 * 64];

typedef __attribute__((ext_vector_type(8))) short short8;
typedef __attribute__((ext_vector_type(8))) unsigned short ushort8;
typedef __attribute__((ext_vector_type(4))) float f32x4;

__device__ __forceinline__ float elu1(float x) {
    return x > 0.f ? x + 1.f : __expf(x);
}
__device__ __forceinline__ unsigned short f2bf(float x) {
    unsigned u = __float_as_uint(x);
    u += 0x7fffu + ((u >> 16) & 1u);           // RNE
    return (unsigned short)(u >> 16);
}
__device__ __forceinline__ float bf2f(unsigned short h) {
    return __uint_as_float((unsigned)h << 16);
}
__device__ __forceinline__ void load_lds16(const unsigned short* g, unsigned short* l) {
    __builtin_amdgcn_global_load_lds(
        (const __attribute__((address_space(1))) unsigned int*)g,
        (__attribute__((address_space(3))) unsigned int*)l, 16, 0, 0);
}
// ushort offset of (row, 8-ushort block blk) in a [64][64]-bf16 LDS tile,
// XOR-swizzled so column-slice b128 reads hit the uniform bank floor.
__device__ __forceinline__ int sz8(int row, int blk) {
    return row * 64 + ((blk ^ (row & 7)) << 3);
}

// Fused prologue: cast x, Wq, Wk, Wv to bf16; split Wout into hi/lo.
__global__ __launch_bounds__(256) void prep_cast(
    const float* __restrict__ x, const float* __restrict__ Wq,
    const float* __restrict__ Wk, const float* __restrict__ Wv,
    const float* __restrict__ Wout,
    unsigned short* __restrict__ xh, unsigned short* __restrict__ wqkv,
    unsigned short* __restrict__ woh, unsigned short* __restrict__ wol)
{
    const int b = blockIdx.x;
    const int nXB = (int)(NPROJ / 1024);           // 16384
    const int nWB = (int)(NW / 1024);              // 1024
    if (b < nXB + 3 * nWB) {
        const float* in;
        unsigned short* out;
        int i;
        if (b < nXB) {
            in = x; out = xh; i = (b * 256 + threadIdx.x) * 4;
        } else {
            const int wsel = (b - nXB) / nWB;      // 0,1,2
            const int wb   = (b - nXB) % nWB;
            in  = wsel == 0 ? Wq : (wsel == 1 ? Wk : Wv);
            out = wqkv + (size_t)wsel * NW;
            i = (wb * 256 + threadIdx.x) * 4;
        }
        float4 v = *(const float4*)(in + i);
        ushort4 h;
        h.x = f2bf(v.x); h.y = f2bf(v.y); h.z = f2bf(v.z); h.w = f2bf(v.w);
        *(ushort4*)(out + i) = h;
    } else {
        const int wb = b - nXB - 3 * nWB;
        const int i = (wb * 256 + threadIdx.x) * 4;
        float4 v = *(const float4*)(Wout + i);
        ushort4 h, l;
        h.x = f2bf(v.x); l.x = f2bf(v.x - bf2f(h.x));
        h.y = f2bf(v.y); l.y = f2bf(v.y - bf2f(h.y));
        h.z = f2bf(v.z); l.z = f2bf(v.z - bf2f(h.z));
        h.w = f2bf(v.w); l.w = f2bf(v.w - bf2f(h.w));
        *(ushort4*)(woh + i) = h;
        *(ushort4*)(wol + i) = l;
    }
}

// ---------------------------------------------------------------------------
// Fused QKV GEMM, 8-phase 256x256 pipeline (unchanged from round 9).
// ---------------------------------------------------------------------------

#define VMC(N) asm volatile("s_waitcnt vmcnt(" #N ")" ::: "memory")

#define STAGE_A(p, h, tt, u) \
    load_lds16(Aw + ((h) * 128 + (u) * 8) * 1024 + (tt) * 64, \
               &lds[(p) * 32768 + ((h) * 128 + w * 16 + (u) * 8) * 64])
#define STAGE_B(p, h, tt, u) \
    load_lds16(Bww + ((h) * 128 + (u) * 8) * 1024 + (tt) * 64, \
               &lds[(p) * 32768 + 16384 + ((h) * 128 + w * 16 + (u) * 8) * 64])
#define STAGE_AH(p, h, tt) do { STAGE_A(p, h, tt, 0); STAGE_A(p, h, tt, 1); } while (0)
#define STAGE_BH(p, h, tt) do { STAGE_B(p, h, tt, 0); STAGE_B(p, h, tt, 1); } while (0)

#define LDA(PBUF, MLO) do { \
    _Pragma("unroll") for (int m2 = 0; m2 < 4; ++m2) \
    _Pragma("unroll") for (int ks2 = 0; ks2 < 2; ++ks2) \
        a[m2][ks2] = *(const short8*)&lds[(PBUF) * 32768 + aoff[ks2] + ((MLO) + m2) * 1024]; \
} while (0)

#define LDB(PBUF) do { \
    _Pragma("unroll") for (int n2 = 0; n2 < 4; ++n2) \
    _Pragma("unroll") for (int ks2 = 0; ks2 < 2; ++ks2) \
        b[n2][ks2] = *(const short8*)&lds[(PBUF) * 32768 + boff[ks2] + n2 * 1024]; \
} while (0)

#define MFMA_QUAD(MLO, NLO) do { \
    _Pragma("unroll") for (int m2 = 0; m2 < 4; ++m2) \
    _Pragma("unroll") for (int n2 = 0; n2 < 2; ++n2) \
    _Pragma("unroll") for (int ks2 = 0; ks2 < 2; ++ks2) \
        acc[(MLO) + m2][(NLO) + n2] = __builtin_amdgcn_mfma_f32_16x16x32_bf16( \
            a[m2][ks2], b[(NLO) + n2][ks2], acc[(MLO) + m2][(NLO) + n2], 0, 0, 0); \
} while (0)

#define PH(MLO, NLO) do { \
    __builtin_amdgcn_s_barrier(); \
    asm volatile("s_waitcnt lgkmcnt(0)" ::: "memory"); \
    __builtin_amdgcn_sched_barrier(0); \
    __builtin_amdgcn_s_setprio(1); \
    MFMA_QUAD(MLO, NLO); \
    __builtin_amdgcn_s_setprio(0); \
    __builtin_amdgcn_sched_barrier(0); \
    __builtin_amdgcn_s_barrier(); \
} while (0)

__global__ __launch_bounds__(512, 2) void gemm_qkv8(
    const unsigned short* __restrict__ A, const unsigned short* __restrict__ Bw,
    unsigned short* __restrict__ Q, unsigned short* __restrict__ Kp,
    unsigned short* __restrict__ V)
{
    __shared__ unsigned short lds[65536];   // 128KB: [buf0 A|B][buf1 A|B]
    const int t = threadIdx.x, lane = t & 63, w = t >> 6;
    const int wave_m = w >> 2, wave_n = w & 3;

    // XCD-bijective swizzle: 768 blocks = 96 * 8.
    const int bid = blockIdx.x;
    const int sb = (bid & 7) * 96 + (bid >> 3);
    const int mb = sb / 12, nb = sb % 12;
    const int m0 = mb * 256, n0 = nb * 256;

    // staging per-lane constants (LDS linear; swizzle folded into global col)
    const int lrow = lane >> 3;                       // 0..7
    const int lcol = ((lane & 7) ^ lrow) * 8;         // swizzled ushort col
    const unsigned short* Aw  = A  + (size_t)(m0 + w * 16 + lrow) * 1024 + lcol;
    const unsigned short* Bww = Bw + (size_t)(n0 + w * 16 + lrow) * 1024 + lcol;

    // frag-read per-lane ushort offsets (same involution as the stage side)
    const int fr = lane & 15, g4 = lane >> 4;
    int aoff[2], boff[2];
#pragma unroll
    for (int ks2 = 0; ks2 < 2; ++ks2) {
        aoff[ks2] = (wave_m * 128 + fr) * 64 + (((ks2 * 4 + g4) ^ (fr & 7)) * 8);
        boff[ks2] = 16384 + (wave_n * 64 + fr) * 64 + (((ks2 * 4 + g4) ^ (fr & 7)) * 8);
    }

    f32x4 acc[8][4];
#pragma unroll
    for (int i = 0; i < 8; ++i)
#pragma unroll
        for (int j = 0; j < 4; ++j) acc[i][j] = (f32x4)0.f;
    short8 a[4][2], b[4][2];

    // Prologue: tile0 (buf0) fully + tile1 (buf1) B0,B1,A0. vmcnt(6) -> tile0 landed.
    STAGE_BH(0, 0, 0); STAGE_BH(0, 1, 0); STAGE_AH(0, 0, 0); STAGE_AH(0, 1, 0);
    STAGE_BH(1, 0, 1); STAGE_BH(1, 1, 1); STAGE_AH(1, 0, 1);
    VMC(6);
    __builtin_amdgcn_s_barrier();

#pragma unroll 1
    for (int it = 0; it < 7; ++it) {
        const int t1 = 2 * it + 1, t2 = 2 * it + 2, t3 = 2 * it + 3;
        LDB(0); LDA(0, 0);
        STAGE_AH(1, 1, t1);
        PH(0, 0);
        STAGE_BH(0, 0, t2);
        PH(0, 2);
        LDA(0, 4);
        STAGE_BH(0, 1, t2);
        PH(4, 0);
        STAGE_AH(0, 0, t2);
        VMC(6);
        PH(4, 2);
        LDB(1); LDA(1, 0);
        STAGE_AH(0, 1, t2);
        PH(0, 0);
        STAGE_BH(1, 0, t3);
        PH(0, 2);
        LDA(1, 4);
        STAGE_BH(1, 1, t3);
        PH(4, 0);
        STAGE_AH(1, 0, t3);
        VMC(6);
        PH(4, 2);
    }
    LDB(0); LDA(0, 0);
    STAGE_AH(1, 1, 15);
    PH(0, 0);
    PH(0, 2);
    LDA(0, 4);
    PH(4, 0);
    VMC(0);
    PH(4, 2);
    LDB(1); LDA(1, 0);
    PH(0, 0);
    PH(0, 2);
    LDA(1, 4);
    PH(4, 0);
    PH(4, 2);

    // Epilogue: acc -> bf16 -> LDS -> coalesced store (row&31 XOR, round 9).
    const int ccol = lane & 15, crow = (lane >> 4) * 4;
#pragma unroll
    for (int m = 0; m < 8; ++m)
#pragma unroll
        for (int n = 0; n < 4; ++n) {
            const int col = wave_n * 64 + n * 16 + ccol;
            const int cb = col >> 3, cl = col & 7;
#pragma unroll
            for (int r = 0; r < 4; ++r) {
                const int row = wave_m * 128 + m * 16 + crow + r;
                lds[row * 256 + ((cb ^ (row & 31)) << 3) + cl] = f2bf(acc[m][n][r]);
            }
        }
    __syncthreads();
    const int which = n0 >> 10, col0 = n0 & 1023;
    unsigned short* outp = which == 0 ? Q : (which == 1 ? Kp : V);
    const int orow = t >> 1, och = (t & 1) * 128;
    unsigned short* gp = outp + (size_t)(m0 + orow) * 1024 + col0 + och;
#pragma unroll
    for (int u = 0; u < 128; u += 8) {
        const int bo = (och + u) >> 3;
        *(ushort8*)(gp + u) = *(const ushort8*)&lds[orow * 256 + ((bo ^ (orow & 31)) << 3)];
    }
}

// ---------------------------------------------------------------------------
// Out-GEMM, 8-phase 256x256/BK=32 split-bf16 pipeline (unchanged, round 7).
// ---------------------------------------------------------------------------

#define OSTG(p, arrp, aroff, tt, u) \
    load_lds16(arrp + (size_t)(u) * 16 * 1024 + (tt) * 32, \
               &lds[(p) * 32768 + (aroff) + (w * 32 + (u) * 16) * 32])
#define OUNIT(p, arrp, aroff, tt) do { OSTG(p, arrp, aroff, tt, 0); OSTG(p, arrp, aroff, tt, 1); } while (0)

#define OLDA(PBUF, MLO) do { \
    _Pragma("unroll") for (int m2 = 0; m2 < 4; ++m2) { \
        ah[m2] = *(const short8*)&lds[(PBUF) * 32768 +         ao + ((MLO) + m2) * 512]; \
        al[m2] = *(const short8*)&lds[(PBUF) * 32768 +  8192 + ao + ((MLO) + m2) * 512]; \
    } \
} while (0)

#define OLDB(PBUF) do { \
    _Pragma("unroll") for (int n2 = 0; n2 < 4; ++n2) { \
        bh[n2] = *(const short8*)&lds[(PBUF) * 32768 + 16384 + bo + n2 * 512]; \
        bl[n2] = *(const short8*)&lds[(PBUF) * 32768 + 24576 + bo + n2 * 512]; \
    } \
} while (0)

#define OQUAD(MLO, NLO) do { \
    _Pragma("unroll") for (int m2 = 0; m2 < 4; ++m2) \
    _Pragma("unroll") for (int n2 = 0; n2 < 2; ++n2) { \
        acc[(MLO) + m2][(NLO) + n2] = __builtin_amdgcn_mfma_f32_16x16x32_bf16( \
            ah[m2], bh[(NLO) + n2], acc[(MLO) + m2][(NLO) + n2], 0, 0, 0); \
        acc[(MLO) + m2][(NLO) + n2] = __builtin_amdgcn_mfma_f32_16x16x32_bf16( \
            al[m2], bh[(NLO) + n2], acc[(MLO) + m2][(NLO) + n2], 0, 0, 0); \
        acc[(MLO) + m2][(NLO) + n2] = __builtin_amdgcn_mfma_f32_16x16x32_bf16( \
            ah[m2], bl[(NLO) + n2], acc[(MLO) + m2][(NLO) + n2], 0, 0, 0); \
    } \
} while (0)

#define OPH(MLO, NLO) do { \
    __builtin_amdgcn_s_barrier(); \
    asm volatile("s_waitcnt lgkmcnt(0)" ::: "memory"); \
    __builtin_amdgcn_sched_barrier(0); \
    __builtin_amdgcn_s_setprio(1); \
    OQUAD(MLO, NLO); \
    __builtin_amdgcn_s_setprio(0); \
    __builtin_amdgcn_sched_barrier(0); \
    __builtin_amdgcn_s_barrier(); \
} while (0)

__global__ __launch_bounds__(512, 2) void gemm_bt8(
    const unsigned short* __restrict__ Ah, const unsigned short* __restrict__ Al,
    const unsigned short* __restrict__ Bh, const unsigned short* __restrict__ Bl,
    float* __restrict__ C)
{
    __shared__ unsigned short lds[65536];   // 128KB: [buf0 Ah|Al|Bh|Bl][buf1 ...]
    const int t = threadIdx.x, lane = t & 63, w = t >> 6;
    const int wave_m = w >> 2, wave_n = w & 3;

    const int bid = blockIdx.x;
    const int sb = (bid & 7) * 32 + (bid >> 3);
    const int m0 = (sb >> 2) * 256, n0 = (sb & 3) * 256;

    const int lrow = lane >> 2;                               // 0..15
    const int lcol = ((lane & 3) ^ ((lane >> 3) & 3)) * 8;    // blk ^ ((row>>1)&3)
    const unsigned short* Ahp = Ah + (size_t)(m0 + w * 32 + lrow) * 1024 + lcol;
    const unsigned short* Alp = Al + (size_t)(m0 + w * 32 + lrow) * 1024 + lcol;
    const unsigned short* Bhp = Bh + (size_t)(n0 + w * 32 + lrow) * 1024 + lcol;
    const unsigned short* Blp = Bl + (size_t)(n0 + w * 32 + lrow) * 1024 + lcol;

    const int fr = lane & 15, g4 = lane >> 4;
    const int xo = (g4 ^ ((fr >> 1) & 3)) * 8;
    const int ao = (wave_m * 128 + fr) * 32 + xo;
    const int bo = (wave_n * 64 + fr) * 32 + xo;

    f32x4 acc[8][4];
#pragma unroll
    for (int i = 0; i < 8; ++i)
#pragma unroll
        for (int j = 0; j < 4; ++j) acc[i][j] = (f32x4)0.f;
    short8 ah[4], al[4], bh[4], bl[4];

    OUNIT(0, Bhp, 16384, 0); OUNIT(0, Blp, 24576, 0); OUNIT(0, Ahp, 0, 0); OUNIT(0, Alp, 8192, 0);
    OUNIT(1, Bhp, 16384, 1); OUNIT(1, Blp, 24576, 1); OUNIT(1, Ahp, 0, 1);
    VMC(6);
    __builtin_amdgcn_s_barrier();

#pragma unroll 1
    for (int it = 0; it < 15; ++it) {
        const int t1 = 2 * it + 1, t2 = 2 * it + 2, t3 = 2 * it + 3;
        OLDB(0); OLDA(0, 0);
        OUNIT(1, Alp, 8192, t1);
        OPH(0, 0);
        OUNIT(0, Bhp, 16384, t2);
        OPH(0, 2);
        OLDA(0, 4);
        OUNIT(0, Blp, 24576, t2);
        OPH(4, 0);
        OUNIT(0, Ahp, 0, t2);
        VMC(6);
        OPH(4, 2);
        OLDB(1); OLDA(1, 0);
        OUNIT(0, Alp, 8192, t2);
        OPH(0, 0);
        OUNIT(1, Bhp, 16384, t3);
        OPH(0, 2);
        OLDA(1, 4);
        OUNIT(1, Blp, 24576, t3);
        OPH(4, 0);
        OUNIT(1, Ahp, 0, t3);
        VMC(6);
        OPH(4, 2);
    }
    OLDB(0); OLDA(0, 0);
    OUNIT(1, Alp, 8192, 31);
    OPH(0, 0);
    OPH(0, 2);
    OLDA(0, 4);
    OPH(4, 0);
    VMC(0);
    OPH(4, 2);
    OLDB(1); OLDA(1, 0);
    OPH(0, 0);
    OPH(0, 2);
    OLDA(1, 4);
    OPH(4, 0);
    OPH(4, 2);

    const int ccol = lane & 15, crow = (lane >> 4) * 4;
#pragma unroll
    for (int m = 0; m < 8; ++m)
#pragma unroll
        for (int n = 0; n < 4; ++n) {
            float* cp = C + (size_t)(m0 + wave_m * 128 + m * 16 + crow) * 1024
                          + (n0 + wave_n * 64 + n * 16 + ccol);
#pragma unroll
            for (int r = 0; r < 4; ++r) cp[(size_t)r * 1024] = acc[m][n][r];
        }
}

// Per (b,h,seg): M_seg[d][v] = sk^T v, zsum[d], V^T bf16 tile — via MFMA.
// 4 waves: wave w owns d-rows [w*16, w*16+16) (A m-tile) and stages that
// d-chunk of ksT/vsT. sk split hi/lo (2 MFMA) for f32-class precision;
// v is already exact bf16. z via ones-MFMA. vsT tile doubles as vtg staging.
__global__ __launch_bounds__(256) void seg_stats(
    const unsigned short* __restrict__ kproj, const unsigned short* __restrict__ vproj,
    float* __restrict__ Mseg, float* __restrict__ zsum,
    unsigned short* __restrict__ vtg)
{
    __shared__ unsigned short sm_kh[64 * 64];   // skT hi (sz8)
    __shared__ unsigned short sm_kl[64 * 64];   // skT lo (sz8)
    __shared__ unsigned short sm_vt[64 * 64];   // vT exact bf16 (sz8)
    const int idx = blockIdx.x;
    const int seg = idx & 15;
    const int bh  = idx >> 4;
    const int h   = bh & 15;
    const int b   = bh >> 4;
    const size_t base = ((size_t)b * T_ + (size_t)seg * SEG_ + (size_t)h * 32) * D_;
    const unsigned short* kt = kproj + base;
    const unsigned short* vt = vproj + base;
    const int t    = threadIdx.x;
    const int lane = t & 63;
    const int w    = t >> 6;
    const int c16  = lane & 15;
    const int g4   = lane >> 4;
    const int lr   = t >> 2;
    const int lc   = (t & 3) * 16;

    short8 bones;
#pragma unroll
    for (int j = 0; j < 8; ++j) bones[j] = (short)0x3F80;   // bf16 1.0

    f32x4 acc[4];                                // n-tiles 0..3 for m-tile w
#pragma unroll
    for (int nt = 0; nt < 4; ++nt) acc[nt] = (f32x4)0.f;
    f32x4 zacc = (f32x4)0.f;

    for (int c0 = 0; c0 < SEG_; c0 += 64) {
        __syncthreads();   // previous chunk's frag reads / vtg readback done
        {   // transpose-stage: lane = t-row, wave = 16-wide d-chunk.
            // write granule: 8 lanes (l&7) fill consecutive ushorts of one
            // 16B granule -> conflict-free.
            const int row = c0 + lane;
            const unsigned short* kp = kt + (size_t)row * 64 + w * 16;
            const unsigned short* vp = vt + (size_t)row * 64 + w * 16;
            ushort8 k0 = *(const ushort8*)kp, k1 = *(const ushort8*)(kp + 8);
            ushort8 v0 = *(const ushort8*)vp, v1 = *(const ushort8*)(vp + 8);
            const int tb = lane >> 3, tl = lane & 7;
#pragma unroll
            for (int e = 0; e < 8; ++e) {
                const float f0 = elu1(bf2f(k0[e]));
                const unsigned short h0 = f2bf(f0), l0 = f2bf(f0 - bf2f(h0));
                const float f1 = elu1(bf2f(k1[e]));
                const unsigned short h1 = f2bf(f1), l1 = f2bf(f1 - bf2f(h1));
                const int a0 = sz8(w * 16 + e,     tb) + tl;
                const int a1 = sz8(w * 16 + 8 + e, tb) + tl;
                sm_kh[a0] = h0; sm_kl[a0] = l0; sm_vt[a0] = v0[e];
                sm_kh[a1] = h1; sm_kl[a1] = l1; sm_vt[a1] = v1[e];
            }
        }
        __syncthreads();
        // MFMA: C[d][v] += skT[d][t] * vT[v][t], k-dim = t (2 k-steps of 32)
#pragma unroll
        for (int ks = 0; ks < 2; ++ks) {
            const short8 ahh = *(const short8*)&sm_kh[sz8(w * 16 + c16, ks * 4 + g4)];
            const short8 alo = *(const short8*)&sm_kl[sz8(w * 16 + c16, ks * 4 + g4)];
            zacc = __builtin_amdgcn_mfma_f32_16x16x32_bf16(ahh, bones, zacc, 0, 0, 0);
            zacc = __builtin_amdgcn_mfma_f32_16x16x32_bf16(alo, bones, zacc, 0, 0, 0);
#pragma unroll
            for (int nt = 0; nt < 4; ++nt) {
                const short8 bv = *(const short8*)&sm_vt[sz8(nt * 16 + c16, ks * 4 + g4)];
                acc[nt] = __builtin_amdgcn_mfma_f32_16x16x32_bf16(ahh, bv, acc[nt], 0, 0, 0);
                acc[nt] = __builtin_amdgcn_mfma_f32_16x16x32_bf16(alo, bv, acc[nt], 0, 0, 0);
            }
        }
        {   // vtg writeback for this chunk (same pattern as attn epilogue)
            unsigned short* vo = vtg + ((size_t)idx * 64 + lr) * 512 + c0 + lc;
            *(ushort8*)vo       = *(const ushort8*)&sm_vt[sz8(lr, lc >> 3)];
            *(ushort8*)(vo + 8) = *(const ushort8*)&sm_vt[sz8(lr, (lc >> 3) + 1)];
        }
    }
    // epilogue: M (C-layout rows d = w*16 + g4*4 + r, cols v = nt*16 + c16), z
    float* Mout = Mseg + (size_t)idx * 4096;
#pragma unroll
    for (int nt = 0; nt < 4; ++nt)
#pragma unroll
        for (int r = 0; r < 4; ++r)
            Mout[(size_t)(w * 16 + g4 * 4 + r) * 64 + nt * 16 + c16] = acc[nt][r];
    if (c16 == 0) {
#pragma unroll
        for (int r = 0; r < 4; ++r)
            zsum[(size_t)idx * 64 + w * 16 + g4 * 4 + r] = zacc[r];
    }
}

// Per (b,h,slice): in-place exclusive prefix of M (1024-float slice),
// inclusive prefix of z (slice 0). 128 blocks.
__global__ __launch_bounds__(256) void prefix_scan(
    float* __restrict__ M, float* __restrict__ z)
{
    const int blk = blockIdx.x;
    const int bh  = blk >> 2, sl = blk & 3;
    const int t   = threadIdx.x;
    const size_t off = (size_t)bh * NSEG_ * 4096 + (size_t)sl * 1024 + (size_t)t * 4;
    float4 run = make_float4(0.f, 0.f, 0.f, 0.f);
    float runz = 0.f;
    for (int seg = 0; seg < NSEG_; ++seg) {
        const size_t o = off + (size_t)seg * 4096;
        float4 m = *(const float4*)(M + o);
        *(float4*)(M + o) = run;
        run.x += m.x; run.y += m.y; run.z += m.z; run.w += m.w;
        if (sl == 0 && t < 64) {
            const size_t oz = ((size_t)bh * NSEG_ + seg) * 64 + t;
            runz += z[oz];
            z[oz] = runz;
        }
    }
}

// MFMA flash attention per (b,h,seg,64-row q-chunk). bf16 q/k/v inputs.
__global__ __launch_bounds__(256) void attn_mfma(
    const unsigned short* __restrict__ qproj, const unsigned short* __restrict__ kproj,
    const unsigned short* __restrict__ vtg, const float* __restrict__ memb,
    const float* __restrict__ Zaf, const float* __restrict__ betas,
    unsigned short* __restrict__ ath, unsigned short* __restrict__ atl)
{
    __shared__ unsigned short sm_k[64 * 64];   // k bf16 ; epilogue att_hi (swizzled)
    __shared__ unsigned short sm_v[64 * 64];   // V^T bf16 ; epilogue att_lo (swizzled)
    __shared__ unsigned short sm_p[64 * 64];   // mem^T bf16, then P bf16 (swizzled)
    __shared__ float Zsh[64], gsh[64];

    const int idx  = blockIdx.x;
    // XCD-aware remap: bids g*64 + qc*8 + x -> rest = g*8 + x, so one rest's
    // 8 qc-blocks share bid%8 (same XCD) inside a 64-bid window (co-resident).
    const int qc   = (idx >> 3) & 7;
    const int rest = (idx >> 6) * 8 + (idx & 7);
    const int bh   = rest >> 4;
    const int seg  = rest & 15;
    const int h    = bh & 15;
    const int b    = bh >> 4;
    const size_t base = ((size_t)b * T_ + (size_t)seg * SEG_ + (size_t)h * 32) * D_;

    const int t    = threadIdx.x;
    const int lane = t & 63;
    const int w    = t >> 6;
    const int c16  = lane & 15;
    const int g4   = lane >> 4;
    const int lr   = t >> 2;
    const int lc   = (t & 3) * 16;

    const unsigned short* qt = qproj + base + (size_t)qc * 4096;
    const unsigned short* kt = kproj + base;
    const unsigned short* vt = vtg + (size_t)rest * (64 * 512);
    const float* mb = memb + (size_t)rest * 4096;

    if (t < 64) {
        Zsh[t] = Zaf[(size_t)rest * 64 + t];
        gsh[t] = 1.f / (1.f + __expf(-betas[h * 64 + t]));
    }

    // q fragments (A-layout: m = w*16+c16, k = g4*8 + ks*32 + j), sq, rowsum
    short8 qh[2], sqh[2];
    float rowsum = 0.f;
#pragma unroll
    for (int ks = 0; ks < 2; ++ks) {
        const unsigned short* qp = qt + (size_t)(w * 16 + c16) * 64 + g4 * 8 + ks * 32;
        ushort8 qv = *(const ushort8*)qp;
        short8 qf, sf;
#pragma unroll
        for (int j = 0; j < 8; ++j) {
            float e = elu1(bf2f(qv[j]));
            rowsum += e;
            qf[j] = (short)qv[j];
            sf[j] = (short)f2bf(e);
        }
        qh[ks] = qf; sqh[ks] = sf;
    }
    rowsum += __shfl_xor(rowsum, 16);
    rowsum += __shfl_xor(rowsum, 32);

    // stage mem^T (bf16) into sm_p (swizzled scalar writes)
    {
        const float* mp = mb + (size_t)lr * 64 + lc;
#pragma unroll
        for (int u = 0; u < 4; ++u) {
            float4 m4 = *(const float4*)(mp + u * 4);
            sm_p[sz8(lc + u * 4 + 0, lr >> 3) + (lr & 7)] = f2bf(m4.x);
            sm_p[sz8(lc + u * 4 + 1, lr >> 3) + (lr & 7)] = f2bf(m4.y);
            sm_p[sz8(lc + u * 4 + 2, lr >> 3) + (lr & 7)] = f2bf(m4.z);
            sm_p[sz8(lc + u * 4 + 3, lr >> 3) + (lr & 7)] = f2bf(m4.w);
        }
    }
    __syncthreads();

    // num = sq @ mem  (B-operand = mem^T[v][d])
    f32x4 numf[4];
#pragma unroll
    for (int nf = 0; nf < 4; ++nf) numf[nf] = (f32x4)0.f;
#pragma unroll
    for (int ks = 0; ks < 2; ++ks)
#pragma unroll
        for (int nf = 0; nf < 4; ++nf) {
            short8 bm = *(const short8*)&sm_p[sz8(nf * 16 + c16, g4 + ks * 4)];
            numf[nf] = __builtin_amdgcn_mfma_f32_16x16x32_bf16(sqh[ks], bm, numf[nf], 0, 0, 0);
        }

    // ones B-frag (bf16 1.0) for row-sum-via-MFMA
    short8 bones;
#pragma unroll
    for (int j = 0; j < 8; ++j) bones[j] = (short)0x3F80;

    f32x4 o[4];
#pragma unroll
    for (int nf = 0; nf < 4; ++nf) o[nf] = (f32x4)0.f;
    float mrow[4] = {-1e30f, -1e30f, -1e30f, -1e30f};
    float lrow[4] = {0.f, 0.f, 0.f, 0.f};

    for (int kb = 0; kb < 8; ++kb) {
        __syncthreads();
        {   // stage k and V^T (both already bf16 — swizzled 16B copies)
            const unsigned short* kp = kt + (size_t)(kb * 64 + lr) * 64 + lc;
            *(ushort8*)&sm_k[sz8(lr, lc >> 3)]       = *(const ushort8*)kp;
            *(ushort8*)&sm_k[sz8(lr, (lc >> 3) + 1)] = *(const ushort8*)(kp + 8);
            const unsigned short* vp = vt + (size_t)lr * 512 + kb * 64 + lc;
            *(ushort8*)&sm_v[sz8(lr, lc >> 3)]       = *(const ushort8*)vp;
            *(ushort8*)&sm_v[sz8(lr, (lc >> 3) + 1)] = *(const ushort8*)(vp + 8);
        }
        __syncthreads();

        // scores S = Q @ K^T
        f32x4 s[4];
#pragma unroll
        for (int nf = 0; nf < 4; ++nf) s[nf] = (f32x4)0.f;
#pragma unroll
        for (int ks = 0; ks < 2; ++ks)
#pragma unroll
            for (int nf = 0; nf < 4; ++nf) {
                short8 bk = *(const short8*)&sm_k[sz8(nf * 16 + c16, g4 + ks * 4)];
                s[nf] = __builtin_amdgcn_mfma_f32_16x16x32_bf16(qh[ks], bk, s[nf], 0, 0, 0);
            }
#pragma unroll
        for (int nf = 0; nf < 4; ++nf) s[nf] *= 0.125f;

        // T13 deferred max: wave-wide __all over per-lane partial maxima
        // covers the c16 reduction lanes for free.
        float pmax[4];
#pragma unroll
        for (int r = 0; r < 4; ++r)
            pmax[r] = fmaxf(fmaxf(s[0][r], s[1][r]), fmaxf(s[2][r], s[3][r]));
        const bool ok = pmax[0] <= mrow[0] + 8.f && pmax[1] <= mrow[1] + 8.f &&
                        pmax[2] <= mrow[2] + 8.f && pmax[3] <= mrow[3] + 8.f;
        if (!__all(ok)) {
#pragma unroll
            for (int r = 0; r < 4; ++r) {
                float mx = pmax[r];
                mx = fmaxf(mx, __shfl_xor(mx, 1));
                mx = fmaxf(mx, __shfl_xor(mx, 2));
                mx = fmaxf(mx, __shfl_xor(mx, 4));
                mx = fmaxf(mx, __shfl_xor(mx, 8));
                const float mnew = fmaxf(mrow[r], mx);
                const float corr = __expf(mrow[r] - mnew);
                mrow[r] = mnew;
                lrow[r] *= corr;
#pragma unroll
                for (int nf = 0; nf < 4; ++nf) o[nf][r] *= corr;
            }
        }
#pragma unroll
        for (int nf = 0; nf < 4; ++nf)
#pragma unroll
            for (int r = 0; r < 4; ++r) {
                s[nf][r] = __expf(s[nf][r] - mrow[r]);
                // publish P (C-layout -> A-layout), same-wave rows only
                sm_p[sz8(w * 16 + g4 * 4 + r, nf * 2 + (c16 >> 3)) + (c16 & 7)] =
                    f2bf(s[nf][r]);
            }

        // O += P @ V ; row-sum via ones-MFMA (denominator from the same bf16 P)
        f32x4 psum = (f32x4)0.f;
#pragma unroll
        for (int ks = 0; ks < 2; ++ks) {
            short8 pa = *(const short8*)&sm_p[sz8(w * 16 + c16, g4 + ks * 4)];
            psum = __builtin_amdgcn_mfma_f32_16x16x32_bf16(pa, bones, psum, 0, 0, 0);
#pragma unroll
            for (int nf = 0; nf < 4; ++nf) {
                short8 bv = *(const short8*)&sm_v[sz8(nf * 16 + c16, g4 + ks * 4)];
                o[nf] = __builtin_amdgcn_mfma_f32_16x16x32_bf16(pa, bv, o[nf], 0, 0, 0);
            }
        }
#pragma unroll
        for (int r = 0; r < 4; ++r) lrow[r] += psum[r];
    }

    __syncthreads();   // staging done — reuse sm_k/sm_v for att hi/lo

    float rs[4], invl[4];
#pragma unroll
    for (int r = 0; r < 4; ++r) {
        rs[r]   = __shfl(rowsum, (g4 << 2) + r);
        invl[r] = 1.f / lrow[r];
    }
#pragma unroll
    for (int nf = 0; nf < 4; ++nf) {
        const int col = nf * 16 + c16;
        const float Zc = Zsh[col], gc = gsh[col];
        const float izc = 1.f / Zc;
#pragma unroll
        for (int r = 0; r < 4; ++r) {
            const float adot = o[nf][r] * invl[r];
            const float amem = numf[nf][r] * izc / rs[r];
            const float res  = gc * amem + (1.f - gc) * adot;
            const unsigned short hv = f2bf(res);
            const unsigned short lv = f2bf(res - bf2f(hv));
            const int row = w * 16 + g4 * 4 + r;
            const int so  = sz8(row, nf * 2 + (c16 >> 3)) + (c16 & 7);
            sm_k[so] = hv;
            sm_v[so] = lv;
        }
    }
    __syncthreads();
    {
        const size_t ob = base + (size_t)(qc * 64 + lr) * 64 + lc;
        *(ushort8*)(ath + ob)     = *(const ushort8*)&sm_k[sz8(lr, lc >> 3)];
        *(ushort8*)(ath + ob + 8) = *(const ushort8*)&sm_k[sz8(lr, (lc >> 3) + 1)];
        *(ushort8*)(atl + ob)     = *(const ushort8*)&sm_v[sz8(lr, lc >> 3)];
        *(ushort8*)(atl + ob + 8) = *(const ushort8*)&sm_v[sz8(lr, (lc >> 3) + 1)];
    }
}

extern "C" void kernel_launch(void* const* d_in, const int* in_sizes, int n_in,
                              void* d_out, int out_size, void* d_ws, size_t ws_size,
                              hipStream_t stream) {
    const float* x     = (const float*)d_in[0];
    const float* Wq    = (const float*)d_in[1];
    const float* Wk    = (const float*)d_in[2];
    const float* Wv    = (const float*)d_in[3];
    const float* Wout  = (const float*)d_in[4];
    const float* betas = (const float*)d_in[5];
    float* out = (float*)d_out;
    (void)d_ws; (void)ws_size;

    float *M, *z;
    unsigned short *qb, *kb, *vb, *xh, *wqkv, *vt, *ath, *atl, *woh, *wol;
    hipGetSymbolAddress((void**)&qb,   HIP_SYMBOL(g_qb));
    hipGetSymbolAddress((void**)&kb,   HIP_SYMBOL(g_kb));
    hipGetSymbolAddress((void**)&vb,   HIP_SYMBOL(g_vb));
    hipGetSymbolAddress((void**)&xh,   HIP_SYMBOL(g_xh));
    hipGetSymbolAddress((void**)&wqkv, HIP_SYMBOL(g_wqkv));
    hipGetSymbolAddress((void**)&vt,   HIP_SYMBOL(g_vt));
    hipGetSymbolAddress((void**)&ath,  HIP_SYMBOL(g_ath));
    hipGetSymbolAddress((void**)&atl,  HIP_SYMBOL(g_atl));
    hipGetSymbolAddress((void**)&woh,  HIP_SYMBOL(g_woh));
    hipGetSymbolAddress((void**)&wol,  HIP_SYMBOL(g_wol));
    hipGetSymbolAddress((void**)&M,    HIP_SYMBOL(g_M));
    hipGetSymbolAddress((void**)&z,    HIP_SYMBOL(g_z));

    // fused prologue: x + Wq/Wk/Wv casts + Wout split in one launch
    const int nXB = (int)(NPROJ / 1024), nWB = (int)(NW / 1024);
    prep_cast<<<nXB + 4 * nWB, 256, 0, stream>>>(x, Wq, Wk, Wv, Wout,
                                                 xh, wqkv, woh, wol);

    gemm_qkv8<<<dim3(768), 512, 0, stream>>>(xh, wqkv, qb, kb, vb);
    seg_stats<<<B_ * H_ * NSEG_, 256, 0, stream>>>(kb, vb, M, z, vt);
    prefix_scan<<<B_ * H_ * 4, 256, 0, stream>>>(M, z);
    attn_mfma<<<B_ * H_ * NSEG_ * 8, 256, 0, stream>>>(qb, kb, vt, M, z, betas, ath, atl);
    gemm_bt8<<<dim3(256), 512, 0, stream>>>(ath, atl, woh, wol, out);
}

// Round 6
// 483.682 us; speedup vs baseline: 1.4229x; 1.0043x over previous
//
#include <hip/hip_runtime.h>

// CompressiveMemory — round 11.
//  * attn_mfma restructured: ONE block per (b,h,seg) rest (512 blocks x 512
//    threads), K (64KB) + V^T (64KB) + mem^T (8KB) staged into LDS ONCE
//    (was: 8 qc-blocks each re-staging the same 128KB through L2 with 16
//    barrier pairs — staging machinery dominated, MFMA was ~0.9us/block).
//    kb inner loop is now BARRIER-FREE (persistent K/V; P-publish is
//    wave-private rows). 4 q-sub-tiles of 128 rows; epilogue reuses smP
//    (16KB) as hi/lo scratch. All per-row math bit-identical to round 10
//    -> absmax must stay exactly 2.441406e-4 (indexing canary).
//  * qkv8 / bt8 / seg_stats / prefix / prep unchanged (rounds 6-10).
//  * Ledger: qkv8 @136us is phase-structure-limited (acc=128 VGPR forbids
//    2 blocks/CU at 256^2); bt8 ~125us (same FLOP as qkv8) is next target.

#define H_ 16
#define SEG_ 512
#define NSEG_ 16
#define B_ 2
#define T_ 8192
#define D_ 1024
#define BT_ 16384

#define NPROJ ((size_t)BT_ * D_)   // 16,777,216
#define NW ((size_t)D_ * D_)       // 1,048,576

__device__ unsigned short g_qb[NPROJ], g_kb[NPROJ], g_vb[NPROJ];   // bf16 projections
__device__ unsigned short g_xh[NPROJ];
__device__ unsigned short g_wqkv[3 * NW];                          // [Wq;Wk;Wv] bf16
__device__ unsigned short g_ath[NPROJ], g_atl[NPROJ];
__device__ unsigned short g_woh[NW], g_wol[NW];
__device__ unsigned short g_vt[(size_t)512 * 64 * 512];            // per-tile V^T bf16
__device__ float g_M[(size_t)512 * 4096];
__device__ float g_z[(size_t)512 * 64];

typedef __attribute__((ext_vector_type(8))) short short8;
typedef __attribute__((ext_vector_type(8))) unsigned short ushort8;
typedef __attribute__((ext_vector_type(4))) float f32x4;

__device__ __forceinline__ float elu1(float x) {
    return x > 0.f ? x + 1.f : __expf(x);
}
__device__ __forceinline__ unsigned short f2bf(float x) {
    unsigned u = __float_as_uint(x);
    u += 0x7fffu + ((u >> 16) & 1u);           // RNE
    return (unsigned short)(u >> 16);
}
__device__ __forceinline__ float bf2f(unsigned short h) {
    return __uint_as_float((unsigned)h << 16);
}
__device__ __forceinline__ void load_lds16(const unsigned short* g, unsigned short* l) {
    __builtin_amdgcn_global_load_lds(
        (const __attribute__((address_space(1))) unsigned int*)g,
        (__attribute__((address_space(3))) unsigned int*)l, 16, 0, 0);
}
// ushort offset of (row, 8-ushort block blk) in a [*][64]-bf16 LDS tile,
// XOR-swizzled so column-slice b128 reads hit the uniform bank floor.
__device__ __forceinline__ int sz8(int row, int blk) {
    return row * 64 + ((blk ^ (row & 7)) << 3);
}

// Fused prologue: cast x, Wq, Wk, Wv to bf16; split Wout into hi/lo.
__global__ __launch_bounds__(256) void prep_cast(
    const float* __restrict__ x, const float* __restrict__ Wq,
    const float* __restrict__ Wk, const float* __restrict__ Wv,
    const float* __restrict__ Wout,
    unsigned short* __restrict__ xh, unsigned short* __restrict__ wqkv,
    unsigned short* __restrict__ woh, unsigned short* __restrict__ wol)
{
    const int b = blockIdx.x;
    const int nXB = (int)(NPROJ / 1024);           // 16384
    const int nWB = (int)(NW / 1024);              // 1024
    if (b < nXB + 3 * nWB) {
        const float* in;
        unsigned short* out;
        int i;
        if (b < nXB) {
            in = x; out = xh; i = (b * 256 + threadIdx.x) * 4;
        } else {
            const int wsel = (b - nXB) / nWB;      // 0,1,2
            const int wb   = (b - nXB) % nWB;
            in  = wsel == 0 ? Wq : (wsel == 1 ? Wk : Wv);
            out = wqkv + (size_t)wsel * NW;
            i = (wb * 256 + threadIdx.x) * 4;
        }
        float4 v = *(const float4*)(in + i);
        ushort4 h;
        h.x = f2bf(v.x); h.y = f2bf(v.y); h.z = f2bf(v.z); h.w = f2bf(v.w);
        *(ushort4*)(out + i) = h;
    } else {
        const int wb = b - nXB - 3 * nWB;
        const int i = (wb * 256 + threadIdx.x) * 4;
        float4 v = *(const float4*)(Wout + i);
        ushort4 h, l;
        h.x = f2bf(v.x); l.x = f2bf(v.x - bf2f(h.x));
        h.y = f2bf(v.y); l.y = f2bf(v.y - bf2f(h.y));
        h.z = f2bf(v.z); l.z = f2bf(v.z - bf2f(h.z));
        h.w = f2bf(v.w); l.w = f2bf(v.w - bf2f(h.w));
        *(ushort4*)(woh + i) = h;
        *(ushort4*)(wol + i) = l;
    }
}

// ---------------------------------------------------------------------------
// Fused QKV GEMM, 8-phase 256x256 pipeline (unchanged from round 9).
// ---------------------------------------------------------------------------

#define VMC(N) asm volatile("s_waitcnt vmcnt(" #N ")" ::: "memory")

#define STAGE_A(p, h, tt, u) \
    load_lds16(Aw + ((h) * 128 + (u) * 8) * 1024 + (tt) * 64, \
               &lds[(p) * 32768 + ((h) * 128 + w * 16 + (u) * 8) * 64])
#define STAGE_B(p, h, tt, u) \
    load_lds16(Bww + ((h) * 128 + (u) * 8) * 1024 + (tt) * 64, \
               &lds[(p) * 32768 + 16384 + ((h) * 128 + w * 16 + (u) * 8) * 64])
#define STAGE_AH(p, h, tt) do { STAGE_A(p, h, tt, 0); STAGE_A(p, h, tt, 1); } while (0)
#define STAGE_BH(p, h, tt) do { STAGE_B(p, h, tt, 0); STAGE_B(p, h, tt, 1); } while (0)

#define LDA(PBUF, MLO) do { \
    _Pragma("unroll") for (int m2 = 0; m2 < 4; ++m2) \
    _Pragma("unroll") for (int ks2 = 0; ks2 < 2; ++ks2) \
        a[m2][ks2] = *(const short8*)&lds[(PBUF) * 32768 + aoff[ks2] + ((MLO) + m2) * 1024]; \
} while (0)

#define LDB(PBUF) do { \
    _Pragma("unroll") for (int n2 = 0; n2 < 4; ++n2) \
    _Pragma("unroll") for (int ks2 = 0; ks2 < 2; ++ks2) \
        b[n2][ks2] = *(const short8*)&lds[(PBUF) * 32768 + boff[ks2] + n2 * 1024]; \
} while (0)

#define MFMA_QUAD(MLO, NLO) do { \
    _Pragma("unroll") for (int m2 = 0; m2 < 4; ++m2) \
    _Pragma("unroll") for (int n2 = 0; n2 < 2; ++n2) \
    _Pragma("unroll") for (int ks2 = 0; ks2 < 2; ++ks2) \
        acc[(MLO) + m2][(NLO) + n2] = __builtin_amdgcn_mfma_f32_16x16x32_bf16( \
            a[m2][ks2], b[(NLO) + n2][ks2], acc[(MLO) + m2][(NLO) + n2], 0, 0, 0); \
} while (0)

#define PH(MLO, NLO) do { \
    __builtin_amdgcn_s_barrier(); \
    asm volatile("s_waitcnt lgkmcnt(0)" ::: "memory"); \
    __builtin_amdgcn_sched_barrier(0); \
    __builtin_amdgcn_s_setprio(1); \
    MFMA_QUAD(MLO, NLO); \
    __builtin_amdgcn_s_setprio(0); \
    __builtin_amdgcn_sched_barrier(0); \
    __builtin_amdgcn_s_barrier(); \
} while (0)

__global__ __launch_bounds__(512, 2) void gemm_qkv8(
    const unsigned short* __restrict__ A, const unsigned short* __restrict__ Bw,
    unsigned short* __restrict__ Q, unsigned short* __restrict__ Kp,
    unsigned short* __restrict__ V)
{
    __shared__ unsigned short lds[65536];   // 128KB: [buf0 A|B][buf1 A|B]
    const int t = threadIdx.x, lane = t & 63, w = t >> 6;
    const int wave_m = w >> 2, wave_n = w & 3;

    // XCD-bijective swizzle: 768 blocks = 96 * 8.
    const int bid = blockIdx.x;
    const int sb = (bid & 7) * 96 + (bid >> 3);
    const int mb = sb / 12, nb = sb % 12;
    const int m0 = mb * 256, n0 = nb * 256;

    // staging per-lane constants (LDS linear; swizzle folded into global col)
    const int lrow = lane >> 3;                       // 0..7
    const int lcol = ((lane & 7) ^ lrow) * 8;         // swizzled ushort col
    const unsigned short* Aw  = A  + (size_t)(m0 + w * 16 + lrow) * 1024 + lcol;
    const unsigned short* Bww = Bw + (size_t)(n0 + w * 16 + lrow) * 1024 + lcol;

    // frag-read per-lane ushort offsets (same involution as the stage side)
    const int fr = lane & 15, g4 = lane >> 4;
    int aoff[2], boff[2];
#pragma unroll
    for (int ks2 = 0; ks2 < 2; ++ks2) {
        aoff[ks2] = (wave_m * 128 + fr) * 64 + (((ks2 * 4 + g4) ^ (fr & 7)) * 8);
        boff[ks2] = 16384 + (wave_n * 64 + fr) * 64 + (((ks2 * 4 + g4) ^ (fr & 7)) * 8);
    }

    f32x4 acc[8][4];
#pragma unroll
    for (int i = 0; i < 8; ++i)
#pragma unroll
        for (int j = 0; j < 4; ++j) acc[i][j] = (f32x4)0.f;
    short8 a[4][2], b[4][2];

    // Prologue: tile0 (buf0) fully + tile1 (buf1) B0,B1,A0. vmcnt(6) -> tile0 landed.
    STAGE_BH(0, 0, 0); STAGE_BH(0, 1, 0); STAGE_AH(0, 0, 0); STAGE_AH(0, 1, 0);
    STAGE_BH(1, 0, 1); STAGE_BH(1, 1, 1); STAGE_AH(1, 0, 1);
    VMC(6);
    __builtin_amdgcn_s_barrier();

#pragma unroll 1
    for (int it = 0; it < 7; ++it) {
        const int t1 = 2 * it + 1, t2 = 2 * it + 2, t3 = 2 * it + 3;
        LDB(0); LDA(0, 0);
        STAGE_AH(1, 1, t1);
        PH(0, 0);
        STAGE_BH(0, 0, t2);
        PH(0, 2);
        LDA(0, 4);
        STAGE_BH(0, 1, t2);
        PH(4, 0);
        STAGE_AH(0, 0, t2);
        VMC(6);
        PH(4, 2);
        LDB(1); LDA(1, 0);
        STAGE_AH(0, 1, t2);
        PH(0, 0);
        STAGE_BH(1, 0, t3);
        PH(0, 2);
        LDA(1, 4);
        STAGE_BH(1, 1, t3);
        PH(4, 0);
        STAGE_AH(1, 0, t3);
        VMC(6);
        PH(4, 2);
    }
    LDB(0); LDA(0, 0);
    STAGE_AH(1, 1, 15);
    PH(0, 0);
    PH(0, 2);
    LDA(0, 4);
    PH(4, 0);
    VMC(0);
    PH(4, 2);
    LDB(1); LDA(1, 0);
    PH(0, 0);
    PH(0, 2);
    LDA(1, 4);
    PH(4, 0);
    PH(4, 2);

    // Epilogue: acc -> bf16 -> LDS -> coalesced store (row&31 XOR, round 9).
    const int ccol = lane & 15, crow = (lane >> 4) * 4;
#pragma unroll
    for (int m = 0; m < 8; ++m)
#pragma unroll
        for (int n = 0; n < 4; ++n) {
            const int col = wave_n * 64 + n * 16 + ccol;
            const int cb = col >> 3, cl = col & 7;
#pragma unroll
            for (int r = 0; r < 4; ++r) {
                const int row = wave_m * 128 + m * 16 + crow + r;
                lds[row * 256 + ((cb ^ (row & 31)) << 3) + cl] = f2bf(acc[m][n][r]);
            }
        }
    __syncthreads();
    const int which = n0 >> 10, col0 = n0 & 1023;
    unsigned short* outp = which == 0 ? Q : (which == 1 ? Kp : V);
    const int orow = t >> 1, och = (t & 1) * 128;
    unsigned short* gp = outp + (size_t)(m0 + orow) * 1024 + col0 + och;
#pragma unroll
    for (int u = 0; u < 128; u += 8) {
        const int bo = (och + u) >> 3;
        *(ushort8*)(gp + u) = *(const ushort8*)&lds[orow * 256 + ((bo ^ (orow & 31)) << 3)];
    }
}

// ---------------------------------------------------------------------------
// Out-GEMM, 8-phase 256x256/BK=32 split-bf16 pipeline (unchanged, round 7).
// ---------------------------------------------------------------------------

#define OSTG(p, arrp, aroff, tt, u) \
    load_lds16(arrp + (size_t)(u) * 16 * 1024 + (tt) * 32, \
               &lds[(p) * 32768 + (aroff) + (w * 32 + (u) * 16) * 32])
#define OUNIT(p, arrp, aroff, tt) do { OSTG(p, arrp, aroff, tt, 0); OSTG(p, arrp, aroff, tt, 1); } while (0)

#define OLDA(PBUF, MLO) do { \
    _Pragma("unroll") for (int m2 = 0; m2 < 4; ++m2) { \
        ah[m2] = *(const short8*)&lds[(PBUF) * 32768 +         ao + ((MLO) + m2) * 512]; \
        al[m2] = *(const short8*)&lds[(PBUF) * 32768 +  8192 + ao + ((MLO) + m2) * 512]; \
    } \
} while (0)

#define OLDB(PBUF) do { \
    _Pragma("unroll") for (int n2 = 0; n2 < 4; ++n2) { \
        bh[n2] = *(const short8*)&lds[(PBUF) * 32768 + 16384 + bo + n2 * 512]; \
        bl[n2] = *(const short8*)&lds[(PBUF) * 32768 + 24576 + bo + n2 * 512]; \
    } \
} while (0)

#define OQUAD(MLO, NLO) do { \
    _Pragma("unroll") for (int m2 = 0; m2 < 4; ++m2) \
    _Pragma("unroll") for (int n2 = 0; n2 < 2; ++n2) { \
        acc[(MLO) + m2][(NLO) + n2] = __builtin_amdgcn_mfma_f32_16x16x32_bf16( \
            ah[m2], bh[(NLO) + n2], acc[(MLO) + m2][(NLO) + n2], 0, 0, 0); \
        acc[(MLO) + m2][(NLO) + n2] = __builtin_amdgcn_mfma_f32_16x16x32_bf16( \
            al[m2], bh[(NLO) + n2], acc[(MLO) + m2][(NLO) + n2], 0, 0, 0); \
        acc[(MLO) + m2][(NLO) + n2] = __builtin_amdgcn_mfma_f32_16x16x32_bf16( \
            ah[m2], bl[(NLO) + n2], acc[(MLO) + m2][(NLO) + n2], 0, 0, 0); \
    } \
} while (0)

#define OPH(MLO, NLO) do { \
    __builtin_amdgcn_s_barrier(); \
    asm volatile("s_waitcnt lgkmcnt(0)" ::: "memory"); \
    __builtin_amdgcn_sched_barrier(0); \
    __builtin_amdgcn_s_setprio(1); \
    OQUAD(MLO, NLO); \
    __builtin_amdgcn_s_setprio(0); \
    __builtin_amdgcn_sched_barrier(0); \
    __builtin_amdgcn_s_barrier(); \
} while (0)

__global__ __launch_bounds__(512, 2) void gemm_bt8(
    const unsigned short* __restrict__ Ah, const unsigned short* __restrict__ Al,
    const unsigned short* __restrict__ Bh, const unsigned short* __restrict__ Bl,
    float* __restrict__ C)
{
    __shared__ unsigned short lds[65536];   // 128KB: [buf0 Ah|Al|Bh|Bl][buf1 ...]
    const int t = threadIdx.x, lane = t & 63, w = t >> 6;
    const int wave_m = w >> 2, wave_n = w & 3;

    const int bid = blockIdx.x;
    const int sb = (bid & 7) * 32 + (bid >> 3);
    const int m0 = (sb >> 2) * 256, n0 = (sb & 3) * 256;

    const int lrow = lane >> 2;                               // 0..15
    const int lcol = ((lane & 3) ^ ((lane >> 3) & 3)) * 8;    // blk ^ ((row>>1)&3)
    const unsigned short* Ahp = Ah + (size_t)(m0 + w * 32 + lrow) * 1024 + lcol;
    const unsigned short* Alp = Al + (size_t)(m0 + w * 32 + lrow) * 1024 + lcol;
    const unsigned short* Bhp = Bh + (size_t)(n0 + w * 32 + lrow) * 1024 + lcol;
    const unsigned short* Blp = Bl + (size_t)(n0 + w * 32 + lrow) * 1024 + lcol;

    const int fr = lane & 15, g4 = lane >> 4;
    const int xo = (g4 ^ ((fr >> 1) & 3)) * 8;
    const int ao = (wave_m * 128 + fr) * 32 + xo;
    const int bo = (wave_n * 64 + fr) * 32 + xo;

    f32x4 acc[8][4];
#pragma unroll
    for (int i = 0; i < 8; ++i)
#pragma unroll
        for (int j = 0; j < 4; ++j) acc[i][j] = (f32x4)0.f;
    short8 ah[4], al[4], bh[4], bl[4];

    OUNIT(0, Bhp, 16384, 0); OUNIT(0, Blp, 24576, 0); OUNIT(0, Ahp, 0, 0); OUNIT(0, Alp, 8192, 0);
    OUNIT(1, Bhp, 16384, 1); OUNIT(1, Blp, 24576, 1); OUNIT(1, Ahp, 0, 1);
    VMC(6);
    __builtin_amdgcn_s_barrier();

#pragma unroll 1
    for (int it = 0; it < 15; ++it) {
        const int t1 = 2 * it + 1, t2 = 2 * it + 2, t3 = 2 * it + 3;
        OLDB(0); OLDA(0, 0);
        OUNIT(1, Alp, 8192, t1);
        OPH(0, 0);
        OUNIT(0, Bhp, 16384, t2);
        OPH(0, 2);
        OLDA(0, 4);
        OUNIT(0, Blp, 24576, t2);
        OPH(4, 0);
        OUNIT(0, Ahp, 0, t2);
        VMC(6);
        OPH(4, 2);
        OLDB(1); OLDA(1, 0);
        OUNIT(0, Alp, 8192, t2);
        OPH(0, 0);
        OUNIT(1, Bhp, 16384, t3);
        OPH(0, 2);
        OLDA(1, 4);
        OUNIT(1, Blp, 24576, t3);
        OPH(4, 0);
        OUNIT(1, Ahp, 0, t3);
        VMC(6);
        OPH(4, 2);
    }
    OLDB(0); OLDA(0, 0);
    OUNIT(1, Alp, 8192, 31);
    OPH(0, 0);
    OPH(0, 2);
    OLDA(0, 4);
    OPH(4, 0);
    VMC(0);
    OPH(4, 2);
    OLDB(1); OLDA(1, 0);
    OPH(0, 0);
    OPH(0, 2);
    OLDA(1, 4);
    OPH(4, 0);
    OPH(4, 2);

    const int ccol = lane & 15, crow = (lane >> 4) * 4;
#pragma unroll
    for (int m = 0; m < 8; ++m)
#pragma unroll
        for (int n = 0; n < 4; ++n) {
            float* cp = C + (size_t)(m0 + wave_m * 128 + m * 16 + crow) * 1024
                          + (n0 + wave_n * 64 + n * 16 + ccol);
#pragma unroll
            for (int r = 0; r < 4; ++r) cp[(size_t)r * 1024] = acc[m][n][r];
        }
}

// Per (b,h,seg): M_seg[d][v] = sk^T v, zsum[d], V^T bf16 tile — via MFMA.
__global__ __launch_bounds__(256) void seg_stats(
    const unsigned short* __restrict__ kproj, const unsigned short* __restrict__ vproj,
    float* __restrict__ Mseg, float* __restrict__ zsum,
    unsigned short* __restrict__ vtg)
{
    __shared__ unsigned short sm_kh[64 * 64];   // skT hi (sz8)
    __shared__ unsigned short sm_kl[64 * 64];   // skT lo (sz8)
    __shared__ unsigned short sm_vt[64 * 64];   // vT exact bf16 (sz8)
    const int idx = blockIdx.x;
    const int seg = idx & 15;
    const int bh  = idx >> 4;
    const int h   = bh & 15;
    const int b   = bh >> 4;
    const size_t base = ((size_t)b * T_ + (size_t)seg * SEG_ + (size_t)h * 32) * D_;
    const unsigned short* kt = kproj + base;
    const unsigned short* vt = vproj + base;
    const int t    = threadIdx.x;
    const int lane = t & 63;
    const int w    = t >> 6;
    const int c16  = lane & 15;
    const int g4   = lane >> 4;
    const int lr   = t >> 2;
    const int lc   = (t & 3) * 16;

    short8 bones;
#pragma unroll
    for (int j = 0; j < 8; ++j) bones[j] = (short)0x3F80;   // bf16 1.0

    f32x4 acc[4];                                // n-tiles 0..3 for m-tile w
#pragma unroll
    for (int nt = 0; nt < 4; ++nt) acc[nt] = (f32x4)0.f;
    f32x4 zacc = (f32x4)0.f;

    for (int c0 = 0; c0 < SEG_; c0 += 64) {
        __syncthreads();   // previous chunk's frag reads / vtg readback done
        {   // transpose-stage: lane = t-row, wave = 16-wide d-chunk.
            const int row = c0 + lane;
            const unsigned short* kp = kt + (size_t)row * 64 + w * 16;
            const unsigned short* vp = vt + (size_t)row * 64 + w * 16;
            ushort8 k0 = *(const ushort8*)kp, k1 = *(const ushort8*)(kp + 8);
            ushort8 v0 = *(const ushort8*)vp, v1 = *(const ushort8*)(vp + 8);
            const int tb = lane >> 3, tl = lane & 7;
#pragma unroll
            for (int e = 0; e < 8; ++e) {
                const float f0 = elu1(bf2f(k0[e]));
                const unsigned short h0 = f2bf(f0), l0 = f2bf(f0 - bf2f(h0));
                const float f1 = elu1(bf2f(k1[e]));
                const unsigned short h1 = f2bf(f1), l1 = f2bf(f1 - bf2f(h1));
                const int a0 = sz8(w * 16 + e,     tb) + tl;
                const int a1 = sz8(w * 16 + 8 + e, tb) + tl;
                sm_kh[a0] = h0; sm_kl[a0] = l0; sm_vt[a0] = v0[e];
                sm_kh[a1] = h1; sm_kl[a1] = l1; sm_vt[a1] = v1[e];
            }
        }
        __syncthreads();
        // MFMA: C[d][v] += skT[d][t] * vT[v][t], k-dim = t (2 k-steps of 32)
#pragma unroll
        for (int ks = 0; ks < 2; ++ks) {
            const short8 ahh = *(const short8*)&sm_kh[sz8(w * 16 + c16, ks * 4 + g4)];
            const short8 alo = *(const short8*)&sm_kl[sz8(w * 16 + c16, ks * 4 + g4)];
            zacc = __builtin_amdgcn_mfma_f32_16x16x32_bf16(ahh, bones, zacc, 0, 0, 0);
            zacc = __builtin_amdgcn_mfma_f32_16x16x32_bf16(alo, bones, zacc, 0, 0, 0);
#pragma unroll
            for (int nt = 0; nt < 4; ++nt) {
                const short8 bv = *(const short8*)&sm_vt[sz8(nt * 16 + c16, ks * 4 + g4)];
                acc[nt] = __builtin_amdgcn_mfma_f32_16x16x32_bf16(ahh, bv, acc[nt], 0, 0, 0);
                acc[nt] = __builtin_amdgcn_mfma_f32_16x16x32_bf16(alo, bv, acc[nt], 0, 0, 0);
            }
        }
        {   // vtg writeback for this chunk
            unsigned short* vo = vtg + ((size_t)idx * 64 + lr) * 512 + c0 + lc;
            *(ushort8*)vo       = *(const ushort8*)&sm_vt[sz8(lr, lc >> 3)];
            *(ushort8*)(vo + 8) = *(const ushort8*)&sm_vt[sz8(lr, (lc >> 3) + 1)];
        }
    }
    float* Mout = Mseg + (size_t)idx * 4096;
#pragma unroll
    for (int nt = 0; nt < 4; ++nt)
#pragma unroll
        for (int r = 0; r < 4; ++r)
            Mout[(size_t)(w * 16 + g4 * 4 + r) * 64 + nt * 16 + c16] = acc[nt][r];
    if (c16 == 0) {
#pragma unroll
        for (int r = 0; r < 4; ++r)
            zsum[(size_t)idx * 64 + w * 16 + g4 * 4 + r] = zacc[r];
    }
}

// Per (b,h,slice): in-place exclusive prefix of M (1024-float slice),
// inclusive prefix of z (slice 0). 128 blocks.
__global__ __launch_bounds__(256) void prefix_scan(
    float* __restrict__ M, float* __restrict__ z)
{
    const int blk = blockIdx.x;
    const int bh  = blk >> 2, sl = blk & 3;
    const int t   = threadIdx.x;
    const size_t off = (size_t)bh * NSEG_ * 4096 + (size_t)sl * 1024 + (size_t)t * 4;
    float4 run = make_float4(0.f, 0.f, 0.f, 0.f);
    float runz = 0.f;
    for (int seg = 0; seg < NSEG_; ++seg) {
        const size_t o = off + (size_t)seg * 4096;
        float4 m = *(const float4*)(M + o);
        *(float4*)(M + o) = run;
        run.x += m.x; run.y += m.y; run.z += m.z; run.w += m.w;
        if (sl == 0 && t < 64) {
            const size_t oz = ((size_t)bh * NSEG_ + seg) * 64 + t;
            runz += z[oz];
            z[oz] = runz;
        }
    }
}

// MFMA flash attention: ONE block per (b,h,seg). K/V^T/mem^T staged in LDS
// once; 4 q-sub-tiles of 128 rows (8 waves x 16); kb loop barrier-free.
// Per-row math bit-identical to round 10.
__global__ __launch_bounds__(512) void attn_mfma(
    const unsigned short* __restrict__ qproj, const unsigned short* __restrict__ kproj,
    const unsigned short* __restrict__ vtg, const float* __restrict__ memb,
    const float* __restrict__ Zaf, const float* __restrict__ betas,
    unsigned short* __restrict__ ath, unsigned short* __restrict__ atl)
{
    __shared__ unsigned short smK[8 * 4096];   // K: 8 kb-tiles [64][64] sz8 (64KB)
    __shared__ unsigned short smV[8 * 4096];   // V^T: 8 kb-tiles [64][64] sz8 (64KB)
    __shared__ unsigned short smM[4096];       // mem^T [64][64] sz8 (8KB)
    __shared__ unsigned short smP[128 * 64];   // P publish + epilogue scratch (16KB)
    __shared__ float Zsh[64], gsh[64];

    const int rest = blockIdx.x;
    const int bh   = rest >> 4;
    const int seg  = rest & 15;
    const int h    = bh & 15;
    const int b    = bh >> 4;
    const size_t base = ((size_t)b * T_ + (size_t)seg * SEG_ + (size_t)h * 32) * D_;

    const int t    = threadIdx.x;
    const int lane = t & 63;
    const int w    = t >> 6;          // 0..7
    const int c16  = lane & 15;
    const int g4   = lane >> 4;
    const int sr   = t >> 3;          // staging row 0..63
    const int sg   = t & 7;           // staging granule 0..7

    const unsigned short* qt = qproj + base;
    const unsigned short* kt = kproj + base;
    const unsigned short* vt = vtg + (size_t)rest * (64 * 512);
    const float* mb = memb + (size_t)rest * 4096;

    if (t < 64) {
        Zsh[t] = Zaf[(size_t)rest * 64 + t];
        gsh[t] = 1.f / (1.f + __expf(-betas[h * 64 + t]));
    }

    // stage mem^T (bf16, transposed, sz8)
    {
        const float* mp = mb + (size_t)sr * 64 + sg * 8;
#pragma unroll
        for (int u = 0; u < 2; ++u) {
            float4 m4 = *(const float4*)(mp + u * 4);
            smM[sz8(sg * 8 + u * 4 + 0, sr >> 3) + (sr & 7)] = f2bf(m4.x);
            smM[sz8(sg * 8 + u * 4 + 1, sr >> 3) + (sr & 7)] = f2bf(m4.y);
            smM[sz8(sg * 8 + u * 4 + 2, sr >> 3) + (sr & 7)] = f2bf(m4.z);
            smM[sz8(sg * 8 + u * 4 + 3, sr >> 3) + (sr & 7)] = f2bf(m4.w);
        }
    }
    // stage K and V^T (raw 16B copies, sz8)
#pragma unroll
    for (int kb = 0; kb < 8; ++kb) {
        *(ushort8*)&smK[kb * 4096 + sz8(sr, sg)] =
            *(const ushort8*)(kt + (size_t)(kb * 64 + sr) * 64 + sg * 8);
        *(ushort8*)&smV[kb * 4096 + sz8(sr, sg)] =
            *(const ushort8*)(vt + (size_t)sr * 512 + kb * 64 + sg * 8);
    }
    __syncthreads();

    short8 bones;
#pragma unroll
    for (int j = 0; j < 8; ++j) bones[j] = (short)0x3F80;

#pragma unroll 1
    for (int qc2 = 0; qc2 < 4; ++qc2) {
        // q fragments for this 128-row sub-tile (wave w owns rows w*16..+15)
        short8 qh[2], sqh[2];
        float rowsum = 0.f;
#pragma unroll
        for (int ks = 0; ks < 2; ++ks) {
            const unsigned short* qp =
                qt + (size_t)(qc2 * 128 + w * 16 + c16) * 64 + g4 * 8 + ks * 32;
            ushort8 qv = *(const ushort8*)qp;
            short8 qf, sf;
#pragma unroll
            for (int j = 0; j < 8; ++j) {
                float e = elu1(bf2f(qv[j]));
                rowsum += e;
                qf[j] = (short)qv[j];
                sf[j] = (short)f2bf(e);
            }
            qh[ks] = qf; sqh[ks] = sf;
        }
        rowsum += __shfl_xor(rowsum, 16);
        rowsum += __shfl_xor(rowsum, 32);

        // num = sq @ mem
        f32x4 numf[4];
#pragma unroll
        for (int nf = 0; nf < 4; ++nf) numf[nf] = (f32x4)0.f;
#pragma unroll
        for (int ks = 0; ks < 2; ++ks)
#pragma unroll
            for (int nf = 0; nf < 4; ++nf) {
                short8 bm = *(const short8*)&smM[sz8(nf * 16 + c16, g4 + ks * 4)];
                numf[nf] = __builtin_amdgcn_mfma_f32_16x16x32_bf16(sqh[ks], bm, numf[nf], 0, 0, 0);
            }

        f32x4 o[4];
#pragma unroll
        for (int nf = 0; nf < 4; ++nf) o[nf] = (f32x4)0.f;
        float mrow[4] = {-1e30f, -1e30f, -1e30f, -1e30f};
        float lrow[4] = {0.f, 0.f, 0.f, 0.f};

#pragma unroll 1
        for (int kb = 0; kb < 8; ++kb) {
            // scores S = Q @ K^T (K persistent in LDS — no staging, no barrier)
            f32x4 s[4];
#pragma unroll
            for (int nf = 0; nf < 4; ++nf) s[nf] = (f32x4)0.f;
#pragma unroll
            for (int ks = 0; ks < 2; ++ks)
#pragma unroll
                for (int nf = 0; nf < 4; ++nf) {
                    short8 bk = *(const short8*)&smK[kb * 4096 + sz8(nf * 16 + c16, g4 + ks * 4)];
                    s[nf] = __builtin_amdgcn_mfma_f32_16x16x32_bf16(qh[ks], bk, s[nf], 0, 0, 0);
                }
#pragma unroll
            for (int nf = 0; nf < 4; ++nf) s[nf] *= 0.125f;

            // T13 deferred max
            float pmax[4];
#pragma unroll
            for (int r = 0; r < 4; ++r)
                pmax[r] = fmaxf(fmaxf(s[0][r], s[1][r]), fmaxf(s[2][r], s[3][r]));
            const bool ok = pmax[0] <= mrow[0] + 8.f && pmax[1] <= mrow[1] + 8.f &&
                            pmax[2] <= mrow[2] + 8.f && pmax[3] <= mrow[3] + 8.f;
            if (!__all(ok)) {
#pragma unroll
                for (int r = 0; r < 4; ++r) {
                    float mx = pmax[r];
                    mx = fmaxf(mx, __shfl_xor(mx, 1));
                    mx = fmaxf(mx, __shfl_xor(mx, 2));
                    mx = fmaxf(mx, __shfl_xor(mx, 4));
                    mx = fmaxf(mx, __shfl_xor(mx, 8));
                    const float mnew = fmaxf(mrow[r], mx);
                    const float corr = __expf(mrow[r] - mnew);
                    mrow[r] = mnew;
                    lrow[r] *= corr;
#pragma unroll
                    for (int nf = 0; nf < 4; ++nf) o[nf][r] *= corr;
                }
            }
#pragma unroll
            for (int nf = 0; nf < 4; ++nf)
#pragma unroll
                for (int r = 0; r < 4; ++r) {
                    s[nf][r] = __expf(s[nf][r] - mrow[r]);
                    // publish P (C-layout -> A-layout), wave-private rows
                    smP[sz8(w * 16 + g4 * 4 + r, nf * 2 + (c16 >> 3)) + (c16 & 7)] =
                        f2bf(s[nf][r]);
                }

            // O += P @ V ; row-sum via ones-MFMA
            f32x4 psum = (f32x4)0.f;
#pragma unroll
            for (int ks = 0; ks < 2; ++ks) {
                short8 pa = *(const short8*)&smP[sz8(w * 16 + c16, g4 + ks * 4)];
                psum = __builtin_amdgcn_mfma_f32_16x16x32_bf16(pa, bones, psum, 0, 0, 0);
#pragma unroll
                for (int nf = 0; nf < 4; ++nf) {
                    short8 bv = *(const short8*)&smV[kb * 4096 + sz8(nf * 16 + c16, g4 + ks * 4)];
                    o[nf] = __builtin_amdgcn_mfma_f32_16x16x32_bf16(pa, bv, o[nf], 0, 0, 0);
                }
            }
#pragma unroll
            for (int r = 0; r < 4; ++r) lrow[r] += psum[r];
        }

        // epilogue for this sub-tile: res -> hi/lo via smP scratch
        float rs[4], invl[4];
#pragma unroll
        for (int r = 0; r < 4; ++r) {
            rs[r]   = __shfl(rowsum, (g4 << 2) + r);
            invl[r] = 1.f / lrow[r];
        }
        float res[4][4];
#pragma unroll
        for (int nf = 0; nf < 4; ++nf) {
            const int col = nf * 16 + c16;
            const float Zc = Zsh[col], gc = gsh[col];
            const float izc = 1.f / Zc;
#pragma unroll
            for (int r = 0; r < 4; ++r) {
                const float adot = o[nf][r] * invl[r];
                const float amem = numf[nf][r] * izc / rs[r];
                res[nf][r] = gc * amem + (1.f - gc) * adot;
            }
        }
        const int orow = t >> 2, olc = (t & 3) * 16;
        const size_t ob = base + (size_t)(qc2 * 128 + orow) * 64 + olc;
        // hi pass (wave-private rows -> no pre-barrier needed; P reads done in-wave)
#pragma unroll
        for (int nf = 0; nf < 4; ++nf)
#pragma unroll
            for (int r = 0; r < 4; ++r)
                smP[sz8(w * 16 + g4 * 4 + r, nf * 2 + (c16 >> 3)) + (c16 & 7)] =
                    f2bf(res[nf][r]);
        __syncthreads();
        *(ushort8*)(ath + ob)     = *(const ushort8*)&smP[sz8(orow, olc >> 3)];
        *(ushort8*)(ath + ob + 8) = *(const ushort8*)&smP[sz8(orow, (olc >> 3) + 1)];
        __syncthreads();
        // lo pass
#pragma unroll
        for (int nf = 0; nf < 4; ++nf)
#pragma unroll
            for (int r = 0; r < 4; ++r) {
                const unsigned short hv = f2bf(res[nf][r]);
                smP[sz8(w * 16 + g4 * 4 + r, nf * 2 + (c16 >> 3)) + (c16 & 7)] =
                    f2bf(res[nf][r] - bf2f(hv));
            }
        __syncthreads();
        *(ushort8*)(atl + ob)     = *(const ushort8*)&smP[sz8(orow, olc >> 3)];
        *(ushort8*)(atl + ob + 8) = *(const ushort8*)&smP[sz8(orow, (olc >> 3) + 1)];
        __syncthreads();   // smP free for next sub-tile's P publishes
    }
}

extern "C" void kernel_launch(void* const* d_in, const int* in_sizes, int n_in,
                              void* d_out, int out_size, void* d_ws, size_t ws_size,
                              hipStream_t stream) {
    const float* x     = (const float*)d_in[0];
    const float* Wq    = (const float*)d_in[1];
    const float* Wk    = (const float*)d_in[2];
    const float* Wv    = (const float*)d_in[3];
    const float* Wout  = (const float*)d_in[4];
    const float* betas = (const float*)d_in[5];
    float* out = (float*)d_out;
    (void)d_ws; (void)ws_size;

    float *M, *z;
    unsigned short *qb, *kb, *vb, *xh, *wqkv, *vt, *ath, *atl, *woh, *wol;
    hipGetSymbolAddress((void**)&qb,   HIP_SYMBOL(g_qb));
    hipGetSymbolAddress((void**)&kb,   HIP_SYMBOL(g_kb));
    hipGetSymbolAddress((void**)&vb,   HIP_SYMBOL(g_vb));
    hipGetSymbolAddress((void**)&xh,   HIP_SYMBOL(g_xh));
    hipGetSymbolAddress((void**)&wqkv, HIP_SYMBOL(g_wqkv));
    hipGetSymbolAddress((void**)&vt,   HIP_SYMBOL(g_vt));
    hipGetSymbolAddress((void**)&ath,  HIP_SYMBOL(g_ath));
    hipGetSymbolAddress((void**)&atl,  HIP_SYMBOL(g_atl));
    hipGetSymbolAddress((void**)&woh,  HIP_SYMBOL(g_woh));
    hipGetSymbolAddress((void**)&wol,  HIP_SYMBOL(g_wol));
    hipGetSymbolAddress((void**)&M,    HIP_SYMBOL(g_M));
    hipGetSymbolAddress((void**)&z,    HIP_SYMBOL(g_z));

    // fused prologue: x + Wq/Wk/Wv casts + Wout split in one launch
    const int nXB = (int)(NPROJ / 1024), nWB = (int)(NW / 1024);
    prep_cast<<<nXB + 4 * nWB, 256, 0, stream>>>(x, Wq, Wk, Wv, Wout,
                                                 xh, wqkv, woh, wol);

    gemm_qkv8<<<dim3(768), 512, 0, stream>>>(xh, wqkv, qb, kb, vb);
    seg_stats<<<B_ * H_ * NSEG_, 256, 0, stream>>>(kb, vb, M, z, vt);
    prefix_scan<<<B_ * H_ * 4, 256, 0, stream>>>(M, z);
    attn_mfma<<<B_ * H_ * NSEG_, 512, 0, stream>>>(qb, kb, vt, M, z, betas, ath, atl);
    gemm_bt8<<<dim3(256), 512, 0, stream>>>(ath, atl, woh, wol, out);
}